// Round 7
// baseline (1301.407 us; speedup 1.0000x reference)
//
#include <hip/hip_runtime.h>
#include <stdint.h>

#define N_NODESC 50000
#define N_EDGESC 200000
#define D_INC 128
#define DC 256
#define N_LAYERSC 4
#define N_RELC 4
#define NUM_MC 1024
#define NUM_RC 64
#define NBLK_SCAN ((N_NODESC + 255) / 256)   // 196
#define ECACHE 1792

typedef __attribute__((ext_vector_type(4))) float floatx4;
typedef __attribute__((ext_vector_type(8))) short short8;

// ---------------- threefry2x32 (JAX-compatible) ----------------
__host__ __device__ __forceinline__ uint32_t rotl32(uint32_t x, int r){ return (x<<r)|(x>>(32-r)); }

__host__ __device__ inline void tf2x32(uint32_t k0, uint32_t k1, uint32_t x0, uint32_t x1,
                                       uint32_t* o0, uint32_t* o1){
  uint32_t k2 = k0 ^ k1 ^ 0x1BD11BDAu;
#define TFR(r) { x0 += x1; x1 = rotl32(x1, (r)); x1 ^= x0; }
  x0 += k0; x1 += k1;
  TFR(13) TFR(15) TFR(26) TFR(6)
  x0 += k1; x1 += k2 + 1u;
  TFR(17) TFR(29) TFR(16) TFR(24)
  x0 += k2; x1 += k0 + 2u;
  TFR(13) TFR(15) TFR(26) TFR(6)
  x0 += k0; x1 += k1 + 3u;
  TFR(17) TFR(29) TFR(16) TFR(24)
  x0 += k1; x1 += k2 + 4u;
  TFR(13) TFR(15) TFR(26) TFR(6)
  x0 += k2; x1 += k0 + 5u;
#undef TFR
  *o0 = x0; *o1 = x1;
}

__device__ __forceinline__ float erfinv_f32(float x){
  float w = -log1pf(-x*x);
  float p;
  if (w < 5.0f){
    w -= 2.5f;
    p = 2.81022636e-08f;
    p = fmaf(p, w, 3.43273939e-07f);
    p = fmaf(p, w, -3.5233877e-06f);
    p = fmaf(p, w, -4.39150654e-06f);
    p = fmaf(p, w, 0.00021858087f);
    p = fmaf(p, w, -0.00125372503f);
    p = fmaf(p, w, -0.00417768164f);
    p = fmaf(p, w, 0.246640727f);
    p = fmaf(p, w, 1.50140941f);
  } else {
    w = sqrtf(w) - 3.0f;
    p = -0.000200214257f;
    p = fmaf(p, w, 0.000100950558f);
    p = fmaf(p, w, 0.00134934322f);
    p = fmaf(p, w, -0.00367342844f);
    p = fmaf(p, w, 0.00573950773f);
    p = fmaf(p, w, -0.0076224613f);
    p = fmaf(p, w, 0.00943887047f);
    p = fmaf(p, w, 1.00167406f);
    p = fmaf(p, w, 2.83297682f);
  }
  return p*x;
}

__device__ __forceinline__ float bits_to_unit(uint32_t b){
  return __uint_as_float((b >> 9) | 0x3f800000u) - 1.0f;
}

__device__ __forceinline__ float bits_to_normal(uint32_t b){
  float f = bits_to_unit(b);
  const float lo = -0.99999994f;
  float u = f * (1.0f - lo) + lo;
  u = fmaxf(u, lo);
  return 1.41421356f * erfinv_f32(u);
}

__device__ __forceinline__ float waveReduce(float v){
  #pragma unroll
  for (int m = 1; m < 64; m <<= 1) v += __shfl_xor(v, m, 64);
  return v;
}

__device__ __forceinline__ ushort f2bf(float f){
  uint32_t u = __float_as_uint(f);
  uint32_t r = u + 0x7fffu + ((u>>16)&1u);
  return (ushort)(r>>16);
}
__device__ __forceinline__ float bf2f(ushort h){
  return __uint_as_float(((uint32_t)h)<<16);
}

typedef const __attribute__((address_space(1))) void* gas_t;
typedef __attribute__((address_space(3))) void* las_t;
__device__ __forceinline__ void gld16(const void* g, void* l){
  __builtin_amdgcn_global_load_lds((gas_t)g, (las_t)l, 16, 0, 0);
}

// ---------------- setup kernels ----------------
__global__ __launch_bounds__(256) void k_zero4(float4* p, int n4){
  int i = blockIdx.x*256 + threadIdx.x;
  if (i < n4) p[i] = make_float4(0.f,0.f,0.f,0.f);
}

__global__ __launch_bounds__(256) void k_count(const int* __restrict__ ei, const int* __restrict__ et,
                                               float* __restrict__ cnt, int* __restrict__ deg){
  int e = blockIdx.x*256 + threadIdx.x;
  if (e >= N_EDGESC) return;
  int r = et[e], dstv = ei[N_EDGESC + e];
  atomicAdd(&cnt[(size_t)r*N_NODESC + dstv], 1.0f);
  atomicAdd(&deg[dstv], 1);
}

__global__ __launch_bounds__(256) void k_scan1(const int* __restrict__ deg, int* __restrict__ bsum){
  int i = blockIdx.x*256 + threadIdx.x;
  int v = (i < N_NODESC) ? deg[i] : 0;
  #pragma unroll
  for (int m = 1; m < 64; m <<= 1) v += __shfl_xor(v, m, 64);
  __shared__ int ws_[4];
  if ((threadIdx.x & 63) == 0) ws_[threadIdx.x >> 6] = v;
  __syncthreads();
  if (threadIdx.x == 0) bsum[blockIdx.x] = ws_[0]+ws_[1]+ws_[2]+ws_[3];
}

__global__ __launch_bounds__(256) void k_scan2(int* __restrict__ bsum, int* __restrict__ boff){
  __shared__ int s[256];
  int t = threadIdx.x;
  s[t] = (t < NBLK_SCAN) ? bsum[t] : 0;
  __syncthreads();
  if (t == 0){
    int run = 0;
    for (int i = 0; i < NBLK_SCAN; i++){ int v = s[i]; s[i] = run; run += v; }
  }
  __syncthreads();
  if (t < NBLK_SCAN) boff[t] = s[t];
}

__global__ __launch_bounds__(256) void k_scan3(const int* __restrict__ deg, const int* __restrict__ boff,
                                               int* __restrict__ rowptr){
  int i = blockIdx.x*256 + threadIdx.x;
  int lane = threadIdx.x & 63, w = threadIdx.x >> 6;
  int d = (i < N_NODESC) ? deg[i] : 0;
  int v = d;
  #pragma unroll
  for (int off = 1; off < 64; off <<= 1){
    int t = __shfl_up(v, off, 64);
    if (lane >= off) v += t;
  }
  __shared__ int wt[4];
  if (lane == 63) wt[w] = v;
  __syncthreads();
  int wo = 0;
  for (int k = 0; k < w; k++) wo += wt[k];
  int ex = boff[blockIdx.x] + wo + v - d;
  if (i <= N_NODESC) rowptr[i] = ex;
}

__global__ __launch_bounds__(256) void k_fill2(const int* __restrict__ ei, const int* __restrict__ et,
                                               const float* __restrict__ cnt, const int* __restrict__ rowptr,
                                               int* __restrict__ cursor, int* __restrict__ ep,
                                               float* __restrict__ einvc){
  int e = blockIdx.x*256 + threadIdx.x;
  if (e >= N_EDGESC) return;
  int src = ei[e], dstv = ei[N_EDGESC + e], r = et[e];
  int pos = rowptr[dstv] + atomicAdd(&cursor[dstv], 1);
  ep[pos] = src | (r << 16);
  einvc[pos] = 1.0f / fmaxf(cnt[(size_t)r*N_NODESC + dstv], 1.0f);
}

__global__ __launch_bounds__(256) void k_bnd(const int* __restrict__ batch, int* __restrict__ grow){
  int i = blockIdx.x*256 + threadIdx.x;
  if (i >= N_NODESC) return;
  int b = batch[i];
  if (i == 0){ for (int g = 0; g <= b; g++) grow[g] = 0; }
  else {
    int pb = batch[i-1];
    for (int g = pb+1; g <= b; g++) grow[g] = i;
  }
  if (i == N_NODESC-1){ for (int g = b+1; g <= NUM_MC; g++) grow[g] = N_NODESC; }
}

// ---- one fused prep kernel: x->bf16, all weight transposes/concats ----
#define SEG0 (N_NODESC*D_INC/4)            // x float4 -> ushort4
#define SEG1 (DC*D_INC)                    // node_Wt[n*128+k]
#define SEG2 (N_LAYERSC*DC*1280)           // Wcat[l][n(256)][k(1280)]
#define SEG3 (DC*1024)                     // pqW fp32 [k(256)][n(1024)]
#define SEG4 (DC*512)                      // W1t[n(256)][k(512)]
#define SEG5 1024                          // pqb
__global__ __launch_bounds__(256) void k_prep(const float* __restrict__ x, ushort* __restrict__ xb,
                                              const float* __restrict__ node_W, ushort* __restrict__ node_Wt,
                                              const float* __restrict__ Wroot, const float* __restrict__ Wr,
                                              ushort* __restrict__ Wcat,
                                              const float* __restrict__ pu_W, const float* __restrict__ qz_W,
                                              float* __restrict__ pqW,
                                              const float* __restrict__ out_W1, ushort* __restrict__ W1t,
                                              const float* __restrict__ pu_b, const float* __restrict__ qz_b,
                                              float* __restrict__ pqb){
  int idx = blockIdx.x*256 + threadIdx.x;
  if (idx < SEG0){
    float4 v = ((const float4*)x)[idx];
    ushort4 o; o.x=f2bf(v.x); o.y=f2bf(v.y); o.z=f2bf(v.z); o.w=f2bf(v.w);
    ((ushort4*)xb)[idx] = o;
    return;
  }
  idx -= SEG0;
  if (idx < SEG1){
    int n = idx >> 7, k = idx & 127;
    node_Wt[idx] = f2bf(node_W[(size_t)k*DC + n]);
    return;
  }
  idx -= SEG1;
  if (idx < SEG2){
    int l = idx / (DC*1280), rem = idx - l*(DC*1280);
    int n = rem / 1280, k = rem - n*1280;
    float v;
    if (k < DC) v = Wroot[((size_t)l*DC + k)*DC + n];
    else {
      int kk = k - DC, r = kk >> 8, kr = kk & 255;
      v = Wr[(((size_t)l*N_RELC + r)*DC + kr)*DC + n];
    }
    Wcat[idx] = f2bf(v);
    return;
  }
  idx -= SEG2;
  if (idx < SEG3){
    int k = idx >> 10, n = idx & 1023;
    pqW[idx] = (n < 512) ? pu_W[(size_t)k*512 + n] : qz_W[(size_t)k*512 + (n-512)];
    return;
  }
  idx -= SEG3;
  if (idx < SEG4){
    int n = idx >> 9, k = idx & 511;
    W1t[idx] = f2bf(out_W1[(size_t)k*DC + n]);
    return;
  }
  idx -= SEG4;
  if (idx < SEG5){
    pqb[idx] = (idx < 512) ? pu_b[idx] : qz_b[idx-512];
  }
}

// ============ FUSED RGCN LAYER ============
// One block = 128 dst rows x full N=256. A-source = [curb | agg_r0..r3] built
// phase-by-phase in a 64KB LDS tile (XOR-swizzled). B = Wcat (L2-resident,
// read direct from global). Removes the 102MB agg round-trip entirely.
__global__ __launch_bounds__(512) void k_layer(
    const ushort* __restrict__ curb, const ushort* __restrict__ Wl,
    ushort* __restrict__ outb, const float* __restrict__ bias, int relu,
    const int* __restrict__ rowptr, const int* __restrict__ ep,
    const float* __restrict__ einvc)
{
  __shared__ ushort At[128*256];   // 64 KB; granule g (16B) of row rr at phys g^(rr&7)
  __shared__ int   epc[ECACHE];
  __shared__ float icc[ECACHE];
  const int tid = threadIdx.x, wave = tid >> 6, lane = tid & 63;
  const int m0 = blockIdx.x * 128;
  const int wm = (wave >> 2) * 64, wn = (wave & 3) * 64;
  const int qa = lane >> 4, lm = lane & 15;

  const int mEnd = (m0 + 128 <= N_NODESC) ? m0 + 128 : N_NODESC;
  const int ebeg = rowptr[m0];
  const int ecnt = rowptr[mEnd] - ebeg;
  for (int j = tid; j < ecnt && j < ECACHE; j += 512){
    epc[j] = ep[ebeg + j];
    icc[j] = einvc[ebeg + j];
  }

  floatx4 acc[4][4] = {};

  for (int phase = 0; phase < 5; ++phase){
    if (phase == 0){
      // stage curb tile: 8 rounds, each wave covers 2 rows/round (lane-contiguous LDS)
      #pragma unroll
      for (int t = 0; t < 8; t++){
        int rr = t*16 + wave*2 + (lane >> 5);
        int row = m0 + rr; if (row > N_NODESC-1) row = N_NODESC-1;
        int g = (lane & 31) ^ (rr & 7);
        gld16(curb + (size_t)row*256 + (size_t)g*8,
              At + ((size_t)(t*16 + wave*2))*256 + (size_t)lane*8);
      }
    } else {
      int r = phase - 1;
      for (int i = 0; i < 16; i++){
        int rr = wave*16 + i;
        int dst = m0 + rr;
        float sx=0.f, sy=0.f, sz=0.f, sw=0.f;
        if (dst < N_NODESC){
          int beg = rowptr[dst] - ebeg, end = rowptr[dst+1] - ebeg;
          for (int p = beg; p < end; p++){
            int pk; float ic;
            if (p < ECACHE){ pk = epc[p]; ic = icc[p]; }
            else { pk = ep[ebeg + p]; ic = einvc[ebeg + p]; }
            if ((pk >> 16) == r){
              const ushort4 h = *(const ushort4*)(curb + (size_t)(pk & 0xffff)*256 + lane*4);
              sx = fmaf(bf2f(h.x), ic, sx);
              sy = fmaf(bf2f(h.y), ic, sy);
              sz = fmaf(bf2f(h.z), ic, sz);
              sw = fmaf(bf2f(h.w), ic, sw);
            }
          }
        }
        ushort4 o; o.x=f2bf(sx); o.y=f2bf(sy); o.z=f2bf(sz); o.w=f2bf(sw);
        *(ushort4*)(At + (size_t)rr*256 + (size_t)(((lane>>1) ^ (rr & 7)))*8 + (lane & 1)*4) = o;
      }
    }
    __syncthreads();
    const ushort* Bb = Wl + phase*256;
    #pragma unroll
    for (int kc = 0; kc < 8; kc++){
      short8 bfv[4], af[4];
      #pragma unroll
      for (int nt = 0; nt < 4; nt++)
        bfv[nt] = *(const short8*)(Bb + (size_t)(wn + nt*16 + lm)*1280 + kc*32 + qa*8);
      #pragma unroll
      for (int mt = 0; mt < 4; mt++){
        int rr = wm + mt*16 + lm;
        af[mt] = *(const short8*)(At + (size_t)rr*256 + (size_t)((kc*4 + qa) ^ (rr & 7))*8);
      }
      #pragma unroll
      for (int mt = 0; mt < 4; mt++)
        #pragma unroll
        for (int nt = 0; nt < 4; nt++)
          acc[mt][nt] = __builtin_amdgcn_mfma_f32_16x16x32_bf16(af[mt], bfv[nt], acc[mt][nt], 0, 0, 0);
    }
    __syncthreads();
  }

  #pragma unroll
  for (int mt = 0; mt < 4; mt++){
    #pragma unroll
    for (int i = 0; i < 4; i++){
      int row = m0 + wm + mt*16 + qa*4 + i;
      if (row >= N_NODESC) continue;
      #pragma unroll
      for (int nt = 0; nt < 4; nt++){
        int col = wn + nt*16 + lm;
        float v = acc[mt][nt][i] + bias[col];
        if (relu) v = fmaxf(v, 0.f);
        outb[(size_t)row*256 + col] = f2bf(v);
      }
    }
  }
}

// pooling: rows 0..63 = relu(H_R); rows 64.. = relu(segment mean of bf16 feats)
__global__ __launch_bounds__(256) void k_pool(const ushort* __restrict__ featsb, const int* __restrict__ grow,
                                              const float* __restrict__ H_R, float* __restrict__ Hrelu){
  int row = blockIdx.x*4 + (threadIdx.x >> 6);
  if (row >= NUM_RC + NUM_MC) return;
  int lane = threadIdx.x & 63;
  float4 v;
  if (row < NUM_RC){
    v = *(const float4*)(H_R + (size_t)row*DC + lane*4);
  } else {
    int g = row - NUM_RC;
    int beg = grow[g], end = grow[g+1];
    float ax=0.f, ay=0.f, az=0.f, aw=0.f;
    for (int i = beg; i < end; i++){
      const ushort4 f = *(const ushort4*)(featsb + (size_t)i*DC + lane*4);
      ax += bf2f(f.x); ay += bf2f(f.y); az += bf2f(f.z); aw += bf2f(f.w);
    }
    float ic = 1.0f / fmaxf((float)(end-beg), 1.0f);
    v.x = ax*ic; v.y = ay*ic; v.z = az*ic; v.w = aw*ic;
  }
  v.x = fmaxf(v.x,0.f); v.y = fmaxf(v.y,0.f); v.z = fmaxf(v.z,0.f); v.w = fmaxf(v.w,0.f);
  *(float4*)(Hrelu + (size_t)row*DC + lane*4) = v;
}

// ------- bf16 MFMA GEMM (input proj / head), XOR-swizzled LDS -------
__global__ __launch_bounds__(256) void k_gemm_bf16(
    const ushort* __restrict__ A1, int lda1,
    const ushort* __restrict__ A2, int lda2, int Ksplit,
    const ushort* __restrict__ Bt, int ldb,
    void* __restrict__ Cout0, int ldc,
    int M, int N, int K,
    const float* __restrict__ bias, int flags)
{
  __shared__ ushort As[128*32];
  __shared__ ushort Bs[128*32];
  const int tid = threadIdx.x;
  const int wave = tid >> 6, lane = tid & 63;
  const int m0 = blockIdx.y * 128, n0 = blockIdx.x * 128;
  const int wm = (wave >> 1) * 64, wn = (wave & 1) * 64;
  const int qa = lane >> 4, lm = lane & 15;

  const int srow1 = wave*32 + (lane >> 2);
  const int srow2 = srow1 + 16;
  const int slot  = lane & 3;
  const int gl1 = slot ^ ((srow1 >> 1) & 3);
  const int gl2 = slot ^ ((srow2 >> 1) & 3);

  floatx4 acc[4][4] = {};

  for (int k0 = 0; k0 < K; k0 += 32){
    const ushort* a_base; int a_ld, acol;
    if (k0 < Ksplit){ a_base = A1; a_ld = lda1; acol = k0; }
    else            { a_base = A2; a_ld = lda2; acol = k0 - Ksplit; }
    int ar1 = m0 + srow1; if (ar1 > M-1) ar1 = M-1;
    int ar2 = m0 + srow2; if (ar2 > M-1) ar2 = M-1;
    gld16(a_base + (size_t)ar1*a_ld + acol + gl1*8, As + (size_t)srow1*32 + slot*8);
    gld16(a_base + (size_t)ar2*a_ld + acol + gl2*8, As + (size_t)srow2*32 + slot*8);
    gld16(Bt + (size_t)(n0 + srow1)*ldb + k0 + gl1*8, Bs + (size_t)srow1*32 + slot*8);
    gld16(Bt + (size_t)(n0 + srow2)*ldb + k0 + gl2*8, Bs + (size_t)srow2*32 + slot*8);
    __syncthreads();
    short8 af[4], bfv[4];
    #pragma unroll
    for (int mt = 0; mt < 4; mt++){
      int rr = wm + mt*16 + lm;
      af[mt] = *(const short8*)(As + (size_t)rr*32 + (qa ^ ((rr>>1)&3))*8);
    }
    #pragma unroll
    for (int nt = 0; nt < 4; nt++){
      int rr = wn + nt*16 + lm;
      bfv[nt] = *(const short8*)(Bs + (size_t)rr*32 + (qa ^ ((rr>>1)&3))*8);
    }
    #pragma unroll
    for (int mt = 0; mt < 4; mt++)
      #pragma unroll
      for (int nt = 0; nt < 4; nt++)
        acc[mt][nt] = __builtin_amdgcn_mfma_f32_16x16x32_bf16(af[mt], bfv[nt], acc[mt][nt], 0, 0, 0);
    __syncthreads();
  }

  #pragma unroll
  for (int mt = 0; mt < 4; mt++){
    #pragma unroll
    for (int i = 0; i < 4; i++){
      int row = m0 + wm + mt*16 + qa*4 + i;
      if (row >= M) continue;
      #pragma unroll
      for (int nt = 0; nt < 4; nt++){
        int col = n0 + wn + nt*16 + lm;
        float v = acc[mt][nt][i];
        if (flags & 2) v += bias[col];
        if (flags & 4) v = fmaxf(v, 0.0f);
        if (flags & 1)
          ((ushort*)Cout0)[(size_t)row*ldc + col] = f2bf(v);
        else
          ((float*)Cout0)[(size_t)row*ldc + col] = v;
      }
    }
  }
}

// ---------------- fp32 GEMM (small/accuracy-critical) ----------------
__global__ __launch_bounds__(256) void k_gemm(
    const float* __restrict__ A, int lda,
    const float* __restrict__ B, int ldb,
    float* __restrict__ C, int ldc,
    int M, int N, int K,
    const float* __restrict__ bias, int flags)
{
  __shared__ __align__(16) float Asm[64][36];
  __shared__ __align__(16) float Bsm[32][64];
  const int tid = threadIdx.x;
  const int tx = tid & 15, ty = tid >> 4;
  const int m0 = blockIdx.y * 64, n0 = blockIdx.x * 64;
  const int am = tid >> 2, ak = (tid & 3) * 8;
  const int bk = tid >> 3, bn = (tid & 7) * 8;
  float acc[4][4] = {};
  for (int k0 = 0; k0 < K; k0 += 32){
    float4 a0, a1;
    int arow = m0 + am;
    if (arow < M){
      const float* ap = A + (size_t)arow*lda + (k0 + ak);
      a0 = *(const float4*)ap;
      a1 = *(const float4*)(ap + 4);
    } else {
      a0 = make_float4(0,0,0,0); a1 = a0;
    }
    const float* bp = B + (size_t)(k0 + bk)*ldb + (n0 + bn);
    float4 b0v = *(const float4*)bp;
    float4 b1v = *(const float4*)(bp + 4);
    *(float4*)&Asm[am][ak]   = a0;
    *(float4*)&Asm[am][ak+4] = a1;
    *(float4*)&Bsm[bk][bn]   = b0v;
    *(float4*)&Bsm[bk][bn+4] = b1v;
    __syncthreads();
    #pragma unroll
    for (int kk = 0; kk < 32; ++kk){
      float av[4], bv[4];
      #pragma unroll
      for (int i=0;i<4;i++) av[i] = Asm[ty*4+i][kk];
      #pragma unroll
      for (int j=0;j<4;j++) bv[j] = Bsm[kk][tx*4+j];
      #pragma unroll
      for (int i=0;i<4;i++)
        #pragma unroll
        for (int j=0;j<4;j++)
          acc[i][j] = fmaf(av[i], bv[j], acc[i][j]);
    }
    __syncthreads();
  }
  #pragma unroll
  for (int i=0;i<4;i++){
    int row = m0 + ty*4 + i;
    if (row >= M) continue;
    #pragma unroll
    for (int j=0;j<4;j++){
      int col = n0 + tx*4 + j;
      float v = acc[i][j];
      if (flags & 2) v += bias[col];
      if (flags & 4) v = fmaxf(v, 0.0f);
      C[(size_t)row*ldc + col] = v;
    }
  }
}

// ---------------- sampling & head kernels ----------------
// pq layout per row (1024): [pu_mean(256) | pu_ls(256) | qz_mean(256) | qz_ls(256)]
__global__ __launch_bounds__(256) void k_sample_u(const float* __restrict__ pq, float* __restrict__ u,
                                                  ushort* __restrict__ repb,
                                                  uint32_t k0, uint32_t k1){
  const int half = (1088*DC)/2;
  int j = blockIdx.x*256 + threadIdx.x;
  if (j >= half) return;
  uint32_t o0, o1;
  tf2x32(k0, k1, (uint32_t)j, (uint32_t)(j + half), &o0, &o1);
  #pragma unroll
  for (int t = 0; t < 2; t++){
    int i = j + t*half;
    uint32_t bits = t ? o1 : o0;
    int row = i >> 8, col = i & 255;
    const float* pr = pq + (size_t)row*1024;
    float val = pr[col] + expf(pr[256 + col]) * bits_to_normal(bits);
    u[i] = val;
    repb[(size_t)row*512 + 256 + col] = f2bf(val);
  }
}

__global__ __launch_bounds__(256) void k_sample_zM(const float* __restrict__ pq, float* __restrict__ zM,
                                                   ushort* __restrict__ repb,
                                                   uint32_t k0, uint32_t k1){
  const int half = (NUM_MC*DC)/2;
  int j = blockIdx.x*256 + threadIdx.x;
  if (j >= half) return;
  uint32_t o0, o1;
  tf2x32(k0, k1, (uint32_t)j, (uint32_t)(j + half), &o0, &o1);
  #pragma unroll
  for (int t = 0; t < 2; t++){
    int i = j + t*half;
    uint32_t bits = t ? o1 : o0;
    int m = i >> 8, col = i & 255;
    const float* pr = pq + (size_t)(NUM_RC + m)*1024;
    float val = pr[512 + col] + expf(pr[768 + col]) * bits_to_normal(bits);
    zM[i] = val;
    repb[(size_t)(NUM_RC + m)*512 + col] = f2bf(val);
  }
}

__global__ __launch_bounds__(256) void k_sample_zR(const float* __restrict__ pq, ushort* __restrict__ repb,
                                                   uint32_t k0, uint32_t k1){
  const int half = (NUM_RC*DC)/2;
  int j = blockIdx.x*256 + threadIdx.x;
  if (j >= half) return;
  uint32_t o0, o1;
  tf2x32(k0, k1, (uint32_t)j, (uint32_t)(j + half), &o0, &o1);
  #pragma unroll
  for (int t = 0; t < 2; t++){
    int i = j + t*half;
    uint32_t bits = t ? o1 : o0;
    int r = i >> 8, col = i & 255;
    const float* pr = pq + (size_t)r*1024;
    float val = pr[512 + col] + expf(pr[768 + col]) * bits_to_normal(bits);
    repb[(size_t)r*512 + col] = f2bf(val);
  }
}

__global__ __launch_bounds__(64) void k_d2(const float* __restrict__ u, float* __restrict__ d2){
  int m = blockIdx.x, r = threadIdx.x;
  const float4* um = (const float4*)(u + (size_t)(NUM_RC + m)*DC);
  const float4* ur = (const float4*)(u + (size_t)r*DC);
  float s = 0.f;
  #pragma unroll 4
  for (int d = 0; d < DC/4; ++d){
    float4 a = um[d], b = ur[d];
    float dx = a.x-b.x, dy = a.y-b.y, dz = a.z-b.z, dw = a.w-b.w;
    s = fmaf(dx,dx, fmaf(dy,dy, fmaf(dz,dz, fmaf(dw,dw, s))));
  }
  d2[m*NUM_RC + r] = s;
}

__device__ __forceinline__ void A_elem(float* An, const float* d2, int i, uint32_t bits, float inv_s){
  float logp = -0.5f * d2[i] * inv_s;
  float la = logp - logf(fmaxf(-expm1f(logp), 1e-20f));
  float f = bits_to_unit(bits);
  const float mn = 1e-6f, mx = 0.999999f;
  float U = fmaxf(f*(mx-mn) + mn, mn);
  float g = (la + logf(U) - log1pf(-U)) / 0.3f;
  An[i] = 1.0f / (1.0f + expf(-g));
}

__global__ __launch_bounds__(256) void k_A(const float* __restrict__ d2, const float* __restrict__ pg,
                                           float* __restrict__ An, uint32_t k0, uint32_t k1){
  const int HALF = (NUM_MC*NUM_RC)/2;
  int j = blockIdx.x*256 + threadIdx.x;
  if (j >= HALF) return;
  uint32_t o0, o1;
  tf2x32(k0, k1, (uint32_t)j, (uint32_t)(j + HALF), &o0, &o1);
  float inv_s = expf(-pg[0]);
  A_elem(An, d2, j, o0, inv_s);
  A_elem(An, d2, j + HALF, o1, inv_s);
}

__global__ __launch_bounds__(64) void k_rownorm(float* __restrict__ An){
  int m = blockIdx.x, r = threadIdx.x;
  float v = An[m*NUM_RC + r];
  float s = waveReduce(v);
  An[m*NUM_RC + r] = v / (s + 1e-8f);
}

__global__ __launch_bounds__(256) void k_logpqz(const float* __restrict__ zM, const float* __restrict__ pzcat,
                                                const float* __restrict__ pq, float* __restrict__ scal){
  int idx = blockIdx.x*256 + threadIdx.x;
  int m = idx >> 8, d = idx & 255;
  float z  = zM[idx];
  float pm = pzcat[(size_t)m*512 + d];
  float pl = pzcat[(size_t)m*512 + 256 + d];
  const float* qrow = pq + (size_t)(NUM_RC + m)*1024;
  float qm = qrow[512 + d], ql = qrow[768 + d];
  float tp = (z - pm) * expf(-pl);
  float tq = (z - qm) * expf(-ql);
  float term = (-pl - 0.5f*tp*tp) - (-ql - 0.5f*tq*tq);
  float s = waveReduce(term);
  if ((threadIdx.x & 63) == 0) atomicAdd(&scal[0], s);
}

// fused: rows 0..63 -> rationale (scal[2], yR); rows 64..1087 -> prediction (scal[1], yM)
__global__ __launch_bounds__(256) void k_out_head(const float* __restrict__ hid, const float* __restrict__ W2,
                                                  const float* __restrict__ b2, const int* __restrict__ yM,
                                                  const int* __restrict__ yR, float* __restrict__ scal){
  int wave = threadIdx.x >> 6, lane = threadIdx.x & 63;
  int row = blockIdx.x*4 + wave;
  if (row >= NUM_RC + NUM_MC) return;
  const float* h = hid + (size_t)row*256;
  float p0 = 0.f, p1 = 0.f;
  #pragma unroll
  for (int c = 0; c < 4; c++){
    int d = lane*4 + c;
    float hv = h[d];
    p0 = fmaf(hv, W2[d*2+0], p0);
    p1 = fmaf(hv, W2[d*2+1], p1);
  }
  p0 = waveReduce(p0);
  p1 = waveReduce(p1);
  if (lane == 0){
    float l0 = p0 + b2[0], l1 = p1 + b2[1];
    float mx = fmaxf(l0, l1);
    float lse = mx + logf(expf(l0-mx) + expf(l1-mx));
    int y = (row < NUM_RC) ? yR[row] : yM[row - NUM_RC];
    float lp = ((y == 0) ? l0 : l1) - lse;
    atomicAdd((row < NUM_RC) ? &scal[2] : &scal[1], lp);
  }
}

__global__ __launch_bounds__(256) void k_reg(const float* __restrict__ d2, const int* __restrict__ yM,
                                             float* __restrict__ scal){
  int t = blockIdx.x*256 + threadIdx.x;
  float v = 0.f;
  if (t < 32*1024){
    int i = t >> 10, m = t & 1023;
    int col = i + (1 - yM[m]) * 32;
    v = sqrtf(fmaxf(d2[m*NUM_RC + col], 1e-12f));
  }
  float s = waveReduce(v);
  if ((threadIdx.x & 63) == 0) atomicAdd(&scal[3], s);
}

__global__ void k_final(const float* __restrict__ scal, float* __restrict__ out){
  float pred = -(scal[1] + 0.1f*scal[0]) / 1024.0f;
  float rat  = -scal[2] / 64.0f;
  float regm = scal[3] / 32768.0f;
  out[0] = pred + rat - 0.1f*regm;
}

// ---------------- launch ----------------
extern "C" void kernel_launch(void* const* d_in, const int* in_sizes, int n_in,
                              void* d_out, int out_size, void* d_ws, size_t ws_size,
                              hipStream_t stream) {
  const float* x         = (const float*)d_in[0];
  const int*   edge_index= (const int*)  d_in[1];
  const int*   edge_type = (const int*)  d_in[2];
  const int*   batch     = (const int*)  d_in[3];
  const int*   yM        = (const int*)  d_in[4];
  const int*   yR        = (const int*)  d_in[5];
  const float* H_R       = (const float*)d_in[6];
  const float* node_W    = (const float*)d_in[7];
  const float* node_b    = (const float*)d_in[8];
  const float* gcn_Wr    = (const float*)d_in[9];
  const float* gcn_Wroot = (const float*)d_in[10];
  const float* gcn_b     = (const float*)d_in[11];
  const float* pg_ls     = (const float*)d_in[12];
  const float* pu_W      = (const float*)d_in[13];
  const float* pu_b      = (const float*)d_in[14];
  const float* qz_W      = (const float*)d_in[15];
  const float* qz_b      = (const float*)d_in[16];
  const float* out_W1    = (const float*)d_in[17];
  const float* out_b1    = (const float*)d_in[18];
  const float* out_W2    = (const float*)d_in[19];
  const float* out_b2    = (const float*)d_in[20];
  float* out = (float*)d_out;

  char* base = (char*)d_ws;
  size_t off = 0;
  auto ALLOC = [&](size_t nbytes)->void*{
    void* p = base + off; off += (nbytes + 255) & ~(size_t)255; return p;
  };
  ushort* curb_a  = (ushort*)ALLOC((size_t)N_NODESC*DC*2);
  ushort* curb_b  = (ushort*)ALLOC((size_t)N_NODESC*DC*2);
  ushort* xb      = (ushort*)ALLOC((size_t)N_NODESC*D_INC*2);
  ushort* node_Wt = (ushort*)ALLOC((size_t)SEG1*2);
  ushort* Wcat    = (ushort*)ALLOC((size_t)SEG2*2);
  float*  pqW     = (float*) ALLOC((size_t)SEG3*4);
  ushort* W1t     = (ushort*)ALLOC((size_t)SEG4*2);
  float*  pqb     = (float*) ALLOC((size_t)SEG5*4);
  // contiguous zero group: cnt | deg | cursor | scal
  float*  zgrp    = (float*) ALLOC((size_t)(N_RELC*N_NODESC + N_NODESC + N_NODESC + 16)*4);
  float*  cnt     = zgrp;
  int*    deg     = (int*)(cnt + (size_t)N_RELC*N_NODESC);
  int*    cursor  = deg + N_NODESC;
  float*  scal    = (float*)(cursor + N_NODESC);
  int*    rowptr  = (int*)   ALLOC((size_t)(N_NODESC+1)*4);
  int*    bsum    = (int*)   ALLOC((size_t)NBLK_SCAN*4);
  int*    boff    = (int*)   ALLOC((size_t)NBLK_SCAN*4);
  int*    ep      = (int*)   ALLOC((size_t)N_EDGESC*4);
  float*  einvc   = (float*) ALLOC((size_t)N_EDGESC*4);
  int*    grow    = (int*)   ALLOC((size_t)(NUM_MC+1)*4);
  float*  Hrelu   = (float*) ALLOC((size_t)1088*DC*4);
  float*  pq      = (float*) ALLOC((size_t)1088*1024*4);
  float*  u       = (float*) ALLOC((size_t)1088*DC*4);
  ushort* repb    = (ushort*)ALLOC((size_t)1088*512*2);
  float*  zM      = (float*) ALLOC((size_t)NUM_MC*DC*4);
  float*  d2      = (float*) ALLOC((size_t)NUM_MC*NUM_RC*4);
  float*  An      = (float*) ALLOC((size_t)NUM_MC*NUM_RC*4);
  float*  pzcat   = (float*) ALLOC((size_t)NUM_MC*512*4);
  float*  hid     = (float*) ALLOC((size_t)1088*256*4);
  (void)ws_size; (void)in_sizes; (void)n_in; (void)out_size;

  uint32_t ya0,ya1,yb0,yb1,yc0,yc1,yd0,yd1;
  tf2x32(0u,42u, 0u,4u, &ya0,&ya1);
  tf2x32(0u,42u, 1u,5u, &yb0,&yb1);
  tf2x32(0u,42u, 2u,6u, &yc0,&yc1);
  tf2x32(0u,42u, 3u,7u, &yd0,&yd1);
  const uint32_t ku0=ya0,  ku1=yb0;
  const uint32_t ka0=yc0,  ka1=yd0;
  const uint32_t kzm0=ya1, kzm1=yb1;
  const uint32_t kzr0=yc1, kzr1=yd1;

  auto GEMM = [&](const float* A, int lda, const float* B, int ldb, float* C, int ldc,
                  int M, int N, int K, const float* bias, int flags){
    k_gemm<<<dim3(N/64, (M+63)/64), dim3(256), 0, stream>>>(A, lda, B, ldb, C, ldc, M, N, K, bias, flags);
  };
  auto BGEMM = [&](const ushort* A1, int lda1, const ushort* A2, int lda2, int Ksplit,
                   const ushort* Bt, int ldb, void* C, int ldc,
                   int M, int N, int K, const float* bias, int flags){
    k_gemm_bf16<<<dim3(N/128, (M+127)/128), dim3(256), 0, stream>>>(
        A1, lda1, A2, lda2, Ksplit, Bt, ldb, C, ldc, M, N, K, bias, flags);
  };

  // ---- setup ----
  {
    int n4 = (N_RELC*N_NODESC + 2*N_NODESC + 16)/4;
    k_zero4<<<dim3((n4+255)/256), dim3(256), 0, stream>>>((float4*)zgrp, n4);
  }
  k_count<<<dim3((N_EDGESC+255)/256), dim3(256), 0, stream>>>(edge_index, edge_type, cnt, deg);
  k_scan1<<<dim3(NBLK_SCAN), dim3(256), 0, stream>>>(deg, bsum);
  k_scan2<<<dim3(1), dim3(256), 0, stream>>>(bsum, boff);
  k_scan3<<<dim3(NBLK_SCAN), dim3(256), 0, stream>>>(deg, boff, rowptr);
  k_fill2<<<dim3((N_EDGESC+255)/256), dim3(256), 0, stream>>>(edge_index, edge_type, cnt, rowptr, cursor, ep, einvc);
  k_bnd  <<<dim3((N_NODESC+255)/256), dim3(256), 0, stream>>>(batch, grow);
  {
    int total = SEG0+SEG1+SEG2+SEG3+SEG4+SEG5;
    k_prep<<<dim3((total+255)/256), dim3(256), 0, stream>>>(
        x, xb, node_W, node_Wt, gcn_Wroot, gcn_Wr, Wcat, pu_W, qz_W, pqW, out_W1, W1t, pu_b, qz_b, pqb);
  }

  // ---- input projection: curb_a = bf16(x @ node_W + node_b) ----
  BGEMM(xb, D_INC, xb, D_INC, D_INC, node_Wt, D_INC, curb_a, DC, N_NODESC, DC, D_INC, node_b, 1|2);

  // ---- RGCN layers: fully fused aggregate+transform ----
  ushort* cur = curb_a; ushort* nxt = curb_b;
  for (int l = 0; l < N_LAYERSC; l++){
    k_layer<<<dim3((N_NODESC+127)/128), dim3(512), 0, stream>>>(
        cur, Wcat + (size_t)l*DC*1280, nxt, gcn_b + l*DC,
        (l < N_LAYERSC-1) ? 1 : 0, rowptr, ep, einvc);
    ushort* t = nxt; nxt = cur; cur = t;
  }
  // cur == final feats (bf16, no relu)

  // ---- pool + concat + relu (fp32) ----
  k_pool<<<dim3((NUM_RC+NUM_MC+3)/4), dim3(256), 0, stream>>>(cur, grow, H_R, Hrelu);

  // ---- fused pu|qz projection (fp32, accuracy-critical) ----
  GEMM(Hrelu, DC, pqW, 1024, pq, 1024, 1088, 1024, DC, pqb, 2);

  // ---- u sampling (fp32 u + bf16 rep cols 256..511) ----
  k_sample_u<<<dim3(544), dim3(256), 0, stream>>>(pq, u, repb, ku0, ku1);

  // ---- d2, A, An ----
  k_d2<<<dim3(NUM_MC), dim3(64), 0, stream>>>(u, d2);
  k_A <<<dim3(128), dim3(256), 0, stream>>>(d2, pg_ls, An, ka0, ka1);
  k_rownorm<<<dim3(NUM_MC), dim3(64), 0, stream>>>(An);

  // ---- pzcat = An @ qz[:64] (fp32) ----
  GEMM(An, NUM_RC, pq + 512, 1024, pzcat, 512, NUM_MC, 512, NUM_RC, nullptr, 0);

  // ---- z sampling + log_pqz ----
  k_sample_zM<<<dim3(512), dim3(256), 0, stream>>>(pq, zM, repb, kzm0, kzm1);
  k_logpqz<<<dim3(1024), dim3(256), 0, stream>>>(zM, pzcat, pq, scal);
  k_sample_zR<<<dim3(32), dim3(256), 0, stream>>>(pq, repb, kzr0, kzr1);

  // ---- fused output head: hid = relu(rep @ W1 + b1), then logits+loss ----
  BGEMM(repb, 512, repb, 512, 512, W1t, 512, hid, 256, NUM_RC+NUM_MC, 256, 512, out_b1, 2|4);
  k_out_head<<<dim3((NUM_RC+NUM_MC)/4), dim3(256), 0, stream>>>(hid, out_W2, out_b2, yM, yR, scal);

  // ---- reg term & final combine ----
  k_reg<<<dim3(128), dim3(256), 0, stream>>>(d2, yM, scal);
  k_final<<<dim3(1), dim3(1), 0, stream>>>(scal, out);
}

// Round 8
// 835.384 us; speedup vs baseline: 1.5579x; 1.5579x over previous
//
#include <hip/hip_runtime.h>
#include <stdint.h>

#define N_NODESC 50000
#define N_EDGESC 200000
#define D_INC 128
#define DC 256
#define N_LAYERSC 4
#define N_RELC 4
#define NUM_MC 1024
#define NUM_RC 64
#define NBLK_SCAN ((N_NODESC + 255) / 256)   // 196

typedef __attribute__((ext_vector_type(4))) float floatx4;
typedef __attribute__((ext_vector_type(8))) short short8;

// ---------------- threefry2x32 (JAX-compatible) ----------------
__host__ __device__ __forceinline__ uint32_t rotl32(uint32_t x, int r){ return (x<<r)|(x>>(32-r)); }

__host__ __device__ inline void tf2x32(uint32_t k0, uint32_t k1, uint32_t x0, uint32_t x1,
                                       uint32_t* o0, uint32_t* o1){
  uint32_t k2 = k0 ^ k1 ^ 0x1BD11BDAu;
#define TFR(r) { x0 += x1; x1 = rotl32(x1, (r)); x1 ^= x0; }
  x0 += k0; x1 += k1;
  TFR(13) TFR(15) TFR(26) TFR(6)
  x0 += k1; x1 += k2 + 1u;
  TFR(17) TFR(29) TFR(16) TFR(24)
  x0 += k2; x1 += k0 + 2u;
  TFR(13) TFR(15) TFR(26) TFR(6)
  x0 += k0; x1 += k1 + 3u;
  TFR(17) TFR(29) TFR(16) TFR(24)
  x0 += k1; x1 += k2 + 4u;
  TFR(13) TFR(15) TFR(26) TFR(6)
  x0 += k2; x1 += k0 + 5u;
#undef TFR
  *o0 = x0; *o1 = x1;
}

__device__ __forceinline__ float erfinv_f32(float x){
  float w = -log1pf(-x*x);
  float p;
  if (w < 5.0f){
    w -= 2.5f;
    p = 2.81022636e-08f;
    p = fmaf(p, w, 3.43273939e-07f);
    p = fmaf(p, w, -3.5233877e-06f);
    p = fmaf(p, w, -4.39150654e-06f);
    p = fmaf(p, w, 0.00021858087f);
    p = fmaf(p, w, -0.00125372503f);
    p = fmaf(p, w, -0.00417768164f);
    p = fmaf(p, w, 0.246640727f);
    p = fmaf(p, w, 1.50140941f);
  } else {
    w = sqrtf(w) - 3.0f;
    p = -0.000200214257f;
    p = fmaf(p, w, 0.000100950558f);
    p = fmaf(p, w, 0.00134934322f);
    p = fmaf(p, w, -0.00367342844f);
    p = fmaf(p, w, 0.00573950773f);
    p = fmaf(p, w, -0.0076224613f);
    p = fmaf(p, w, 0.00943887047f);
    p = fmaf(p, w, 1.00167406f);
    p = fmaf(p, w, 2.83297682f);
  }
  return p*x;
}

__device__ __forceinline__ float bits_to_unit(uint32_t b){
  return __uint_as_float((b >> 9) | 0x3f800000u) - 1.0f;
}

__device__ __forceinline__ float bits_to_normal(uint32_t b){
  float f = bits_to_unit(b);
  const float lo = -0.99999994f;
  float u = f * (1.0f - lo) + lo;
  u = fmaxf(u, lo);
  return 1.41421356f * erfinv_f32(u);
}

__device__ __forceinline__ float waveReduce(float v){
  #pragma unroll
  for (int m = 1; m < 64; m <<= 1) v += __shfl_xor(v, m, 64);
  return v;
}

__device__ __forceinline__ ushort f2bf(float f){
  uint32_t u = __float_as_uint(f);
  uint32_t r = u + 0x7fffu + ((u>>16)&1u);
  return (ushort)(r>>16);
}
__device__ __forceinline__ float bf2f(ushort h){
  return __uint_as_float(((uint32_t)h)<<16);
}

typedef const __attribute__((address_space(1))) void* gas_t;
typedef __attribute__((address_space(3))) void* las_t;
__device__ __forceinline__ void gld16(const void* g, void* l){
  __builtin_amdgcn_global_load_lds((gas_t)g, (las_t)l, 16, 0, 0);
}

// ---------------- setup kernels ----------------
__global__ __launch_bounds__(256) void k_zero4(float4* p, int n4){
  int i = blockIdx.x*256 + threadIdx.x;
  if (i < n4) p[i] = make_float4(0.f,0.f,0.f,0.f);
}

__global__ __launch_bounds__(256) void k_count(const int* __restrict__ ei, const int* __restrict__ et,
                                               float* __restrict__ cnt, int* __restrict__ deg){
  int e = blockIdx.x*256 + threadIdx.x;
  if (e >= N_EDGESC) return;
  int r = et[e], dstv = ei[N_EDGESC + e];
  atomicAdd(&cnt[(size_t)r*N_NODESC + dstv], 1.0f);
  atomicAdd(&deg[dstv], 1);
}

__global__ __launch_bounds__(256) void k_scan1(const int* __restrict__ deg, int* __restrict__ bsum){
  int i = blockIdx.x*256 + threadIdx.x;
  int v = (i < N_NODESC) ? deg[i] : 0;
  #pragma unroll
  for (int m = 1; m < 64; m <<= 1) v += __shfl_xor(v, m, 64);
  __shared__ int ws_[4];
  if ((threadIdx.x & 63) == 0) ws_[threadIdx.x >> 6] = v;
  __syncthreads();
  if (threadIdx.x == 0) bsum[blockIdx.x] = ws_[0]+ws_[1]+ws_[2]+ws_[3];
}

__global__ __launch_bounds__(256) void k_scan2(int* __restrict__ bsum, int* __restrict__ boff){
  __shared__ int s[256];
  int t = threadIdx.x;
  s[t] = (t < NBLK_SCAN) ? bsum[t] : 0;
  __syncthreads();
  if (t == 0){
    int run = 0;
    for (int i = 0; i < NBLK_SCAN; i++){ int v = s[i]; s[i] = run; run += v; }
  }
  __syncthreads();
  if (t < NBLK_SCAN) boff[t] = s[t];
}

__global__ __launch_bounds__(256) void k_scan3(const int* __restrict__ deg, const int* __restrict__ boff,
                                               int* __restrict__ rowptr){
  int i = blockIdx.x*256 + threadIdx.x;
  int lane = threadIdx.x & 63, w = threadIdx.x >> 6;
  int d = (i < N_NODESC) ? deg[i] : 0;
  int v = d;
  #pragma unroll
  for (int off = 1; off < 64; off <<= 1){
    int t = __shfl_up(v, off, 64);
    if (lane >= off) v += t;
  }
  __shared__ int wt[4];
  if (lane == 63) wt[w] = v;
  __syncthreads();
  int wo = 0;
  for (int k = 0; k < w; k++) wo += wt[k];
  int ex = boff[blockIdx.x] + wo + v - d;
  if (i <= N_NODESC) rowptr[i] = ex;
}

__global__ __launch_bounds__(256) void k_fill2(const int* __restrict__ ei, const int* __restrict__ et,
                                               const float* __restrict__ cnt, const int* __restrict__ rowptr,
                                               int* __restrict__ cursor, int* __restrict__ ep,
                                               float* __restrict__ einvc){
  int e = blockIdx.x*256 + threadIdx.x;
  if (e >= N_EDGESC) return;
  int src = ei[e], dstv = ei[N_EDGESC + e], r = et[e];
  int pos = rowptr[dstv] + atomicAdd(&cursor[dstv], 1);
  ep[pos] = src | (r << 16);
  einvc[pos] = 1.0f / fmaxf(cnt[(size_t)r*N_NODESC + dstv], 1.0f);
}

__global__ __launch_bounds__(256) void k_bnd(const int* __restrict__ batch, int* __restrict__ grow){
  int i = blockIdx.x*256 + threadIdx.x;
  if (i >= N_NODESC) return;
  int b = batch[i];
  if (i == 0){ for (int g = 0; g <= b; g++) grow[g] = 0; }
  else {
    int pb = batch[i-1];
    for (int g = pb+1; g <= b; g++) grow[g] = i;
  }
  if (i == N_NODESC-1){ for (int g = b+1; g <= NUM_MC; g++) grow[g] = N_NODESC; }
}

// ---- one fused prep kernel: x->bf16, all weight transposes/concats ----
#define SEG0 (N_NODESC*D_INC/4)            // x float4 -> ushort4
#define SEG1 (DC*D_INC)                    // node_Wt[n*128+k]
#define SEG2 (N_LAYERSC*DC*1280)           // Wcat[l][n(256)][k(1280)]
#define SEG3 (DC*1024)                     // pqW fp32 [k(256)][n(1024)]
#define SEG4 (DC*512)                      // W1t[n(256)][k(512)]
#define SEG5 1024                          // pqb
__global__ __launch_bounds__(256) void k_prep(const float* __restrict__ x, ushort* __restrict__ xb,
                                              const float* __restrict__ node_W, ushort* __restrict__ node_Wt,
                                              const float* __restrict__ Wroot, const float* __restrict__ Wr,
                                              ushort* __restrict__ Wcat,
                                              const float* __restrict__ pu_W, const float* __restrict__ qz_W,
                                              float* __restrict__ pqW,
                                              const float* __restrict__ out_W1, ushort* __restrict__ W1t,
                                              const float* __restrict__ pu_b, const float* __restrict__ qz_b,
                                              float* __restrict__ pqb){
  int idx = blockIdx.x*256 + threadIdx.x;
  if (idx < SEG0){
    float4 v = ((const float4*)x)[idx];
    ushort4 o; o.x=f2bf(v.x); o.y=f2bf(v.y); o.z=f2bf(v.z); o.w=f2bf(v.w);
    ((ushort4*)xb)[idx] = o;
    return;
  }
  idx -= SEG0;
  if (idx < SEG1){
    int n = idx >> 7, k = idx & 127;
    node_Wt[idx] = f2bf(node_W[(size_t)k*DC + n]);
    return;
  }
  idx -= SEG1;
  if (idx < SEG2){
    int l = idx / (DC*1280), rem = idx - l*(DC*1280);
    int n = rem / 1280, k = rem - n*1280;
    float v;
    if (k < DC) v = Wroot[((size_t)l*DC + k)*DC + n];
    else {
      int kk = k - DC, r = kk >> 8, kr = kk & 255;
      v = Wr[(((size_t)l*N_RELC + r)*DC + kr)*DC + n];
    }
    Wcat[idx] = f2bf(v);
    return;
  }
  idx -= SEG2;
  if (idx < SEG3){
    int k = idx >> 10, n = idx & 1023;
    pqW[idx] = (n < 512) ? pu_W[(size_t)k*512 + n] : qz_W[(size_t)k*512 + (n-512)];
    return;
  }
  idx -= SEG3;
  if (idx < SEG4){
    int n = idx >> 9, k = idx & 511;
    W1t[idx] = f2bf(out_W1[(size_t)k*DC + n]);
    return;
  }
  idx -= SEG4;
  if (idx < SEG5){
    pqb[idx] = (idx < 512) ? pu_b[idx] : qz_b[idx-512];
  }
}

// ---- aggregation: one wave per dst; 8-edge prefetched gather ----
__global__ __launch_bounds__(256) void k_agg(const ushort* __restrict__ curb, ushort* __restrict__ agg,
                                             const int* __restrict__ rowptr, const int* __restrict__ ep,
                                             const float* __restrict__ einvc){
  int dstv = blockIdx.x*4 + (threadIdx.x >> 6);
  if (dstv >= N_NODESC) return;
  int lane = threadIdx.x & 63;
  int beg = rowptr[dstv], end = rowptr[dstv+1];
  float4 s0 = {0,0,0,0}, s1 = {0,0,0,0}, s2 = {0,0,0,0}, s3 = {0,0,0,0};
  int p = beg;
  while (p < end){
    int nb = end - p; if (nb > 8) nb = 8;
    int pk[8]; float ic[8]; ushort4 h[8];
    #pragma unroll
    for (int j = 0; j < 8; j++) if (j < nb){ pk[j] = ep[p+j]; ic[j] = einvc[p+j]; }
    #pragma unroll
    for (int j = 0; j < 8; j++) if (j < nb)
      h[j] = *(const ushort4*)(curb + (size_t)(pk[j] & 0xffff)*DC + lane*4);
    #pragma unroll
    for (int j = 0; j < 8; j++) if (j < nb){
      float c = ic[j];
      int r = pk[j] >> 16;
      float hx = bf2f(h[j].x)*c, hy = bf2f(h[j].y)*c, hz = bf2f(h[j].z)*c, hw = bf2f(h[j].w)*c;
      if (r == 0){ s0.x+=hx; s0.y+=hy; s0.z+=hz; s0.w+=hw; }
      else if (r == 1){ s1.x+=hx; s1.y+=hy; s1.z+=hz; s1.w+=hw; }
      else if (r == 2){ s2.x+=hx; s2.y+=hy; s2.z+=hz; s2.w+=hw; }
      else { s3.x+=hx; s3.y+=hy; s3.z+=hz; s3.w+=hw; }
    }
    p += nb;
  }
  ushort* ab = agg + (size_t)dstv*1024 + lane*4;
  ushort4 o;
  o.x=f2bf(s0.x); o.y=f2bf(s0.y); o.z=f2bf(s0.z); o.w=f2bf(s0.w); *(ushort4*)(ab       ) = o;
  o.x=f2bf(s1.x); o.y=f2bf(s1.y); o.z=f2bf(s1.z); o.w=f2bf(s1.w); *(ushort4*)(ab + 256 ) = o;
  o.x=f2bf(s2.x); o.y=f2bf(s2.y); o.z=f2bf(s2.z); o.w=f2bf(s2.w); *(ushort4*)(ab + 512 ) = o;
  o.x=f2bf(s3.x); o.y=f2bf(s3.y); o.z=f2bf(s3.z); o.w=f2bf(s3.w); *(ushort4*)(ab + 768 ) = o;
}

// pooling: rows 0..63 = relu(H_R); rows 64.. = relu(segment mean of bf16 feats)
__global__ __launch_bounds__(256) void k_pool(const ushort* __restrict__ featsb, const int* __restrict__ grow,
                                              const float* __restrict__ H_R, float* __restrict__ Hrelu){
  int row = blockIdx.x*4 + (threadIdx.x >> 6);
  if (row >= NUM_RC + NUM_MC) return;
  int lane = threadIdx.x & 63;
  float4 v;
  if (row < NUM_RC){
    v = *(const float4*)(H_R + (size_t)row*DC + lane*4);
  } else {
    int g = row - NUM_RC;
    int beg = grow[g], end = grow[g+1];
    float ax=0.f, ay=0.f, az=0.f, aw=0.f;
    for (int i = beg; i < end; i++){
      const ushort4 f = *(const ushort4*)(featsb + (size_t)i*DC + lane*4);
      ax += bf2f(f.x); ay += bf2f(f.y); az += bf2f(f.z); aw += bf2f(f.w);
    }
    float ic = 1.0f / fmaxf((float)(end-beg), 1.0f);
    v.x = ax*ic; v.y = ay*ic; v.z = az*ic; v.w = aw*ic;
  }
  v.x = fmaxf(v.x,0.f); v.y = fmaxf(v.y,0.f); v.z = fmaxf(v.z,0.f); v.w = fmaxf(v.w,0.f);
  *(float4*)(Hrelu + (size_t)row*DC + lane*4) = v;
}

// ------- bf16 MFMA GEMM, dual A source (K split), BK=64 + XOR swizzle -------
// C = [A1|A2](M x K) @ Bt(N x K)^T. flags: 1=bf16 out, 2=+bias, 4=relu
// Ksplit must be a multiple of 64. LDS rows are 128B (8 x 16B granules);
// logical granule g of row rr lives at phys slot g ^ (rr&7).
__global__ __launch_bounds__(256) void k_gemm_bf16(
    const ushort* __restrict__ A1, int lda1,
    const ushort* __restrict__ A2, int lda2, int Ksplit,
    const ushort* __restrict__ Bt, int ldb,
    void* __restrict__ Cout0, int ldc,
    int M, int N, int K,
    const float* __restrict__ bias, int flags)
{
  __shared__ ushort As[128*64];   // 16 KB
  __shared__ ushort Bs[128*64];   // 16 KB
  const int tid = threadIdx.x;
  const int wave = tid >> 6, lane = tid & 63;
  const int m0 = blockIdx.y * 128, n0 = blockIdx.x * 128;
  const int wm = (wave >> 1) * 64, wn = (wave & 1) * 64;
  const int qa = lane >> 4, lm = lane & 15;

  const int lrow = lane >> 3;   // 0..7 (row within 8-row group)
  const int slot = lane & 7;    // 0..7 (16B slot within 128B row)

  floatx4 acc[4][4] = {};

  for (int k0 = 0; k0 < K; k0 += 64){
    const ushort* a_base; int a_ld, acol;
    if (k0 < Ksplit){ a_base = A1; a_ld = lda1; acol = k0; }
    else            { a_base = A2; a_ld = lda2; acol = k0 - Ksplit; }
    #pragma unroll
    for (int t = 0; t < 4; t++){
      int rr = t*32 + wave*8 + lrow;
      int gl = slot ^ (rr & 7);
      int ar = m0 + rr; if (ar > M-1) ar = M-1;
      gld16(a_base + (size_t)ar*a_ld + acol + gl*8, As + (size_t)rr*64 + slot*8);
      gld16(Bt + (size_t)(n0 + rr)*ldb + k0 + gl*8,  Bs + (size_t)rr*64 + slot*8);
    }
    __syncthreads();
    #pragma unroll
    for (int kk2 = 0; kk2 < 2; kk2++){
      short8 af[4], bfv[4];
      #pragma unroll
      for (int mt = 0; mt < 4; mt++){
        int rr = wm + mt*16 + lm;
        af[mt] = *(const short8*)(As + (size_t)rr*64 + (size_t)(((kk2*4 + qa) ^ (rr & 7)))*8);
      }
      #pragma unroll
      for (int nt = 0; nt < 4; nt++){
        int rr = wn + nt*16 + lm;
        bfv[nt] = *(const short8*)(Bs + (size_t)rr*64 + (size_t)(((kk2*4 + qa) ^ (rr & 7)))*8);
      }
      #pragma unroll
      for (int mt = 0; mt < 4; mt++)
        #pragma unroll
        for (int nt = 0; nt < 4; nt++)
          acc[mt][nt] = __builtin_amdgcn_mfma_f32_16x16x32_bf16(af[mt], bfv[nt], acc[mt][nt], 0, 0, 0);
    }
    __syncthreads();
  }

  #pragma unroll
  for (int mt = 0; mt < 4; mt++){
    #pragma unroll
    for (int i = 0; i < 4; i++){
      int row = m0 + wm + mt*16 + qa*4 + i;
      if (row >= M) continue;
      #pragma unroll
      for (int nt = 0; nt < 4; nt++){
        int col = n0 + wn + nt*16 + lm;
        float v = acc[mt][nt][i];
        if (flags & 2) v += bias[col];
        if (flags & 4) v = fmaxf(v, 0.0f);
        if (flags & 1)
          ((ushort*)Cout0)[(size_t)row*ldc + col] = f2bf(v);
        else
          ((float*)Cout0)[(size_t)row*ldc + col] = v;
      }
    }
  }
}

// ---------------- fp32 GEMM (small/accuracy-critical) ----------------
__global__ __launch_bounds__(256) void k_gemm(
    const float* __restrict__ A, int lda,
    const float* __restrict__ B, int ldb,
    float* __restrict__ C, int ldc,
    int M, int N, int K,
    const float* __restrict__ bias, int flags)
{
  __shared__ __align__(16) float Asm[64][36];
  __shared__ __align__(16) float Bsm[32][64];
  const int tid = threadIdx.x;
  const int tx = tid & 15, ty = tid >> 4;
  const int m0 = blockIdx.y * 64, n0 = blockIdx.x * 64;
  const int am = tid >> 2, ak = (tid & 3) * 8;
  const int bk = tid >> 3, bn = (tid & 7) * 8;
  float acc[4][4] = {};
  for (int k0 = 0; k0 < K; k0 += 32){
    float4 a0, a1;
    int arow = m0 + am;
    if (arow < M){
      const float* ap = A + (size_t)arow*lda + (k0 + ak);
      a0 = *(const float4*)ap;
      a1 = *(const float4*)(ap + 4);
    } else {
      a0 = make_float4(0,0,0,0); a1 = a0;
    }
    const float* bp = B + (size_t)(k0 + bk)*ldb + (n0 + bn);
    float4 b0v = *(const float4*)bp;
    float4 b1v = *(const float4*)(bp + 4);
    *(float4*)&Asm[am][ak]   = a0;
    *(float4*)&Asm[am][ak+4] = a1;
    *(float4*)&Bsm[bk][bn]   = b0v;
    *(float4*)&Bsm[bk][bn+4] = b1v;
    __syncthreads();
    #pragma unroll
    for (int kk = 0; kk < 32; ++kk){
      float av[4], bv[4];
      #pragma unroll
      for (int i=0;i<4;i++) av[i] = Asm[ty*4+i][kk];
      #pragma unroll
      for (int j=0;j<4;j++) bv[j] = Bsm[kk][tx*4+j];
      #pragma unroll
      for (int i=0;i<4;i++)
        #pragma unroll
        for (int j=0;j<4;j++)
          acc[i][j] = fmaf(av[i], bv[j], acc[i][j]);
    }
    __syncthreads();
  }
  #pragma unroll
  for (int i=0;i<4;i++){
    int row = m0 + ty*4 + i;
    if (row >= M) continue;
    #pragma unroll
    for (int j=0;j<4;j++){
      int col = n0 + tx*4 + j;
      float v = acc[i][j];
      if (flags & 2) v += bias[col];
      if (flags & 4) v = fmaxf(v, 0.0f);
      C[(size_t)row*ldc + col] = v;
    }
  }
}

// ---------------- sampling & head kernels ----------------
// pq layout per row (1024): [pu_mean(256) | pu_ls(256) | qz_mean(256) | qz_ls(256)]
__global__ __launch_bounds__(256) void k_sample_u(const float* __restrict__ pq, float* __restrict__ u,
                                                  ushort* __restrict__ repb,
                                                  uint32_t k0, uint32_t k1){
  const int half = (1088*DC)/2;
  int j = blockIdx.x*256 + threadIdx.x;
  if (j >= half) return;
  uint32_t o0, o1;
  tf2x32(k0, k1, (uint32_t)j, (uint32_t)(j + half), &o0, &o1);
  #pragma unroll
  for (int t = 0; t < 2; t++){
    int i = j + t*half;
    uint32_t bits = t ? o1 : o0;
    int row = i >> 8, col = i & 255;
    const float* pr = pq + (size_t)row*1024;
    float val = pr[col] + expf(pr[256 + col]) * bits_to_normal(bits);
    u[i] = val;
    repb[(size_t)row*512 + 256 + col] = f2bf(val);
  }
}

__global__ __launch_bounds__(256) void k_sample_zM(const float* __restrict__ pq, float* __restrict__ zM,
                                                   ushort* __restrict__ repb,
                                                   uint32_t k0, uint32_t k1){
  const int half = (NUM_MC*DC)/2;
  int j = blockIdx.x*256 + threadIdx.x;
  if (j >= half) return;
  uint32_t o0, o1;
  tf2x32(k0, k1, (uint32_t)j, (uint32_t)(j + half), &o0, &o1);
  #pragma unroll
  for (int t = 0; t < 2; t++){
    int i = j + t*half;
    uint32_t bits = t ? o1 : o0;
    int m = i >> 8, col = i & 255;
    const float* pr = pq + (size_t)(NUM_RC + m)*1024;
    float val = pr[512 + col] + expf(pr[768 + col]) * bits_to_normal(bits);
    zM[i] = val;
    repb[(size_t)(NUM_RC + m)*512 + col] = f2bf(val);
  }
}

__global__ __launch_bounds__(256) void k_sample_zR(const float* __restrict__ pq, ushort* __restrict__ repb,
                                                   uint32_t k0, uint32_t k1){
  const int half = (NUM_RC*DC)/2;
  int j = blockIdx.x*256 + threadIdx.x;
  if (j >= half) return;
  uint32_t o0, o1;
  tf2x32(k0, k1, (uint32_t)j, (uint32_t)(j + half), &o0, &o1);
  #pragma unroll
  for (int t = 0; t < 2; t++){
    int i = j + t*half;
    uint32_t bits = t ? o1 : o0;
    int r = i >> 8, col = i & 255;
    const float* pr = pq + (size_t)r*1024;
    float val = pr[512 + col] + expf(pr[768 + col]) * bits_to_normal(bits);
    repb[(size_t)r*512 + col] = f2bf(val);
  }
}

__global__ __launch_bounds__(64) void k_d2(const float* __restrict__ u, float* __restrict__ d2){
  int m = blockIdx.x, r = threadIdx.x;
  const float4* um = (const float4*)(u + (size_t)(NUM_RC + m)*DC);
  const float4* ur = (const float4*)(u + (size_t)r*DC);
  float s = 0.f;
  #pragma unroll 4
  for (int d = 0; d < DC/4; ++d){
    float4 a = um[d], b = ur[d];
    float dx = a.x-b.x, dy = a.y-b.y, dz = a.z-b.z, dw = a.w-b.w;
    s = fmaf(dx,dx, fmaf(dy,dy, fmaf(dz,dz, fmaf(dw,dw, s))));
  }
  d2[m*NUM_RC + r] = s;
}

__device__ __forceinline__ void A_elem(float* An, const float* d2, int i, uint32_t bits, float inv_s){
  float logp = -0.5f * d2[i] * inv_s;
  float la = logp - logf(fmaxf(-expm1f(logp), 1e-20f));
  float f = bits_to_unit(bits);
  const float mn = 1e-6f, mx = 0.999999f;
  float U = fmaxf(f*(mx-mn) + mn, mn);
  float g = (la + logf(U) - log1pf(-U)) / 0.3f;
  An[i] = 1.0f / (1.0f + expf(-g));
}

__global__ __launch_bounds__(256) void k_A(const float* __restrict__ d2, const float* __restrict__ pg,
                                           float* __restrict__ An, uint32_t k0, uint32_t k1){
  const int HALF = (NUM_MC*NUM_RC)/2;
  int j = blockIdx.x*256 + threadIdx.x;
  if (j >= HALF) return;
  uint32_t o0, o1;
  tf2x32(k0, k1, (uint32_t)j, (uint32_t)(j + HALF), &o0, &o1);
  float inv_s = expf(-pg[0]);
  A_elem(An, d2, j, o0, inv_s);
  A_elem(An, d2, j + HALF, o1, inv_s);
}

__global__ __launch_bounds__(64) void k_rownorm(float* __restrict__ An){
  int m = blockIdx.x, r = threadIdx.x;
  float v = An[m*NUM_RC + r];
  float s = waveReduce(v);
  An[m*NUM_RC + r] = v / (s + 1e-8f);
}

__global__ __launch_bounds__(256) void k_logpqz(const float* __restrict__ zM, const float* __restrict__ pzcat,
                                                const float* __restrict__ pq, float* __restrict__ scal){
  int idx = blockIdx.x*256 + threadIdx.x;
  int m = idx >> 8, d = idx & 255;
  float z  = zM[idx];
  float pm = pzcat[(size_t)m*512 + d];
  float pl = pzcat[(size_t)m*512 + 256 + d];
  const float* qrow = pq + (size_t)(NUM_RC + m)*1024;
  float qm = qrow[512 + d], ql = qrow[768 + d];
  float tp = (z - pm) * expf(-pl);
  float tq = (z - qm) * expf(-ql);
  float term = (-pl - 0.5f*tp*tp) - (-ql - 0.5f*tq*tq);
  float s = waveReduce(term);
  if ((threadIdx.x & 63) == 0) atomicAdd(&scal[0], s);
}

// fused: rows 0..63 -> rationale (scal[2], yR); rows 64..1087 -> prediction (scal[1], yM)
__global__ __launch_bounds__(256) void k_out_head(const float* __restrict__ hid, const float* __restrict__ W2,
                                                  const float* __restrict__ b2, const int* __restrict__ yM,
                                                  const int* __restrict__ yR, float* __restrict__ scal){
  int wave = threadIdx.x >> 6, lane = threadIdx.x & 63;
  int row = blockIdx.x*4 + wave;
  if (row >= NUM_RC + NUM_MC) return;
  const float* h = hid + (size_t)row*256;
  float p0 = 0.f, p1 = 0.f;
  #pragma unroll
  for (int c = 0; c < 4; c++){
    int d = lane*4 + c;
    float hv = h[d];
    p0 = fmaf(hv, W2[d*2+0], p0);
    p1 = fmaf(hv, W2[d*2+1], p1);
  }
  p0 = waveReduce(p0);
  p1 = waveReduce(p1);
  if (lane == 0){
    float l0 = p0 + b2[0], l1 = p1 + b2[1];
    float mx = fmaxf(l0, l1);
    float lse = mx + logf(expf(l0-mx) + expf(l1-mx));
    int y = (row < NUM_RC) ? yR[row] : yM[row - NUM_RC];
    float lp = ((y == 0) ? l0 : l1) - lse;
    atomicAdd((row < NUM_RC) ? &scal[2] : &scal[1], lp);
  }
}

__global__ __launch_bounds__(256) void k_reg(const float* __restrict__ d2, const int* __restrict__ yM,
                                             float* __restrict__ scal){
  int t = blockIdx.x*256 + threadIdx.x;
  float v = 0.f;
  if (t < 32*1024){
    int i = t >> 10, m = t & 1023;
    int col = i + (1 - yM[m]) * 32;
    v = sqrtf(fmaxf(d2[m*NUM_RC + col], 1e-12f));
  }
  float s = waveReduce(v);
  if ((threadIdx.x & 63) == 0) atomicAdd(&scal[3], s);
}

__global__ void k_final(const float* __restrict__ scal, float* __restrict__ out){
  float pred = -(scal[1] + 0.1f*scal[0]) / 1024.0f;
  float rat  = -scal[2] / 64.0f;
  float regm = scal[3] / 32768.0f;
  out[0] = pred + rat - 0.1f*regm;
}

// ---------------- launch ----------------
extern "C" void kernel_launch(void* const* d_in, const int* in_sizes, int n_in,
                              void* d_out, int out_size, void* d_ws, size_t ws_size,
                              hipStream_t stream) {
  const float* x         = (const float*)d_in[0];
  const int*   edge_index= (const int*)  d_in[1];
  const int*   edge_type = (const int*)  d_in[2];
  const int*   batch     = (const int*)  d_in[3];
  const int*   yM        = (const int*)  d_in[4];
  const int*   yR        = (const int*)  d_in[5];
  const float* H_R       = (const float*)d_in[6];
  const float* node_W    = (const float*)d_in[7];
  const float* node_b    = (const float*)d_in[8];
  const float* gcn_Wr    = (const float*)d_in[9];
  const float* gcn_Wroot = (const float*)d_in[10];
  const float* gcn_b     = (const float*)d_in[11];
  const float* pg_ls     = (const float*)d_in[12];
  const float* pu_W      = (const float*)d_in[13];
  const float* pu_b      = (const float*)d_in[14];
  const float* qz_W      = (const float*)d_in[15];
  const float* qz_b      = (const float*)d_in[16];
  const float* out_W1    = (const float*)d_in[17];
  const float* out_b1    = (const float*)d_in[18];
  const float* out_W2    = (const float*)d_in[19];
  const float* out_b2    = (const float*)d_in[20];
  float* out = (float*)d_out;

  char* base = (char*)d_ws;
  size_t off = 0;
  auto ALLOC = [&](size_t nbytes)->void*{
    void* p = base + off; off += (nbytes + 255) & ~(size_t)255; return p;
  };
  ushort* curb_a  = (ushort*)ALLOC((size_t)N_NODESC*DC*2);
  ushort* curb_b  = (ushort*)ALLOC((size_t)N_NODESC*DC*2);
  ushort* agg     = (ushort*)ALLOC((size_t)N_NODESC*1024*2);
  ushort* xb      = (ushort*)ALLOC((size_t)N_NODESC*D_INC*2);
  ushort* node_Wt = (ushort*)ALLOC((size_t)SEG1*2);
  ushort* Wcat    = (ushort*)ALLOC((size_t)SEG2*2);
  float*  pqW     = (float*) ALLOC((size_t)SEG3*4);
  ushort* W1t     = (ushort*)ALLOC((size_t)SEG4*2);
  float*  pqb     = (float*) ALLOC((size_t)SEG5*4);
  // contiguous zero group: cnt | deg | cursor | scal
  float*  zgrp    = (float*) ALLOC((size_t)(N_RELC*N_NODESC + N_NODESC + N_NODESC + 16)*4);
  float*  cnt     = zgrp;
  int*    deg     = (int*)(cnt + (size_t)N_RELC*N_NODESC);
  int*    cursor  = deg + N_NODESC;
  float*  scal    = (float*)(cursor + N_NODESC);
  int*    rowptr  = (int*)   ALLOC((size_t)(N_NODESC+1)*4);
  int*    bsum    = (int*)   ALLOC((size_t)NBLK_SCAN*4);
  int*    boff    = (int*)   ALLOC((size_t)NBLK_SCAN*4);
  int*    ep      = (int*)   ALLOC((size_t)N_EDGESC*4);
  float*  einvc   = (float*) ALLOC((size_t)N_EDGESC*4);
  int*    grow    = (int*)   ALLOC((size_t)(NUM_MC+1)*4);
  float*  Hrelu   = (float*) ALLOC((size_t)1088*DC*4);
  float*  pq      = (float*) ALLOC((size_t)1088*1024*4);
  float*  u       = (float*) ALLOC((size_t)1088*DC*4);
  ushort* repb    = (ushort*)ALLOC((size_t)1088*512*2);
  float*  zM      = (float*) ALLOC((size_t)NUM_MC*DC*4);
  float*  d2      = (float*) ALLOC((size_t)NUM_MC*NUM_RC*4);
  float*  An      = (float*) ALLOC((size_t)NUM_MC*NUM_RC*4);
  float*  pzcat   = (float*) ALLOC((size_t)NUM_MC*512*4);
  float*  hid     = (float*) ALLOC((size_t)1088*256*4);
  (void)ws_size; (void)in_sizes; (void)n_in; (void)out_size;

  uint32_t ya0,ya1,yb0,yb1,yc0,yc1,yd0,yd1;
  tf2x32(0u,42u, 0u,4u, &ya0,&ya1);
  tf2x32(0u,42u, 1u,5u, &yb0,&yb1);
  tf2x32(0u,42u, 2u,6u, &yc0,&yc1);
  tf2x32(0u,42u, 3u,7u, &yd0,&yd1);
  const uint32_t ku0=ya0,  ku1=yb0;
  const uint32_t ka0=yc0,  ka1=yd0;
  const uint32_t kzm0=ya1, kzm1=yb1;
  const uint32_t kzr0=yc1, kzr1=yd1;

  auto GEMM = [&](const float* A, int lda, const float* B, int ldb, float* C, int ldc,
                  int M, int N, int K, const float* bias, int flags){
    k_gemm<<<dim3(N/64, (M+63)/64), dim3(256), 0, stream>>>(A, lda, B, ldb, C, ldc, M, N, K, bias, flags);
  };
  auto BGEMM = [&](const ushort* A1, int lda1, const ushort* A2, int lda2, int Ksplit,
                   const ushort* Bt, int ldb, void* C, int ldc,
                   int M, int N, int K, const float* bias, int flags){
    k_gemm_bf16<<<dim3(N/128, (M+127)/128), dim3(256), 0, stream>>>(
        A1, lda1, A2, lda2, Ksplit, Bt, ldb, C, ldc, M, N, K, bias, flags);
  };

  // ---- setup ----
  {
    int n4 = (N_RELC*N_NODESC + 2*N_NODESC + 16)/4;
    k_zero4<<<dim3((n4+255)/256), dim3(256), 0, stream>>>((float4*)zgrp, n4);
  }
  k_count<<<dim3((N_EDGESC+255)/256), dim3(256), 0, stream>>>(edge_index, edge_type, cnt, deg);
  k_scan1<<<dim3(NBLK_SCAN), dim3(256), 0, stream>>>(deg, bsum);
  k_scan2<<<dim3(1), dim3(256), 0, stream>>>(bsum, boff);
  k_scan3<<<dim3(NBLK_SCAN), dim3(256), 0, stream>>>(deg, boff, rowptr);
  k_fill2<<<dim3((N_EDGESC+255)/256), dim3(256), 0, stream>>>(edge_index, edge_type, cnt, rowptr, cursor, ep, einvc);
  k_bnd  <<<dim3((N_NODESC+255)/256), dim3(256), 0, stream>>>(batch, grow);
  {
    int total = SEG0+SEG1+SEG2+SEG3+SEG4+SEG5;
    k_prep<<<dim3((total+255)/256), dim3(256), 0, stream>>>(
        x, xb, node_W, node_Wt, gcn_Wroot, gcn_Wr, Wcat, pu_W, qz_W, pqW, out_W1, W1t, pu_b, qz_b, pqb);
  }

  // ---- input projection: curb_a = bf16(x @ node_W + node_b) ----
  BGEMM(xb, D_INC, xb, D_INC, D_INC, node_Wt, D_INC, curb_a, DC, N_NODESC, DC, D_INC, node_b, 1|2);

  // ---- RGCN layers: aggregate (CSR) then one K=1280 GEMM ----
  ushort* cur = curb_a; ushort* nxt = curb_b;
  for (int l = 0; l < N_LAYERSC; l++){
    k_agg<<<dim3((N_NODESC+3)/4), dim3(256), 0, stream>>>(cur, agg, rowptr, ep, einvc);
    int fl = 1 | 2 | ((l < N_LAYERSC-1) ? 4 : 0);
    BGEMM(cur, DC, agg, 1024, DC, Wcat + (size_t)l*DC*1280, 1280, nxt, DC,
          N_NODESC, DC, 1280, gcn_b + l*DC, fl);
    ushort* t = nxt; nxt = cur; cur = t;
  }
  // cur == final feats (bf16, no relu)

  // ---- pool + concat + relu (fp32) ----
  k_pool<<<dim3((NUM_RC+NUM_MC+3)/4), dim3(256), 0, stream>>>(cur, grow, H_R, Hrelu);

  // ---- fused pu|qz projection (fp32, accuracy-critical) ----
  GEMM(Hrelu, DC, pqW, 1024, pq, 1024, 1088, 1024, DC, pqb, 2);

  // ---- u sampling (fp32 u + bf16 rep cols 256..511) ----
  k_sample_u<<<dim3(544), dim3(256), 0, stream>>>(pq, u, repb, ku0, ku1);

  // ---- d2, A, An ----
  k_d2<<<dim3(NUM_MC), dim3(64), 0, stream>>>(u, d2);
  k_A <<<dim3(128), dim3(256), 0, stream>>>(d2, pg_ls, An, ka0, ka1);
  k_rownorm<<<dim3(NUM_MC), dim3(64), 0, stream>>>(An);

  // ---- pzcat = An @ qz[:64] (fp32) ----
  GEMM(An, NUM_RC, pq + 512, 1024, pzcat, 512, NUM_MC, 512, NUM_RC, nullptr, 0);

  // ---- z sampling + log_pqz ----
  k_sample_zM<<<dim3(512), dim3(256), 0, stream>>>(pq, zM, repb, kzm0, kzm1);
  k_logpqz<<<dim3(1024), dim3(256), 0, stream>>>(zM, pzcat, pq, scal);
  k_sample_zR<<<dim3(32), dim3(256), 0, stream>>>(pq, repb, kzr0, kzr1);

  // ---- fused output head: hid = relu(rep @ W1 + b1), then logits+loss ----
  BGEMM(repb, 512, repb, 512, 512, W1t, 512, hid, 256, NUM_RC+NUM_MC, 256, 512, out_b1, 2|4);
  k_out_head<<<dim3((NUM_RC+NUM_MC)/4), dim3(256), 0, stream>>>(hid, out_W2, out_b2, yM, yR, scal);

  // ---- reg term & final combine ----
  k_reg<<<dim3(128), dim3(256), 0, stream>>>(d2, yM, scal);
  k_final<<<dim3(1), dim3(1), 0, stream>>>(scal, out);
}

// Round 9
// 742.023 us; speedup vs baseline: 1.7539x; 1.1258x over previous
//
#include <hip/hip_runtime.h>
#include <stdint.h>

#define N_NODESC 50000
#define N_EDGESC 200000
#define D_INC 128
#define DC 256
#define N_LAYERSC 4
#define N_RELC 4
#define NUM_MC 1024
#define NUM_RC 64
#define NBLK_SCAN ((N_NODESC + 255) / 256)   // 196

typedef __attribute__((ext_vector_type(4))) float floatx4;
typedef __attribute__((ext_vector_type(8))) short short8;

// ---------------- threefry2x32 (JAX-compatible) ----------------
__host__ __device__ __forceinline__ uint32_t rotl32(uint32_t x, int r){ return (x<<r)|(x>>(32-r)); }

__host__ __device__ inline void tf2x32(uint32_t k0, uint32_t k1, uint32_t x0, uint32_t x1,
                                       uint32_t* o0, uint32_t* o1){
  uint32_t k2 = k0 ^ k1 ^ 0x1BD11BDAu;
#define TFR(r) { x0 += x1; x1 = rotl32(x1, (r)); x1 ^= x0; }
  x0 += k0; x1 += k1;
  TFR(13) TFR(15) TFR(26) TFR(6)
  x0 += k1; x1 += k2 + 1u;
  TFR(17) TFR(29) TFR(16) TFR(24)
  x0 += k2; x1 += k0 + 2u;
  TFR(13) TFR(15) TFR(26) TFR(6)
  x0 += k0; x1 += k1 + 3u;
  TFR(17) TFR(29) TFR(16) TFR(24)
  x0 += k1; x1 += k2 + 4u;
  TFR(13) TFR(15) TFR(26) TFR(6)
  x0 += k2; x1 += k0 + 5u;
#undef TFR
  *o0 = x0; *o1 = x1;
}

__device__ __forceinline__ float erfinv_f32(float x){
  float w = -log1pf(-x*x);
  float p;
  if (w < 5.0f){
    w -= 2.5f;
    p = 2.81022636e-08f;
    p = fmaf(p, w, 3.43273939e-07f);
    p = fmaf(p, w, -3.5233877e-06f);
    p = fmaf(p, w, -4.39150654e-06f);
    p = fmaf(p, w, 0.00021858087f);
    p = fmaf(p, w, -0.00125372503f);
    p = fmaf(p, w, -0.00417768164f);
    p = fmaf(p, w, 0.246640727f);
    p = fmaf(p, w, 1.50140941f);
  } else {
    w = sqrtf(w) - 3.0f;
    p = -0.000200214257f;
    p = fmaf(p, w, 0.000100950558f);
    p = fmaf(p, w, 0.00134934322f);
    p = fmaf(p, w, -0.00367342844f);
    p = fmaf(p, w, 0.00573950773f);
    p = fmaf(p, w, -0.0076224613f);
    p = fmaf(p, w, 0.00943887047f);
    p = fmaf(p, w, 1.00167406f);
    p = fmaf(p, w, 2.83297682f);
  }
  return p*x;
}

__device__ __forceinline__ float bits_to_unit(uint32_t b){
  return __uint_as_float((b >> 9) | 0x3f800000u) - 1.0f;
}

__device__ __forceinline__ float bits_to_normal(uint32_t b){
  float f = bits_to_unit(b);
  const float lo = -0.99999994f;
  float u = f * (1.0f - lo) + lo;
  u = fmaxf(u, lo);
  return 1.41421356f * erfinv_f32(u);
}

__device__ __forceinline__ float waveReduce(float v){
  #pragma unroll
  for (int m = 1; m < 64; m <<= 1) v += __shfl_xor(v, m, 64);
  return v;
}

__device__ __forceinline__ ushort f2bf(float f){
  uint32_t u = __float_as_uint(f);
  uint32_t r = u + 0x7fffu + ((u>>16)&1u);
  return (ushort)(r>>16);
}
__device__ __forceinline__ float bf2f(ushort h){
  return __uint_as_float(((uint32_t)h)<<16);
}

typedef const __attribute__((address_space(1))) void* gas_t;
typedef __attribute__((address_space(3))) void* las_t;
__device__ __forceinline__ void gld16(const void* g, void* l){
  __builtin_amdgcn_global_load_lds((gas_t)g, (las_t)l, 16, 0, 0);
}

// ---------------- setup kernels ----------------
__global__ __launch_bounds__(256) void k_zero4(float4* p, int n4){
  int i = blockIdx.x*256 + threadIdx.x;
  if (i < n4) p[i] = make_float4(0.f,0.f,0.f,0.f);
}

__global__ __launch_bounds__(256) void k_count(const int* __restrict__ ei, const int* __restrict__ et,
                                               float* __restrict__ cnt, int* __restrict__ deg){
  int e = blockIdx.x*256 + threadIdx.x;
  if (e >= N_EDGESC) return;
  int r = et[e], dstv = ei[N_EDGESC + e];
  atomicAdd(&cnt[(size_t)r*N_NODESC + dstv], 1.0f);
  atomicAdd(&deg[dstv], 1);
}

__global__ __launch_bounds__(256) void k_scan1(const int* __restrict__ deg, int* __restrict__ bsum){
  int i = blockIdx.x*256 + threadIdx.x;
  int v = (i < N_NODESC) ? deg[i] : 0;
  #pragma unroll
  for (int m = 1; m < 64; m <<= 1) v += __shfl_xor(v, m, 64);
  __shared__ int ws_[4];
  if ((threadIdx.x & 63) == 0) ws_[threadIdx.x >> 6] = v;
  __syncthreads();
  if (threadIdx.x == 0) bsum[blockIdx.x] = ws_[0]+ws_[1]+ws_[2]+ws_[3];
}

__global__ __launch_bounds__(256) void k_scan2(int* __restrict__ bsum, int* __restrict__ boff){
  __shared__ int s[256];
  int t = threadIdx.x;
  s[t] = (t < NBLK_SCAN) ? bsum[t] : 0;
  __syncthreads();
  if (t == 0){
    int run = 0;
    for (int i = 0; i < NBLK_SCAN; i++){ int v = s[i]; s[i] = run; run += v; }
  }
  __syncthreads();
  if (t < NBLK_SCAN) boff[t] = s[t];
}

__global__ __launch_bounds__(256) void k_scan3(const int* __restrict__ deg, const int* __restrict__ boff,
                                               int* __restrict__ rowptr){
  int i = blockIdx.x*256 + threadIdx.x;
  int lane = threadIdx.x & 63, w = threadIdx.x >> 6;
  int d = (i < N_NODESC) ? deg[i] : 0;
  int v = d;
  #pragma unroll
  for (int off = 1; off < 64; off <<= 1){
    int t = __shfl_up(v, off, 64);
    if (lane >= off) v += t;
  }
  __shared__ int wt[4];
  if (lane == 63) wt[w] = v;
  __syncthreads();
  int wo = 0;
  for (int k = 0; k < w; k++) wo += wt[k];
  int ex = boff[blockIdx.x] + wo + v - d;
  if (i <= N_NODESC) rowptr[i] = ex;
}

__global__ __launch_bounds__(256) void k_fill2(const int* __restrict__ ei, const int* __restrict__ et,
                                               const float* __restrict__ cnt, const int* __restrict__ rowptr,
                                               int* __restrict__ cursor, int* __restrict__ ep,
                                               float* __restrict__ einvc){
  int e = blockIdx.x*256 + threadIdx.x;
  if (e >= N_EDGESC) return;
  int src = ei[e], dstv = ei[N_EDGESC + e], r = et[e];
  int pos = rowptr[dstv] + atomicAdd(&cursor[dstv], 1);
  ep[pos] = src | (r << 16);
  einvc[pos] = 1.0f / fmaxf(cnt[(size_t)r*N_NODESC + dstv], 1.0f);
}

__global__ __launch_bounds__(256) void k_bnd(const int* __restrict__ batch, int* __restrict__ grow){
  int i = blockIdx.x*256 + threadIdx.x;
  if (i >= N_NODESC) return;
  int b = batch[i];
  if (i == 0){ for (int g = 0; g <= b; g++) grow[g] = 0; }
  else {
    int pb = batch[i-1];
    for (int g = pb+1; g <= b; g++) grow[g] = i;
  }
  if (i == N_NODESC-1){ for (int g = b+1; g <= NUM_MC; g++) grow[g] = N_NODESC; }
}

// ---- one fused prep kernel: x->bf16, all weight transposes/concats ----
#define SEG0 (N_NODESC*D_INC/4)            // x float4 -> ushort4
#define SEG1 (DC*D_INC)                    // node_Wt[n*128+k]
#define SEG2 (N_LAYERSC*DC*1280)           // Wcat[l][n(256)][k(1280)]
#define SEG3 (DC*1024)                     // pqW fp32 [k(256)][n(1024)]
#define SEG4 (DC*512)                      // W1t[n(256)][k(512)]
#define SEG5 1024                          // pqb
__global__ __launch_bounds__(256) void k_prep(const float* __restrict__ x, ushort* __restrict__ xb,
                                              const float* __restrict__ node_W, ushort* __restrict__ node_Wt,
                                              const float* __restrict__ Wroot, const float* __restrict__ Wr,
                                              ushort* __restrict__ Wcat,
                                              const float* __restrict__ pu_W, const float* __restrict__ qz_W,
                                              float* __restrict__ pqW,
                                              const float* __restrict__ out_W1, ushort* __restrict__ W1t,
                                              const float* __restrict__ pu_b, const float* __restrict__ qz_b,
                                              float* __restrict__ pqb){
  int idx = blockIdx.x*256 + threadIdx.x;
  if (idx < SEG0){
    float4 v = ((const float4*)x)[idx];
    ushort4 o; o.x=f2bf(v.x); o.y=f2bf(v.y); o.z=f2bf(v.z); o.w=f2bf(v.w);
    ((ushort4*)xb)[idx] = o;
    return;
  }
  idx -= SEG0;
  if (idx < SEG1){
    int n = idx >> 7, k = idx & 127;
    node_Wt[idx] = f2bf(node_W[(size_t)k*DC + n]);
    return;
  }
  idx -= SEG1;
  if (idx < SEG2){
    int l = idx / (DC*1280), rem = idx - l*(DC*1280);
    int n = rem / 1280, k = rem - n*1280;
    float v;
    if (k < DC) v = Wroot[((size_t)l*DC + k)*DC + n];
    else {
      int kk = k - DC, r = kk >> 8, kr = kk & 255;
      v = Wr[(((size_t)l*N_RELC + r)*DC + kr)*DC + n];
    }
    Wcat[idx] = f2bf(v);
    return;
  }
  idx -= SEG2;
  if (idx < SEG3){
    int k = idx >> 10, n = idx & 1023;
    pqW[idx] = (n < 512) ? pu_W[(size_t)k*512 + n] : qz_W[(size_t)k*512 + (n-512)];
    return;
  }
  idx -= SEG3;
  if (idx < SEG4){
    int n = idx >> 9, k = idx & 511;
    W1t[idx] = f2bf(out_W1[(size_t)k*DC + n]);
    return;
  }
  idx -= SEG4;
  if (idx < SEG5){
    pqb[idx] = (idx < 512) ? pu_b[idx] : qz_b[idx-512];
  }
}

// ---- aggregation: one wave per dst; 8-edge prefetched gather ----
__global__ __launch_bounds__(256) void k_agg(const ushort* __restrict__ curb, ushort* __restrict__ agg,
                                             const int* __restrict__ rowptr, const int* __restrict__ ep,
                                             const float* __restrict__ einvc){
  int dstv = blockIdx.x*4 + (threadIdx.x >> 6);
  if (dstv >= N_NODESC) return;
  int lane = threadIdx.x & 63;
  int beg = rowptr[dstv], end = rowptr[dstv+1];
  float4 s0 = {0,0,0,0}, s1 = {0,0,0,0}, s2 = {0,0,0,0}, s3 = {0,0,0,0};
  int p = beg;
  while (p < end){
    int nb = end - p; if (nb > 8) nb = 8;
    int pk[8]; float ic[8]; ushort4 h[8];
    #pragma unroll
    for (int j = 0; j < 8; j++) if (j < nb){ pk[j] = ep[p+j]; ic[j] = einvc[p+j]; }
    #pragma unroll
    for (int j = 0; j < 8; j++) if (j < nb)
      h[j] = *(const ushort4*)(curb + (size_t)(pk[j] & 0xffff)*DC + lane*4);
    #pragma unroll
    for (int j = 0; j < 8; j++) if (j < nb){
      float c = ic[j];
      int r = pk[j] >> 16;
      float hx = bf2f(h[j].x)*c, hy = bf2f(h[j].y)*c, hz = bf2f(h[j].z)*c, hw = bf2f(h[j].w)*c;
      if (r == 0){ s0.x+=hx; s0.y+=hy; s0.z+=hz; s0.w+=hw; }
      else if (r == 1){ s1.x+=hx; s1.y+=hy; s1.z+=hz; s1.w+=hw; }
      else if (r == 2){ s2.x+=hx; s2.y+=hy; s2.z+=hz; s2.w+=hw; }
      else { s3.x+=hx; s3.y+=hy; s3.z+=hz; s3.w+=hw; }
    }
    p += nb;
  }
  ushort* ab = agg + (size_t)dstv*1024 + lane*4;
  ushort4 o;
  o.x=f2bf(s0.x); o.y=f2bf(s0.y); o.z=f2bf(s0.z); o.w=f2bf(s0.w); *(ushort4*)(ab       ) = o;
  o.x=f2bf(s1.x); o.y=f2bf(s1.y); o.z=f2bf(s1.z); o.w=f2bf(s1.w); *(ushort4*)(ab + 256 ) = o;
  o.x=f2bf(s2.x); o.y=f2bf(s2.y); o.z=f2bf(s2.z); o.w=f2bf(s2.w); *(ushort4*)(ab + 512 ) = o;
  o.x=f2bf(s3.x); o.y=f2bf(s3.y); o.z=f2bf(s3.z); o.w=f2bf(s3.w); *(ushort4*)(ab + 768 ) = o;
}

// pooling: rows 0..63 = relu(H_R); rows 64.. = relu(segment mean of bf16 feats)
__global__ __launch_bounds__(256) void k_pool(const ushort* __restrict__ featsb, const int* __restrict__ grow,
                                              const float* __restrict__ H_R, float* __restrict__ Hrelu){
  int row = blockIdx.x*4 + (threadIdx.x >> 6);
  if (row >= NUM_RC + NUM_MC) return;
  int lane = threadIdx.x & 63;
  float4 v;
  if (row < NUM_RC){
    v = *(const float4*)(H_R + (size_t)row*DC + lane*4);
  } else {
    int g = row - NUM_RC;
    int beg = grow[g], end = grow[g+1];
    float ax=0.f, ay=0.f, az=0.f, aw=0.f;
    for (int i = beg; i < end; i++){
      const ushort4 f = *(const ushort4*)(featsb + (size_t)i*DC + lane*4);
      ax += bf2f(f.x); ay += bf2f(f.y); az += bf2f(f.z); aw += bf2f(f.w);
    }
    float ic = 1.0f / fmaxf((float)(end-beg), 1.0f);
    v.x = ax*ic; v.y = ay*ic; v.z = az*ic; v.w = aw*ic;
  }
  v.x = fmaxf(v.x,0.f); v.y = fmaxf(v.y,0.f); v.z = fmaxf(v.z,0.f); v.w = fmaxf(v.w,0.f);
  *(float4*)(Hrelu + (size_t)row*DC + lane*4) = v;
}

// ------- bf16 MFMA GEMM: BM=64, BN=128, BK=64, XOR swizzle -------
// C = [A1|A2](M x K) @ Bt(N x K)^T. flags: 1=bf16 out, 2=+bias, 4=relu
// Ksplit multiple of 64. LDS rows 128B (8 x 16B granules); granule g of
// row rr at phys slot g ^ (rr&7). Grid: (N/128, ceil(M/64)).
__global__ __launch_bounds__(256) void k_gemm_bf16(
    const ushort* __restrict__ A1, int lda1,
    const ushort* __restrict__ A2, int lda2, int Ksplit,
    const ushort* __restrict__ Bt, int ldb,
    void* __restrict__ Cout0, int ldc,
    int M, int N, int K,
    const float* __restrict__ bias, int flags)
{
  __shared__ ushort As[64*64];    // 8 KB
  __shared__ ushort Bs[128*64];   // 16 KB
  const int tid = threadIdx.x;
  const int wave = tid >> 6, lane = tid & 63;
  const int m0 = blockIdx.y * 64, n0 = blockIdx.x * 128;
  const int wn = wave * 32;       // each wave: 64 rows x 32 cols
  const int qa = lane >> 4, lm = lane & 15;

  const int lrow = lane >> 3;     // 0..7
  const int slot = lane & 7;      // 0..7

  floatx4 acc[4][2] = {};

  for (int k0 = 0; k0 < K; k0 += 64){
    const ushort* a_base; int a_ld, acol;
    if (k0 < Ksplit){ a_base = A1; a_ld = lda1; acol = k0; }
    else            { a_base = A2; a_ld = lda2; acol = k0 - Ksplit; }
    // As: 64 rows, 8 insts total -> 2 per wave (rows wave*16 .. wave*16+16)
    #pragma unroll
    for (int t = 0; t < 2; t++){
      int rb = wave*16 + t*8;
      int rr = rb + lrow;
      int gl = slot ^ (rr & 7);
      int ar = m0 + rr; if (ar > M-1) ar = M-1;
      gld16(a_base + (size_t)ar*a_ld + acol + gl*8, As + (size_t)rb*64 + lane*8);
    }
    // Bs: 128 rows, 16 insts -> 4 per wave (rows wave*32 .. wave*32+32)
    #pragma unroll
    for (int t = 0; t < 4; t++){
      int rb = wave*32 + t*8;
      int rr = rb + lrow;
      int gl = slot ^ (rr & 7);
      gld16(Bt + (size_t)(n0 + rr)*ldb + k0 + gl*8, Bs + (size_t)rb*64 + lane*8);
    }
    __syncthreads();
    #pragma unroll
    for (int kk2 = 0; kk2 < 2; kk2++){
      short8 af[4], bfv[2];
      #pragma unroll
      for (int mt = 0; mt < 4; mt++){
        int rr = mt*16 + lm;
        af[mt] = *(const short8*)(As + (size_t)rr*64 + (size_t)(((kk2*4 + qa) ^ (rr & 7)))*8);
      }
      #pragma unroll
      for (int nt = 0; nt < 2; nt++){
        int rr = wn + nt*16 + lm;
        bfv[nt] = *(const short8*)(Bs + (size_t)rr*64 + (size_t)(((kk2*4 + qa) ^ (rr & 7)))*8);
      }
      #pragma unroll
      for (int mt = 0; mt < 4; mt++)
        #pragma unroll
        for (int nt = 0; nt < 2; nt++)
          acc[mt][nt] = __builtin_amdgcn_mfma_f32_16x16x32_bf16(af[mt], bfv[nt], acc[mt][nt], 0, 0, 0);
    }
    __syncthreads();
  }

  #pragma unroll
  for (int mt = 0; mt < 4; mt++){
    #pragma unroll
    for (int i = 0; i < 4; i++){
      int row = m0 + mt*16 + qa*4 + i;
      if (row >= M) continue;
      #pragma unroll
      for (int nt = 0; nt < 2; nt++){
        int col = n0 + wn + nt*16 + lm;
        float v = acc[mt][nt][i];
        if (flags & 2) v += bias[col];
        if (flags & 4) v = fmaxf(v, 0.0f);
        if (flags & 1)
          ((ushort*)Cout0)[(size_t)row*ldc + col] = f2bf(v);
        else
          ((float*)Cout0)[(size_t)row*ldc + col] = v;
      }
    }
  }
}

// ---------------- fp32 GEMM (small/accuracy-critical) ----------------
__global__ __launch_bounds__(256) void k_gemm(
    const float* __restrict__ A, int lda,
    const float* __restrict__ B, int ldb,
    float* __restrict__ C, int ldc,
    int M, int N, int K,
    const float* __restrict__ bias, int flags)
{
  __shared__ __align__(16) float Asm[64][36];
  __shared__ __align__(16) float Bsm[32][64];
  const int tid = threadIdx.x;
  const int tx = tid & 15, ty = tid >> 4;
  const int m0 = blockIdx.y * 64, n0 = blockIdx.x * 64;
  const int am = tid >> 2, ak = (tid & 3) * 8;
  const int bk = tid >> 3, bn = (tid & 7) * 8;
  float acc[4][4] = {};
  for (int k0 = 0; k0 < K; k0 += 32){
    float4 a0, a1;
    int arow = m0 + am;
    if (arow < M){
      const float* ap = A + (size_t)arow*lda + (k0 + ak);
      a0 = *(const float4*)ap;
      a1 = *(const float4*)(ap + 4);
    } else {
      a0 = make_float4(0,0,0,0); a1 = a0;
    }
    const float* bp = B + (size_t)(k0 + bk)*ldb + (n0 + bn);
    float4 b0v = *(const float4*)bp;
    float4 b1v = *(const float4*)(bp + 4);
    *(float4*)&Asm[am][ak]   = a0;
    *(float4*)&Asm[am][ak+4] = a1;
    *(float4*)&Bsm[bk][bn]   = b0v;
    *(float4*)&Bsm[bk][bn+4] = b1v;
    __syncthreads();
    #pragma unroll
    for (int kk = 0; kk < 32; ++kk){
      float av[4], bv[4];
      #pragma unroll
      for (int i=0;i<4;i++) av[i] = Asm[ty*4+i][kk];
      #pragma unroll
      for (int j=0;j<4;j++) bv[j] = Bsm[kk][tx*4+j];
      #pragma unroll
      for (int i=0;i<4;i++)
        #pragma unroll
        for (int j=0;j<4;j++)
          acc[i][j] = fmaf(av[i], bv[j], acc[i][j]);
    }
    __syncthreads();
  }
  #pragma unroll
  for (int i=0;i<4;i++){
    int row = m0 + ty*4 + i;
    if (row >= M) continue;
    #pragma unroll
    for (int j=0;j<4;j++){
      int col = n0 + tx*4 + j;
      float v = acc[i][j];
      if (flags & 2) v += bias[col];
      if (flags & 4) v = fmaxf(v, 0.0f);
      C[(size_t)row*ldc + col] = v;
    }
  }
}

// ---------------- sampling & head kernels ----------------
// pq layout per row (1024): [pu_mean(256) | pu_ls(256) | qz_mean(256) | qz_ls(256)]
__global__ __launch_bounds__(256) void k_sample_u(const float* __restrict__ pq, float* __restrict__ u,
                                                  ushort* __restrict__ repb,
                                                  uint32_t k0, uint32_t k1){
  const int half = (1088*DC)/2;
  int j = blockIdx.x*256 + threadIdx.x;
  if (j >= half) return;
  uint32_t o0, o1;
  tf2x32(k0, k1, (uint32_t)j, (uint32_t)(j + half), &o0, &o1);
  #pragma unroll
  for (int t = 0; t < 2; t++){
    int i = j + t*half;
    uint32_t bits = t ? o1 : o0;
    int row = i >> 8, col = i & 255;
    const float* pr = pq + (size_t)row*1024;
    float val = pr[col] + expf(pr[256 + col]) * bits_to_normal(bits);
    u[i] = val;
    repb[(size_t)row*512 + 256 + col] = f2bf(val);
  }
}

__global__ __launch_bounds__(256) void k_sample_zM(const float* __restrict__ pq, float* __restrict__ zM,
                                                   ushort* __restrict__ repb,
                                                   uint32_t k0, uint32_t k1){
  const int half = (NUM_MC*DC)/2;
  int j = blockIdx.x*256 + threadIdx.x;
  if (j >= half) return;
  uint32_t o0, o1;
  tf2x32(k0, k1, (uint32_t)j, (uint32_t)(j + half), &o0, &o1);
  #pragma unroll
  for (int t = 0; t < 2; t++){
    int i = j + t*half;
    uint32_t bits = t ? o1 : o0;
    int m = i >> 8, col = i & 255;
    const float* pr = pq + (size_t)(NUM_RC + m)*1024;
    float val = pr[512 + col] + expf(pr[768 + col]) * bits_to_normal(bits);
    zM[i] = val;
    repb[(size_t)(NUM_RC + m)*512 + col] = f2bf(val);
  }
}

__global__ __launch_bounds__(256) void k_sample_zR(const float* __restrict__ pq, ushort* __restrict__ repb,
                                                   uint32_t k0, uint32_t k1){
  const int half = (NUM_RC*DC)/2;
  int j = blockIdx.x*256 + threadIdx.x;
  if (j >= half) return;
  uint32_t o0, o1;
  tf2x32(k0, k1, (uint32_t)j, (uint32_t)(j + half), &o0, &o1);
  #pragma unroll
  for (int t = 0; t < 2; t++){
    int i = j + t*half;
    uint32_t bits = t ? o1 : o0;
    int r = i >> 8, col = i & 255;
    const float* pr = pq + (size_t)r*1024;
    float val = pr[512 + col] + expf(pr[768 + col]) * bits_to_normal(bits);
    repb[(size_t)r*512 + col] = f2bf(val);
  }
}

__global__ __launch_bounds__(64) void k_d2(const float* __restrict__ u, float* __restrict__ d2){
  int m = blockIdx.x, r = threadIdx.x;
  const float4* um = (const float4*)(u + (size_t)(NUM_RC + m)*DC);
  const float4* ur = (const float4*)(u + (size_t)r*DC);
  float s = 0.f;
  #pragma unroll 4
  for (int d = 0; d < DC/4; ++d){
    float4 a = um[d], b = ur[d];
    float dx = a.x-b.x, dy = a.y-b.y, dz = a.z-b.z, dw = a.w-b.w;
    s = fmaf(dx,dx, fmaf(dy,dy, fmaf(dz,dz, fmaf(dw,dw, s))));
  }
  d2[m*NUM_RC + r] = s;
}

__device__ __forceinline__ void A_elem(float* An, const float* d2, int i, uint32_t bits, float inv_s){
  float logp = -0.5f * d2[i] * inv_s;
  float la = logp - logf(fmaxf(-expm1f(logp), 1e-20f));
  float f = bits_to_unit(bits);
  const float mn = 1e-6f, mx = 0.999999f;
  float U = fmaxf(f*(mx-mn) + mn, mn);
  float g = (la + logf(U) - log1pf(-U)) / 0.3f;
  An[i] = 1.0f / (1.0f + expf(-g));
}

__global__ __launch_bounds__(256) void k_A(const float* __restrict__ d2, const float* __restrict__ pg,
                                           float* __restrict__ An, uint32_t k0, uint32_t k1){
  const int HALF = (NUM_MC*NUM_RC)/2;
  int j = blockIdx.x*256 + threadIdx.x;
  if (j >= HALF) return;
  uint32_t o0, o1;
  tf2x32(k0, k1, (uint32_t)j, (uint32_t)(j + HALF), &o0, &o1);
  float inv_s = expf(-pg[0]);
  A_elem(An, d2, j, o0, inv_s);
  A_elem(An, d2, j + HALF, o1, inv_s);
}

__global__ __launch_bounds__(64) void k_rownorm(float* __restrict__ An){
  int m = blockIdx.x, r = threadIdx.x;
  float v = An[m*NUM_RC + r];
  float s = waveReduce(v);
  An[m*NUM_RC + r] = v / (s + 1e-8f);
}

__global__ __launch_bounds__(256) void k_logpqz(const float* __restrict__ zM, const float* __restrict__ pzcat,
                                                const float* __restrict__ pq, float* __restrict__ scal){
  int idx = blockIdx.x*256 + threadIdx.x;
  int m = idx >> 8, d = idx & 255;
  float z  = zM[idx];
  float pm = pzcat[(size_t)m*512 + d];
  float pl = pzcat[(size_t)m*512 + 256 + d];
  const float* qrow = pq + (size_t)(NUM_RC + m)*1024;
  float qm = qrow[512 + d], ql = qrow[768 + d];
  float tp = (z - pm) * expf(-pl);
  float tq = (z - qm) * expf(-ql);
  float term = (-pl - 0.5f*tp*tp) - (-ql - 0.5f*tq*tq);
  float s = waveReduce(term);
  if ((threadIdx.x & 63) == 0) atomicAdd(&scal[0], s);
}

// fused: rows 0..63 -> rationale (scal[2], yR); rows 64..1087 -> prediction (scal[1], yM)
__global__ __launch_bounds__(256) void k_out_head(const float* __restrict__ hid, const float* __restrict__ W2,
                                                  const float* __restrict__ b2, const int* __restrict__ yM,
                                                  const int* __restrict__ yR, float* __restrict__ scal){
  int wave = threadIdx.x >> 6, lane = threadIdx.x & 63;
  int row = blockIdx.x*4 + wave;
  if (row >= NUM_RC + NUM_MC) return;
  const float* h = hid + (size_t)row*256;
  float p0 = 0.f, p1 = 0.f;
  #pragma unroll
  for (int c = 0; c < 4; c++){
    int d = lane*4 + c;
    float hv = h[d];
    p0 = fmaf(hv, W2[d*2+0], p0);
    p1 = fmaf(hv, W2[d*2+1], p1);
  }
  p0 = waveReduce(p0);
  p1 = waveReduce(p1);
  if (lane == 0){
    float l0 = p0 + b2[0], l1 = p1 + b2[1];
    float mx = fmaxf(l0, l1);
    float lse = mx + logf(expf(l0-mx) + expf(l1-mx));
    int y = (row < NUM_RC) ? yR[row] : yM[row - NUM_RC];
    float lp = ((y == 0) ? l0 : l1) - lse;
    atomicAdd((row < NUM_RC) ? &scal[2] : &scal[1], lp);
  }
}

__global__ __launch_bounds__(256) void k_reg(const float* __restrict__ d2, const int* __restrict__ yM,
                                             float* __restrict__ scal){
  int t = blockIdx.x*256 + threadIdx.x;
  float v = 0.f;
  if (t < 32*1024){
    int i = t >> 10, m = t & 1023;
    int col = i + (1 - yM[m]) * 32;
    v = sqrtf(fmaxf(d2[m*NUM_RC + col], 1e-12f));
  }
  float s = waveReduce(v);
  if ((threadIdx.x & 63) == 0) atomicAdd(&scal[3], s);
}

__global__ void k_final(const float* __restrict__ scal, float* __restrict__ out){
  float pred = -(scal[1] + 0.1f*scal[0]) / 1024.0f;
  float rat  = -scal[2] / 64.0f;
  float regm = scal[3] / 32768.0f;
  out[0] = pred + rat - 0.1f*regm;
}

// ---------------- launch ----------------
extern "C" void kernel_launch(void* const* d_in, const int* in_sizes, int n_in,
                              void* d_out, int out_size, void* d_ws, size_t ws_size,
                              hipStream_t stream) {
  const float* x         = (const float*)d_in[0];
  const int*   edge_index= (const int*)  d_in[1];
  const int*   edge_type = (const int*)  d_in[2];
  const int*   batch     = (const int*)  d_in[3];
  const int*   yM        = (const int*)  d_in[4];
  const int*   yR        = (const int*)  d_in[5];
  const float* H_R       = (const float*)d_in[6];
  const float* node_W    = (const float*)d_in[7];
  const float* node_b    = (const float*)d_in[8];
  const float* gcn_Wr    = (const float*)d_in[9];
  const float* gcn_Wroot = (const float*)d_in[10];
  const float* gcn_b     = (const float*)d_in[11];
  const float* pg_ls     = (const float*)d_in[12];
  const float* pu_W      = (const float*)d_in[13];
  const float* pu_b      = (const float*)d_in[14];
  const float* qz_W      = (const float*)d_in[15];
  const float* qz_b      = (const float*)d_in[16];
  const float* out_W1    = (const float*)d_in[17];
  const float* out_b1    = (const float*)d_in[18];
  const float* out_W2    = (const float*)d_in[19];
  const float* out_b2    = (const float*)d_in[20];
  float* out = (float*)d_out;

  char* base = (char*)d_ws;
  size_t off = 0;
  auto ALLOC = [&](size_t nbytes)->void*{
    void* p = base + off; off += (nbytes + 255) & ~(size_t)255; return p;
  };
  ushort* curb_a  = (ushort*)ALLOC((size_t)N_NODESC*DC*2);
  ushort* curb_b  = (ushort*)ALLOC((size_t)N_NODESC*DC*2);
  ushort* agg     = (ushort*)ALLOC((size_t)N_NODESC*1024*2);
  ushort* xb      = (ushort*)ALLOC((size_t)N_NODESC*D_INC*2);
  ushort* node_Wt = (ushort*)ALLOC((size_t)SEG1*2);
  ushort* Wcat    = (ushort*)ALLOC((size_t)SEG2*2);
  float*  pqW     = (float*) ALLOC((size_t)SEG3*4);
  ushort* W1t     = (ushort*)ALLOC((size_t)SEG4*2);
  float*  pqb     = (float*) ALLOC((size_t)SEG5*4);
  // contiguous zero group: cnt | deg | cursor | scal
  float*  zgrp    = (float*) ALLOC((size_t)(N_RELC*N_NODESC + N_NODESC + N_NODESC + 16)*4);
  float*  cnt     = zgrp;
  int*    deg     = (int*)(cnt + (size_t)N_RELC*N_NODESC);
  int*    cursor  = deg + N_NODESC;
  float*  scal    = (float*)(cursor + N_NODESC);
  int*    rowptr  = (int*)   ALLOC((size_t)(N_NODESC+1)*4);
  int*    bsum    = (int*)   ALLOC((size_t)NBLK_SCAN*4);
  int*    boff    = (int*)   ALLOC((size_t)NBLK_SCAN*4);
  int*    ep      = (int*)   ALLOC((size_t)N_EDGESC*4);
  float*  einvc   = (float*) ALLOC((size_t)N_EDGESC*4);
  int*    grow    = (int*)   ALLOC((size_t)(NUM_MC+1)*4);
  float*  Hrelu   = (float*) ALLOC((size_t)1088*DC*4);
  float*  pq      = (float*) ALLOC((size_t)1088*1024*4);
  float*  u       = (float*) ALLOC((size_t)1088*DC*4);
  ushort* repb    = (ushort*)ALLOC((size_t)1088*512*2);
  float*  zM      = (float*) ALLOC((size_t)NUM_MC*DC*4);
  float*  d2      = (float*) ALLOC((size_t)NUM_MC*NUM_RC*4);
  float*  An      = (float*) ALLOC((size_t)NUM_MC*NUM_RC*4);
  float*  pzcat   = (float*) ALLOC((size_t)NUM_MC*512*4);
  float*  hid     = (float*) ALLOC((size_t)1088*256*4);
  (void)ws_size; (void)in_sizes; (void)n_in; (void)out_size;

  uint32_t ya0,ya1,yb0,yb1,yc0,yc1,yd0,yd1;
  tf2x32(0u,42u, 0u,4u, &ya0,&ya1);
  tf2x32(0u,42u, 1u,5u, &yb0,&yb1);
  tf2x32(0u,42u, 2u,6u, &yc0,&yc1);
  tf2x32(0u,42u, 3u,7u, &yd0,&yd1);
  const uint32_t ku0=ya0,  ku1=yb0;
  const uint32_t ka0=yc0,  ka1=yd0;
  const uint32_t kzm0=ya1, kzm1=yb1;
  const uint32_t kzr0=yc1, kzr1=yd1;

  auto GEMM = [&](const float* A, int lda, const float* B, int ldb, float* C, int ldc,
                  int M, int N, int K, const float* bias, int flags){
    k_gemm<<<dim3(N/64, (M+63)/64), dim3(256), 0, stream>>>(A, lda, B, ldb, C, ldc, M, N, K, bias, flags);
  };
  auto BGEMM = [&](const ushort* A1, int lda1, const ushort* A2, int lda2, int Ksplit,
                   const ushort* Bt, int ldb, void* C, int ldc,
                   int M, int N, int K, const float* bias, int flags){
    k_gemm_bf16<<<dim3(N/128, (M+63)/64), dim3(256), 0, stream>>>(
        A1, lda1, A2, lda2, Ksplit, Bt, ldb, C, ldc, M, N, K, bias, flags);
  };

  // ---- setup ----
  {
    int n4 = (N_RELC*N_NODESC + 2*N_NODESC + 16)/4;
    k_zero4<<<dim3((n4+255)/256), dim3(256), 0, stream>>>((float4*)zgrp, n4);
  }
  k_count<<<dim3((N_EDGESC+255)/256), dim3(256), 0, stream>>>(edge_index, edge_type, cnt, deg);
  k_scan1<<<dim3(NBLK_SCAN), dim3(256), 0, stream>>>(deg, bsum);
  k_scan2<<<dim3(1), dim3(256), 0, stream>>>(bsum, boff);
  k_scan3<<<dim3(NBLK_SCAN), dim3(256), 0, stream>>>(deg, boff, rowptr);
  k_fill2<<<dim3((N_EDGESC+255)/256), dim3(256), 0, stream>>>(edge_index, edge_type, cnt, rowptr, cursor, ep, einvc);
  k_bnd  <<<dim3((N_NODESC+255)/256), dim3(256), 0, stream>>>(batch, grow);
  {
    int total = SEG0+SEG1+SEG2+SEG3+SEG4+SEG5;
    k_prep<<<dim3((total+255)/256), dim3(256), 0, stream>>>(
        x, xb, node_W, node_Wt, gcn_Wroot, gcn_Wr, Wcat, pu_W, qz_W, pqW, out_W1, W1t, pu_b, qz_b, pqb);
  }

  // ---- input projection: curb_a = bf16(x @ node_W + node_b) ----
  BGEMM(xb, D_INC, xb, D_INC, D_INC, node_Wt, D_INC, curb_a, DC, N_NODESC, DC, D_INC, node_b, 1|2);

  // ---- RGCN layers: aggregate (CSR) then one K=1280 GEMM ----
  ushort* cur = curb_a; ushort* nxt = curb_b;
  for (int l = 0; l < N_LAYERSC; l++){
    k_agg<<<dim3((N_NODESC+3)/4), dim3(256), 0, stream>>>(cur, agg, rowptr, ep, einvc);
    int fl = 1 | 2 | ((l < N_LAYERSC-1) ? 4 : 0);
    BGEMM(cur, DC, agg, 1024, DC, Wcat + (size_t)l*DC*1280, 1280, nxt, DC,
          N_NODESC, DC, 1280, gcn_b + l*DC, fl);
    ushort* t = nxt; nxt = cur; cur = t;
  }
  // cur == final feats (bf16, no relu)

  // ---- pool + concat + relu (fp32) ----
  k_pool<<<dim3((NUM_RC+NUM_MC+3)/4), dim3(256), 0, stream>>>(cur, grow, H_R, Hrelu);

  // ---- fused pu|qz projection (fp32, accuracy-critical) ----
  GEMM(Hrelu, DC, pqW, 1024, pq, 1024, 1088, 1024, DC, pqb, 2);

  // ---- u sampling (fp32 u + bf16 rep cols 256..511) ----
  k_sample_u<<<dim3(544), dim3(256), 0, stream>>>(pq, u, repb, ku0, ku1);

  // ---- d2, A, An ----
  k_d2<<<dim3(NUM_MC), dim3(64), 0, stream>>>(u, d2);
  k_A <<<dim3(128), dim3(256), 0, stream>>>(d2, pg_ls, An, ka0, ka1);
  k_rownorm<<<dim3(NUM_MC), dim3(64), 0, stream>>>(An);

  // ---- pzcat = An @ qz[:64] (fp32) ----
  GEMM(An, NUM_RC, pq + 512, 1024, pzcat, 512, NUM_MC, 512, NUM_RC, nullptr, 0);

  // ---- z sampling + log_pqz ----
  k_sample_zM<<<dim3(512), dim3(256), 0, stream>>>(pq, zM, repb, kzm0, kzm1);
  k_logpqz<<<dim3(1024), dim3(256), 0, stream>>>(zM, pzcat, pq, scal);
  k_sample_zR<<<dim3(32), dim3(256), 0, stream>>>(pq, repb, kzr0, kzr1);

  // ---- fused output head: hid = relu(rep @ W1 + b1), then logits+loss ----
  BGEMM(repb, 512, repb, 512, 512, W1t, 512, hid, 256, NUM_RC+NUM_MC, 256, 512, out_b1, 2|4);
  k_out_head<<<dim3((NUM_RC+NUM_MC)/4), dim3(256), 0, stream>>>(hid, out_W2, out_b2, yM, yR, scal);

  // ---- reg term & final combine ----
  k_reg<<<dim3(128), dim3(256), 0, stream>>>(d2, yM, scal);
  k_final<<<dim3(1), dim3(1), 0, stream>>>(scal, out);
}

// Round 10
// 707.818 us; speedup vs baseline: 1.8386x; 1.0483x over previous
//
#include <hip/hip_runtime.h>
#include <stdint.h>

#define N_NODESC 50000
#define N_EDGESC 200000
#define D_INC 128
#define DC 256
#define N_LAYERSC 4
#define N_RELC 4
#define NUM_MC 1024
#define NUM_RC 64
#define NBLK_SCAN ((N_NODESC + 255) / 256)   // 196

typedef __attribute__((ext_vector_type(4))) float floatx4;
typedef __attribute__((ext_vector_type(8))) short short8;

// ---------------- threefry2x32 (JAX-compatible) ----------------
__host__ __device__ __forceinline__ uint32_t rotl32(uint32_t x, int r){ return (x<<r)|(x>>(32-r)); }

__host__ __device__ inline void tf2x32(uint32_t k0, uint32_t k1, uint32_t x0, uint32_t x1,
                                       uint32_t* o0, uint32_t* o1){
  uint32_t k2 = k0 ^ k1 ^ 0x1BD11BDAu;
#define TFR(r) { x0 += x1; x1 = rotl32(x1, (r)); x1 ^= x0; }
  x0 += k0; x1 += k1;
  TFR(13) TFR(15) TFR(26) TFR(6)
  x0 += k1; x1 += k2 + 1u;
  TFR(17) TFR(29) TFR(16) TFR(24)
  x0 += k2; x1 += k0 + 2u;
  TFR(13) TFR(15) TFR(26) TFR(6)
  x0 += k0; x1 += k1 + 3u;
  TFR(17) TFR(29) TFR(16) TFR(24)
  x0 += k1; x1 += k2 + 4u;
  TFR(13) TFR(15) TFR(26) TFR(6)
  x0 += k2; x1 += k0 + 5u;
#undef TFR
  *o0 = x0; *o1 = x1;
}

__device__ __forceinline__ float erfinv_f32(float x){
  float w = -log1pf(-x*x);
  float p;
  if (w < 5.0f){
    w -= 2.5f;
    p = 2.81022636e-08f;
    p = fmaf(p, w, 3.43273939e-07f);
    p = fmaf(p, w, -3.5233877e-06f);
    p = fmaf(p, w, -4.39150654e-06f);
    p = fmaf(p, w, 0.00021858087f);
    p = fmaf(p, w, -0.00125372503f);
    p = fmaf(p, w, -0.00417768164f);
    p = fmaf(p, w, 0.246640727f);
    p = fmaf(p, w, 1.50140941f);
  } else {
    w = sqrtf(w) - 3.0f;
    p = -0.000200214257f;
    p = fmaf(p, w, 0.000100950558f);
    p = fmaf(p, w, 0.00134934322f);
    p = fmaf(p, w, -0.00367342844f);
    p = fmaf(p, w, 0.00573950773f);
    p = fmaf(p, w, -0.0076224613f);
    p = fmaf(p, w, 0.00943887047f);
    p = fmaf(p, w, 1.00167406f);
    p = fmaf(p, w, 2.83297682f);
  }
  return p*x;
}

__device__ __forceinline__ float bits_to_unit(uint32_t b){
  return __uint_as_float((b >> 9) | 0x3f800000u) - 1.0f;
}

__device__ __forceinline__ float bits_to_normal(uint32_t b){
  float f = bits_to_unit(b);
  const float lo = -0.99999994f;
  float u = f * (1.0f - lo) + lo;
  u = fmaxf(u, lo);
  return 1.41421356f * erfinv_f32(u);
}

__device__ __forceinline__ float waveReduce(float v){
  #pragma unroll
  for (int m = 1; m < 64; m <<= 1) v += __shfl_xor(v, m, 64);
  return v;
}

__device__ __forceinline__ ushort f2bf(float f){
  uint32_t u = __float_as_uint(f);
  uint32_t r = u + 0x7fffu + ((u>>16)&1u);
  return (ushort)(r>>16);
}
__device__ __forceinline__ float bf2f(ushort h){
  return __uint_as_float(((uint32_t)h)<<16);
}

typedef const __attribute__((address_space(1))) void* gas_t;
typedef __attribute__((address_space(3))) void* las_t;
__device__ __forceinline__ void gld16(const void* g, void* l){
  __builtin_amdgcn_global_load_lds((gas_t)g, (las_t)l, 16, 0, 0);
}

// ---------------- setup kernels ----------------
__global__ __launch_bounds__(256) void k_zero4(float4* p, int n4){
  int i = blockIdx.x*256 + threadIdx.x;
  if (i < n4) p[i] = make_float4(0.f,0.f,0.f,0.f);
}

__global__ __launch_bounds__(256) void k_count(const int* __restrict__ ei, const int* __restrict__ et,
                                               float* __restrict__ cnt, int* __restrict__ deg){
  int e = blockIdx.x*256 + threadIdx.x;
  if (e >= N_EDGESC) return;
  int r = et[e], dstv = ei[N_EDGESC + e];
  atomicAdd(&cnt[(size_t)r*N_NODESC + dstv], 1.0f);
  atomicAdd(&deg[dstv], 1);
}

__global__ __launch_bounds__(256) void k_scan1(const int* __restrict__ deg, int* __restrict__ bsum){
  int i = blockIdx.x*256 + threadIdx.x;
  int v = (i < N_NODESC) ? deg[i] : 0;
  #pragma unroll
  for (int m = 1; m < 64; m <<= 1) v += __shfl_xor(v, m, 64);
  __shared__ int ws_[4];
  if ((threadIdx.x & 63) == 0) ws_[threadIdx.x >> 6] = v;
  __syncthreads();
  if (threadIdx.x == 0) bsum[blockIdx.x] = ws_[0]+ws_[1]+ws_[2]+ws_[3];
}

__global__ __launch_bounds__(256) void k_scan2(int* __restrict__ bsum, int* __restrict__ boff){
  __shared__ int s[256];
  int t = threadIdx.x;
  s[t] = (t < NBLK_SCAN) ? bsum[t] : 0;
  __syncthreads();
  if (t == 0){
    int run = 0;
    for (int i = 0; i < NBLK_SCAN; i++){ int v = s[i]; s[i] = run; run += v; }
  }
  __syncthreads();
  if (t < NBLK_SCAN) boff[t] = s[t];
}

__global__ __launch_bounds__(256) void k_scan3(const int* __restrict__ deg, const int* __restrict__ boff,
                                               int* __restrict__ rowptr){
  int i = blockIdx.x*256 + threadIdx.x;
  int lane = threadIdx.x & 63, w = threadIdx.x >> 6;
  int d = (i < N_NODESC) ? deg[i] : 0;
  int v = d;
  #pragma unroll
  for (int off = 1; off < 64; off <<= 1){
    int t = __shfl_up(v, off, 64);
    if (lane >= off) v += t;
  }
  __shared__ int wt[4];
  if (lane == 63) wt[w] = v;
  __syncthreads();
  int wo = 0;
  for (int k = 0; k < w; k++) wo += wt[k];
  int ex = boff[blockIdx.x] + wo + v - d;
  if (i <= N_NODESC) rowptr[i] = ex;
}

__global__ __launch_bounds__(256) void k_fill2(const int* __restrict__ ei, const int* __restrict__ et,
                                               const float* __restrict__ cnt, const int* __restrict__ rowptr,
                                               int* __restrict__ cursor, int* __restrict__ ep,
                                               float* __restrict__ einvc){
  int e = blockIdx.x*256 + threadIdx.x;
  if (e >= N_EDGESC) return;
  int src = ei[e], dstv = ei[N_EDGESC + e], r = et[e];
  int pos = rowptr[dstv] + atomicAdd(&cursor[dstv], 1);
  ep[pos] = src | (r << 16);
  einvc[pos] = 1.0f / fmaxf(cnt[(size_t)r*N_NODESC + dstv], 1.0f);
}

__global__ __launch_bounds__(256) void k_bnd(const int* __restrict__ batch, int* __restrict__ grow){
  int i = blockIdx.x*256 + threadIdx.x;
  if (i >= N_NODESC) return;
  int b = batch[i];
  if (i == 0){ for (int g = 0; g <= b; g++) grow[g] = 0; }
  else {
    int pb = batch[i-1];
    for (int g = pb+1; g <= b; g++) grow[g] = i;
  }
  if (i == N_NODESC-1){ for (int g = b+1; g <= NUM_MC; g++) grow[g] = N_NODESC; }
}

// ---- one fused prep kernel: x->bf16, all weight transposes/concats ----
#define SEG0 (N_NODESC*D_INC/4)            // x float4 -> ushort4
#define SEG1 (DC*D_INC)                    // node_Wt[n*128+k]
#define SEG2 (N_LAYERSC*DC*1280)           // Wcat[l][n(256)][k(1280)]
#define SEG3 (DC*1024)                     // pqW fp32 [k(256)][n(1024)]
#define SEG4 (DC*512)                      // W1t[n(256)][k(512)]
#define SEG5 1024                          // pqb
__global__ __launch_bounds__(256) void k_prep(const float* __restrict__ x, ushort* __restrict__ xb,
                                              const float* __restrict__ node_W, ushort* __restrict__ node_Wt,
                                              const float* __restrict__ Wroot, const float* __restrict__ Wr,
                                              ushort* __restrict__ Wcat,
                                              const float* __restrict__ pu_W, const float* __restrict__ qz_W,
                                              float* __restrict__ pqW,
                                              const float* __restrict__ out_W1, ushort* __restrict__ W1t,
                                              const float* __restrict__ pu_b, const float* __restrict__ qz_b,
                                              float* __restrict__ pqb){
  int idx = blockIdx.x*256 + threadIdx.x;
  if (idx < SEG0){
    float4 v = ((const float4*)x)[idx];
    ushort4 o; o.x=f2bf(v.x); o.y=f2bf(v.y); o.z=f2bf(v.z); o.w=f2bf(v.w);
    ((ushort4*)xb)[idx] = o;
    return;
  }
  idx -= SEG0;
  if (idx < SEG1){
    int n = idx >> 7, k = idx & 127;
    node_Wt[idx] = f2bf(node_W[(size_t)k*DC + n]);
    return;
  }
  idx -= SEG1;
  if (idx < SEG2){
    int l = idx / (DC*1280), rem = idx - l*(DC*1280);
    int n = rem / 1280, k = rem - n*1280;
    float v;
    if (k < DC) v = Wroot[((size_t)l*DC + k)*DC + n];
    else {
      int kk = k - DC, r = kk >> 8, kr = kk & 255;
      v = Wr[(((size_t)l*N_RELC + r)*DC + kr)*DC + n];
    }
    Wcat[idx] = f2bf(v);
    return;
  }
  idx -= SEG2;
  if (idx < SEG3){
    int k = idx >> 10, n = idx & 1023;
    pqW[idx] = (n < 512) ? pu_W[(size_t)k*512 + n] : qz_W[(size_t)k*512 + (n-512)];
    return;
  }
  idx -= SEG3;
  if (idx < SEG4){
    int n = idx >> 9, k = idx & 511;
    W1t[idx] = f2bf(out_W1[(size_t)k*DC + n]);
    return;
  }
  idx -= SEG4;
  if (idx < SEG5){
    pqb[idx] = (idx < 512) ? pu_b[idx] : qz_b[idx-512];
  }
}

// ---- aggregation: 2 dsts per wave (32-lane halves, ushort8/lane), 8-edge ILP ----
__global__ __launch_bounds__(256) void k_agg(const ushort* __restrict__ curb, ushort* __restrict__ agg,
                                             const int* __restrict__ rowptr, const int* __restrict__ ep,
                                             const float* __restrict__ einvc){
  int halfid = threadIdx.x >> 5;           // 0..7
  int dstv = blockIdx.x*8 + halfid;
  if (dstv >= N_NODESC) return;
  int lane = threadIdx.x & 31;             // 32 lanes cover 256 cols as 8 each
  int beg = rowptr[dstv], end = rowptr[dstv+1];
  float s0[8] = {}, s1[8] = {}, s2[8] = {}, s3[8] = {};
  int p = beg;
  while (p < end){
    int nb = end - p; if (nb > 8) nb = 8;
    int pk[8]; float ic[8]; short8 h[8];
    #pragma unroll
    for (int j = 0; j < 8; j++) if (j < nb){ pk[j] = ep[p+j]; ic[j] = einvc[p+j]; }
    #pragma unroll
    for (int j = 0; j < 8; j++) if (j < nb)
      h[j] = *(const short8*)(curb + (size_t)(pk[j] & 0xffff)*DC + lane*8);
    #pragma unroll
    for (int j = 0; j < 8; j++) if (j < nb){
      float c = ic[j];
      int r = pk[j] >> 16;
      if (r == 0){
        #pragma unroll
        for (int e = 0; e < 8; e++) s0[e] = fmaf(bf2f((ushort)h[j][e]), c, s0[e]);
      } else if (r == 1){
        #pragma unroll
        for (int e = 0; e < 8; e++) s1[e] = fmaf(bf2f((ushort)h[j][e]), c, s1[e]);
      } else if (r == 2){
        #pragma unroll
        for (int e = 0; e < 8; e++) s2[e] = fmaf(bf2f((ushort)h[j][e]), c, s2[e]);
      } else {
        #pragma unroll
        for (int e = 0; e < 8; e++) s3[e] = fmaf(bf2f((ushort)h[j][e]), c, s3[e]);
      }
    }
    p += nb;
  }
  ushort* ab = agg + (size_t)dstv*1024 + lane*8;
  short8 o;
  #pragma unroll
  for (int e = 0; e < 8; e++) o[e] = (short)f2bf(s0[e]);
  *(short8*)(ab      ) = o;
  #pragma unroll
  for (int e = 0; e < 8; e++) o[e] = (short)f2bf(s1[e]);
  *(short8*)(ab + 256) = o;
  #pragma unroll
  for (int e = 0; e < 8; e++) o[e] = (short)f2bf(s2[e]);
  *(short8*)(ab + 512) = o;
  #pragma unroll
  for (int e = 0; e < 8; e++) o[e] = (short)f2bf(s3[e]);
  *(short8*)(ab + 768) = o;
}

// pooling: rows 0..63 = relu(H_R); rows 64.. = relu(segment mean), 4-row ILP
__global__ __launch_bounds__(256) void k_pool(const ushort* __restrict__ featsb, const int* __restrict__ grow,
                                              const float* __restrict__ H_R, float* __restrict__ Hrelu){
  int row = blockIdx.x*4 + (threadIdx.x >> 6);
  if (row >= NUM_RC + NUM_MC) return;
  int lane = threadIdx.x & 63;
  float4 v;
  if (row < NUM_RC){
    v = *(const float4*)(H_R + (size_t)row*DC + lane*4);
  } else {
    int g = row - NUM_RC;
    int beg = grow[g], end = grow[g+1];
    float ax=0.f, ay=0.f, az=0.f, aw=0.f;
    int i = beg;
    while (i < end){
      int nb = end - i; if (nb > 4) nb = 4;
      ushort4 f[4];
      #pragma unroll
      for (int j = 0; j < 4; j++) if (j < nb)
        f[j] = *(const ushort4*)(featsb + (size_t)(i+j)*DC + lane*4);
      #pragma unroll
      for (int j = 0; j < 4; j++) if (j < nb){
        ax += bf2f(f[j].x); ay += bf2f(f[j].y); az += bf2f(f[j].z); aw += bf2f(f[j].w);
      }
      i += nb;
    }
    float ic = 1.0f / fmaxf((float)(end-beg), 1.0f);
    v.x = ax*ic; v.y = ay*ic; v.z = az*ic; v.w = aw*ic;
  }
  v.x = fmaxf(v.x,0.f); v.y = fmaxf(v.y,0.f); v.z = fmaxf(v.z,0.f); v.w = fmaxf(v.w,0.f);
  *(float4*)(Hrelu + (size_t)row*DC + lane*4) = v;
}

// ------- bf16 MFMA GEMM: BM=64, BN=128, BK=64, 512 threads (8 waves, 32x32/wave) -------
// C = [A1|A2](M x K) @ Bt(N x K)^T. flags: 1=bf16 out, 2=+bias, 4=relu
// Ksplit multiple of 64. LDS rows 128B (8 x 16B granules); granule g of
// row rr at phys slot g ^ (rr&7). Grid: (N/128, ceil(M/64)), 512 thr.
__global__ __launch_bounds__(512) void k_gemm_bf16(
    const ushort* __restrict__ A1, int lda1,
    const ushort* __restrict__ A2, int lda2, int Ksplit,
    const ushort* __restrict__ Bt, int ldb,
    void* __restrict__ Cout0, int ldc,
    int M, int N, int K,
    const float* __restrict__ bias, int flags)
{
  __shared__ ushort As[64*64];    // 8 KB
  __shared__ ushort Bs[128*64];   // 16 KB
  const int tid = threadIdx.x;
  const int wave = tid >> 6, lane = tid & 63;   // 8 waves
  const int m0 = blockIdx.y * 64, n0 = blockIdx.x * 128;
  const int wm = (wave >> 2) * 32;    // 0 / 32
  const int wn = (wave & 3) * 32;     // 0 / 32 / 64 / 96
  const int qa = lane >> 4, lm = lane & 15;

  const int lrow = lane >> 3;     // 0..7
  const int slot = lane & 7;      // 0..7

  floatx4 acc[2][2] = {};

  for (int k0 = 0; k0 < K; k0 += 64){
    const ushort* a_base; int a_ld, acol;
    if (k0 < Ksplit){ a_base = A1; a_ld = lda1; acol = k0; }
    else            { a_base = A2; a_ld = lda2; acol = k0 - Ksplit; }
    // As: 64 rows, 1 inst per wave (rows wave*8 .. +8)
    {
      int rr = wave*8 + lrow;
      int gl = slot ^ (rr & 7);
      int ar = m0 + rr; if (ar > M-1) ar = M-1;
      gld16(a_base + (size_t)ar*a_ld + acol + gl*8, As + (size_t)(wave*8)*64 + lane*8);
    }
    // Bs: 128 rows, 2 insts per wave (rows wave*16 .. +16)
    #pragma unroll
    for (int t = 0; t < 2; t++){
      int rb = wave*16 + t*8;
      int rr = rb + lrow;
      int gl = slot ^ (rr & 7);
      gld16(Bt + (size_t)(n0 + rr)*ldb + k0 + gl*8, Bs + (size_t)rb*64 + lane*8);
    }
    __syncthreads();
    #pragma unroll
    for (int kk2 = 0; kk2 < 2; kk2++){
      short8 af[2], bfv[2];
      #pragma unroll
      for (int mt = 0; mt < 2; mt++){
        int rr = wm + mt*16 + lm;
        af[mt] = *(const short8*)(As + (size_t)rr*64 + (size_t)(((kk2*4 + qa) ^ (rr & 7)))*8);
      }
      #pragma unroll
      for (int nt = 0; nt < 2; nt++){
        int rr = wn + nt*16 + lm;
        bfv[nt] = *(const short8*)(Bs + (size_t)rr*64 + (size_t)(((kk2*4 + qa) ^ (rr & 7)))*8);
      }
      #pragma unroll
      for (int mt = 0; mt < 2; mt++)
        #pragma unroll
        for (int nt = 0; nt < 2; nt++)
          acc[mt][nt] = __builtin_amdgcn_mfma_f32_16x16x32_bf16(af[mt], bfv[nt], acc[mt][nt], 0, 0, 0);
    }
    __syncthreads();
  }

  #pragma unroll
  for (int mt = 0; mt < 2; mt++){
    #pragma unroll
    for (int i = 0; i < 4; i++){
      int row = m0 + wm + mt*16 + qa*4 + i;
      if (row >= M) continue;
      #pragma unroll
      for (int nt = 0; nt < 2; nt++){
        int col = n0 + wn + nt*16 + lm;
        float v = acc[mt][nt][i];
        if (flags & 2) v += bias[col];
        if (flags & 4) v = fmaxf(v, 0.0f);
        if (flags & 1)
          ((ushort*)Cout0)[(size_t)row*ldc + col] = f2bf(v);
        else
          ((float*)Cout0)[(size_t)row*ldc + col] = v;
      }
    }
  }
}

// ---------------- fp32 GEMM (small/accuracy-critical) ----------------
__global__ __launch_bounds__(256) void k_gemm(
    const float* __restrict__ A, int lda,
    const float* __restrict__ B, int ldb,
    float* __restrict__ C, int ldc,
    int M, int N, int K,
    const float* __restrict__ bias, int flags)
{
  __shared__ __align__(16) float Asm[64][36];
  __shared__ __align__(16) float Bsm[32][64];
  const int tid = threadIdx.x;
  const int tx = tid & 15, ty = tid >> 4;
  const int m0 = blockIdx.y * 64, n0 = blockIdx.x * 64;
  const int am = tid >> 2, ak = (tid & 3) * 8;
  const int bk = tid >> 3, bn = (tid & 7) * 8;
  float acc[4][4] = {};
  for (int k0 = 0; k0 < K; k0 += 32){
    float4 a0, a1;
    int arow = m0 + am;
    if (arow < M){
      const float* ap = A + (size_t)arow*lda + (k0 + ak);
      a0 = *(const float4*)ap;
      a1 = *(const float4*)(ap + 4);
    } else {
      a0 = make_float4(0,0,0,0); a1 = a0;
    }
    const float* bp = B + (size_t)(k0 + bk)*ldb + (n0 + bn);
    float4 b0v = *(const float4*)bp;
    float4 b1v = *(const float4*)(bp + 4);
    *(float4*)&Asm[am][ak]   = a0;
    *(float4*)&Asm[am][ak+4] = a1;
    *(float4*)&Bsm[bk][bn]   = b0v;
    *(float4*)&Bsm[bk][bn+4] = b1v;
    __syncthreads();
    #pragma unroll
    for (int kk = 0; kk < 32; ++kk){
      float av[4], bv[4];
      #pragma unroll
      for (int i=0;i<4;i++) av[i] = Asm[ty*4+i][kk];
      #pragma unroll
      for (int j=0;j<4;j++) bv[j] = Bsm[kk][tx*4+j];
      #pragma unroll
      for (int i=0;i<4;i++)
        #pragma unroll
        for (int j=0;j<4;j++)
          acc[i][j] = fmaf(av[i], bv[j], acc[i][j]);
    }
    __syncthreads();
  }
  #pragma unroll
  for (int i=0;i<4;i++){
    int row = m0 + ty*4 + i;
    if (row >= M) continue;
    #pragma unroll
    for (int j=0;j<4;j++){
      int col = n0 + tx*4 + j;
      float v = acc[i][j];
      if (flags & 2) v += bias[col];
      if (flags & 4) v = fmaxf(v, 0.0f);
      C[(size_t)row*ldc + col] = v;
    }
  }
}

// ---------------- sampling & head kernels ----------------
// pq layout per row (1024): [pu_mean(256) | pu_ls(256) | qz_mean(256) | qz_ls(256)]
__global__ __launch_bounds__(256) void k_sample_u(const float* __restrict__ pq, float* __restrict__ u,
                                                  ushort* __restrict__ repb,
                                                  uint32_t k0, uint32_t k1){
  const int half = (1088*DC)/2;
  int j = blockIdx.x*256 + threadIdx.x;
  if (j >= half) return;
  uint32_t o0, o1;
  tf2x32(k0, k1, (uint32_t)j, (uint32_t)(j + half), &o0, &o1);
  #pragma unroll
  for (int t = 0; t < 2; t++){
    int i = j + t*half;
    uint32_t bits = t ? o1 : o0;
    int row = i >> 8, col = i & 255;
    const float* pr = pq + (size_t)row*1024;
    float val = pr[col] + expf(pr[256 + col]) * bits_to_normal(bits);
    u[i] = val;
    repb[(size_t)row*512 + 256 + col] = f2bf(val);
  }
}

__global__ __launch_bounds__(256) void k_sample_zM(const float* __restrict__ pq, float* __restrict__ zM,
                                                   ushort* __restrict__ repb,
                                                   uint32_t k0, uint32_t k1){
  const int half = (NUM_MC*DC)/2;
  int j = blockIdx.x*256 + threadIdx.x;
  if (j >= half) return;
  uint32_t o0, o1;
  tf2x32(k0, k1, (uint32_t)j, (uint32_t)(j + half), &o0, &o1);
  #pragma unroll
  for (int t = 0; t < 2; t++){
    int i = j + t*half;
    uint32_t bits = t ? o1 : o0;
    int m = i >> 8, col = i & 255;
    const float* pr = pq + (size_t)(NUM_RC + m)*1024;
    float val = pr[512 + col] + expf(pr[768 + col]) * bits_to_normal(bits);
    zM[i] = val;
    repb[(size_t)(NUM_RC + m)*512 + col] = f2bf(val);
  }
}

__global__ __launch_bounds__(256) void k_sample_zR(const float* __restrict__ pq, ushort* __restrict__ repb,
                                                   uint32_t k0, uint32_t k1){
  const int half = (NUM_RC*DC)/2;
  int j = blockIdx.x*256 + threadIdx.x;
  if (j >= half) return;
  uint32_t o0, o1;
  tf2x32(k0, k1, (uint32_t)j, (uint32_t)(j + half), &o0, &o1);
  #pragma unroll
  for (int t = 0; t < 2; t++){
    int i = j + t*half;
    uint32_t bits = t ? o1 : o0;
    int r = i >> 8, col = i & 255;
    const float* pr = pq + (size_t)r*1024;
    float val = pr[512 + col] + expf(pr[768 + col]) * bits_to_normal(bits);
    repb[(size_t)r*512 + col] = f2bf(val);
  }
}

__global__ __launch_bounds__(64) void k_d2(const float* __restrict__ u, float* __restrict__ d2){
  int m = blockIdx.x, r = threadIdx.x;
  const float4* um = (const float4*)(u + (size_t)(NUM_RC + m)*DC);
  const float4* ur = (const float4*)(u + (size_t)r*DC);
  float s = 0.f;
  #pragma unroll 4
  for (int d = 0; d < DC/4; ++d){
    float4 a = um[d], b = ur[d];
    float dx = a.x-b.x, dy = a.y-b.y, dz = a.z-b.z, dw = a.w-b.w;
    s = fmaf(dx,dx, fmaf(dy,dy, fmaf(dz,dz, fmaf(dw,dw, s))));
  }
  d2[m*NUM_RC + r] = s;
}

__device__ __forceinline__ void A_elem(float* An, const float* d2, int i, uint32_t bits, float inv_s){
  float logp = -0.5f * d2[i] * inv_s;
  float la = logp - logf(fmaxf(-expm1f(logp), 1e-20f));
  float f = bits_to_unit(bits);
  const float mn = 1e-6f, mx = 0.999999f;
  float U = fmaxf(f*(mx-mn) + mn, mn);
  float g = (la + logf(U) - log1pf(-U)) / 0.3f;
  An[i] = 1.0f / (1.0f + expf(-g));
}

__global__ __launch_bounds__(256) void k_A(const float* __restrict__ d2, const float* __restrict__ pg,
                                           float* __restrict__ An, uint32_t k0, uint32_t k1){
  const int HALF = (NUM_MC*NUM_RC)/2;
  int j = blockIdx.x*256 + threadIdx.x;
  if (j >= HALF) return;
  uint32_t o0, o1;
  tf2x32(k0, k1, (uint32_t)j, (uint32_t)(j + HALF), &o0, &o1);
  float inv_s = expf(-pg[0]);
  A_elem(An, d2, j, o0, inv_s);
  A_elem(An, d2, j + HALF, o1, inv_s);
}

__global__ __launch_bounds__(64) void k_rownorm(float* __restrict__ An){
  int m = blockIdx.x, r = threadIdx.x;
  float v = An[m*NUM_RC + r];
  float s = waveReduce(v);
  An[m*NUM_RC + r] = v / (s + 1e-8f);
}

__global__ __launch_bounds__(256) void k_logpqz(const float* __restrict__ zM, const float* __restrict__ pzcat,
                                                const float* __restrict__ pq, float* __restrict__ scal){
  int idx = blockIdx.x*256 + threadIdx.x;
  int m = idx >> 8, d = idx & 255;
  float z  = zM[idx];
  float pm = pzcat[(size_t)m*512 + d];
  float pl = pzcat[(size_t)m*512 + 256 + d];
  const float* qrow = pq + (size_t)(NUM_RC + m)*1024;
  float qm = qrow[512 + d], ql = qrow[768 + d];
  float tp = (z - pm) * expf(-pl);
  float tq = (z - qm) * expf(-ql);
  float term = (-pl - 0.5f*tp*tp) - (-ql - 0.5f*tq*tq);
  float s = waveReduce(term);
  if ((threadIdx.x & 63) == 0) atomicAdd(&scal[0], s);
}

// fused: rows 0..63 -> rationale (scal[2], yR); rows 64..1087 -> prediction (scal[1], yM)
__global__ __launch_bounds__(256) void k_out_head(const float* __restrict__ hid, const float* __restrict__ W2,
                                                  const float* __restrict__ b2, const int* __restrict__ yM,
                                                  const int* __restrict__ yR, float* __restrict__ scal){
  int wave = threadIdx.x >> 6, lane = threadIdx.x & 63;
  int row = blockIdx.x*4 + wave;
  if (row >= NUM_RC + NUM_MC) return;
  const float* h = hid + (size_t)row*256;
  float p0 = 0.f, p1 = 0.f;
  #pragma unroll
  for (int c = 0; c < 4; c++){
    int d = lane*4 + c;
    float hv = h[d];
    p0 = fmaf(hv, W2[d*2+0], p0);
    p1 = fmaf(hv, W2[d*2+1], p1);
  }
  p0 = waveReduce(p0);
  p1 = waveReduce(p1);
  if (lane == 0){
    float l0 = p0 + b2[0], l1 = p1 + b2[1];
    float mx = fmaxf(l0, l1);
    float lse = mx + logf(expf(l0-mx) + expf(l1-mx));
    int y = (row < NUM_RC) ? yR[row] : yM[row - NUM_RC];
    float lp = ((y == 0) ? l0 : l1) - lse;
    atomicAdd((row < NUM_RC) ? &scal[2] : &scal[1], lp);
  }
}

__global__ __launch_bounds__(256) void k_reg(const float* __restrict__ d2, const int* __restrict__ yM,
                                             float* __restrict__ scal){
  int t = blockIdx.x*256 + threadIdx.x;
  float v = 0.f;
  if (t < 32*1024){
    int i = t >> 10, m = t & 1023;
    int col = i + (1 - yM[m]) * 32;
    v = sqrtf(fmaxf(d2[m*NUM_RC + col], 1e-12f));
  }
  float s = waveReduce(v);
  if ((threadIdx.x & 63) == 0) atomicAdd(&scal[3], s);
}

__global__ void k_final(const float* __restrict__ scal, float* __restrict__ out){
  float pred = -(scal[1] + 0.1f*scal[0]) / 1024.0f;
  float rat  = -scal[2] / 64.0f;
  float regm = scal[3] / 32768.0f;
  out[0] = pred + rat - 0.1f*regm;
}

// ---------------- launch ----------------
extern "C" void kernel_launch(void* const* d_in, const int* in_sizes, int n_in,
                              void* d_out, int out_size, void* d_ws, size_t ws_size,
                              hipStream_t stream) {
  const float* x         = (const float*)d_in[0];
  const int*   edge_index= (const int*)  d_in[1];
  const int*   edge_type = (const int*)  d_in[2];
  const int*   batch     = (const int*)  d_in[3];
  const int*   yM        = (const int*)  d_in[4];
  const int*   yR        = (const int*)  d_in[5];
  const float* H_R       = (const float*)d_in[6];
  const float* node_W    = (const float*)d_in[7];
  const float* node_b    = (const float*)d_in[8];
  const float* gcn_Wr    = (const float*)d_in[9];
  const float* gcn_Wroot = (const float*)d_in[10];
  const float* gcn_b     = (const float*)d_in[11];
  const float* pg_ls     = (const float*)d_in[12];
  const float* pu_W      = (const float*)d_in[13];
  const float* pu_b      = (const float*)d_in[14];
  const float* qz_W      = (const float*)d_in[15];
  const float* qz_b      = (const float*)d_in[16];
  const float* out_W1    = (const float*)d_in[17];
  const float* out_b1    = (const float*)d_in[18];
  const float* out_W2    = (const float*)d_in[19];
  const float* out_b2    = (const float*)d_in[20];
  float* out = (float*)d_out;

  char* base = (char*)d_ws;
  size_t off = 0;
  auto ALLOC = [&](size_t nbytes)->void*{
    void* p = base + off; off += (nbytes + 255) & ~(size_t)255; return p;
  };
  ushort* curb_a  = (ushort*)ALLOC((size_t)N_NODESC*DC*2);
  ushort* curb_b  = (ushort*)ALLOC((size_t)N_NODESC*DC*2);
  ushort* agg     = (ushort*)ALLOC((size_t)N_NODESC*1024*2);
  ushort* xb      = (ushort*)ALLOC((size_t)N_NODESC*D_INC*2);
  ushort* node_Wt = (ushort*)ALLOC((size_t)SEG1*2);
  ushort* Wcat    = (ushort*)ALLOC((size_t)SEG2*2);
  float*  pqW     = (float*) ALLOC((size_t)SEG3*4);
  ushort* W1t     = (ushort*)ALLOC((size_t)SEG4*2);
  float*  pqb     = (float*) ALLOC((size_t)SEG5*4);
  // contiguous zero group: cnt | deg | cursor | scal
  float*  zgrp    = (float*) ALLOC((size_t)(N_RELC*N_NODESC + N_NODESC + N_NODESC + 16)*4);
  float*  cnt     = zgrp;
  int*    deg     = (int*)(cnt + (size_t)N_RELC*N_NODESC);
  int*    cursor  = deg + N_NODESC;
  float*  scal    = (float*)(cursor + N_NODESC);
  int*    rowptr  = (int*)   ALLOC((size_t)(N_NODESC+1)*4);
  int*    bsum    = (int*)   ALLOC((size_t)NBLK_SCAN*4);
  int*    boff    = (int*)   ALLOC((size_t)NBLK_SCAN*4);
  int*    ep      = (int*)   ALLOC((size_t)N_EDGESC*4);
  float*  einvc   = (float*) ALLOC((size_t)N_EDGESC*4);
  int*    grow    = (int*)   ALLOC((size_t)(NUM_MC+1)*4);
  float*  Hrelu   = (float*) ALLOC((size_t)1088*DC*4);
  float*  pq      = (float*) ALLOC((size_t)1088*1024*4);
  float*  u       = (float*) ALLOC((size_t)1088*DC*4);
  ushort* repb    = (ushort*)ALLOC((size_t)1088*512*2);
  float*  zM      = (float*) ALLOC((size_t)NUM_MC*DC*4);
  float*  d2      = (float*) ALLOC((size_t)NUM_MC*NUM_RC*4);
  float*  An      = (float*) ALLOC((size_t)NUM_MC*NUM_RC*4);
  float*  pzcat   = (float*) ALLOC((size_t)NUM_MC*512*4);
  float*  hid     = (float*) ALLOC((size_t)1088*256*4);
  (void)ws_size; (void)in_sizes; (void)n_in; (void)out_size;

  uint32_t ya0,ya1,yb0,yb1,yc0,yc1,yd0,yd1;
  tf2x32(0u,42u, 0u,4u, &ya0,&ya1);
  tf2x32(0u,42u, 1u,5u, &yb0,&yb1);
  tf2x32(0u,42u, 2u,6u, &yc0,&yc1);
  tf2x32(0u,42u, 3u,7u, &yd0,&yd1);
  const uint32_t ku0=ya0,  ku1=yb0;
  const uint32_t ka0=yc0,  ka1=yd0;
  const uint32_t kzm0=ya1, kzm1=yb1;
  const uint32_t kzr0=yc1, kzr1=yd1;

  auto GEMM = [&](const float* A, int lda, const float* B, int ldb, float* C, int ldc,
                  int M, int N, int K, const float* bias, int flags){
    k_gemm<<<dim3(N/64, (M+63)/64), dim3(256), 0, stream>>>(A, lda, B, ldb, C, ldc, M, N, K, bias, flags);
  };
  auto BGEMM = [&](const ushort* A1, int lda1, const ushort* A2, int lda2, int Ksplit,
                   const ushort* Bt, int ldb, void* C, int ldc,
                   int M, int N, int K, const float* bias, int flags){
    k_gemm_bf16<<<dim3(N/128, (M+63)/64), dim3(512), 0, stream>>>(
        A1, lda1, A2, lda2, Ksplit, Bt, ldb, C, ldc, M, N, K, bias, flags);
  };

  // ---- setup ----
  {
    int n4 = (N_RELC*N_NODESC + 2*N_NODESC + 16)/4;
    k_zero4<<<dim3((n4+255)/256), dim3(256), 0, stream>>>((float4*)zgrp, n4);
  }
  k_count<<<dim3((N_EDGESC+255)/256), dim3(256), 0, stream>>>(edge_index, edge_type, cnt, deg);
  k_scan1<<<dim3(NBLK_SCAN), dim3(256), 0, stream>>>(deg, bsum);
  k_scan2<<<dim3(1), dim3(256), 0, stream>>>(bsum, boff);
  k_scan3<<<dim3(NBLK_SCAN), dim3(256), 0, stream>>>(deg, boff, rowptr);
  k_fill2<<<dim3((N_EDGESC+255)/256), dim3(256), 0, stream>>>(edge_index, edge_type, cnt, rowptr, cursor, ep, einvc);
  k_bnd  <<<dim3((N_NODESC+255)/256), dim3(256), 0, stream>>>(batch, grow);
  {
    int total = SEG0+SEG1+SEG2+SEG3+SEG4+SEG5;
    k_prep<<<dim3((total+255)/256), dim3(256), 0, stream>>>(
        x, xb, node_W, node_Wt, gcn_Wroot, gcn_Wr, Wcat, pu_W, qz_W, pqW, out_W1, W1t, pu_b, qz_b, pqb);
  }

  // ---- input projection: curb_a = bf16(x @ node_W + node_b) ----
  BGEMM(xb, D_INC, xb, D_INC, D_INC, node_Wt, D_INC, curb_a, DC, N_NODESC, DC, D_INC, node_b, 1|2);

  // ---- RGCN layers: aggregate (CSR) then one K=1280 GEMM ----
  ushort* cur = curb_a; ushort* nxt = curb_b;
  for (int l = 0; l < N_LAYERSC; l++){
    k_agg<<<dim3((N_NODESC+7)/8), dim3(256), 0, stream>>>(cur, agg, rowptr, ep, einvc);
    int fl = 1 | 2 | ((l < N_LAYERSC-1) ? 4 : 0);
    BGEMM(cur, DC, agg, 1024, DC, Wcat + (size_t)l*DC*1280, 1280, nxt, DC,
          N_NODESC, DC, 1280, gcn_b + l*DC, fl);
    ushort* t = nxt; nxt = cur; cur = t;
  }
  // cur == final feats (bf16, no relu)

  // ---- pool + concat + relu (fp32) ----
  k_pool<<<dim3((NUM_RC+NUM_MC+3)/4), dim3(256), 0, stream>>>(cur, grow, H_R, Hrelu);

  // ---- fused pu|qz projection (fp32, accuracy-critical) ----
  GEMM(Hrelu, DC, pqW, 1024, pq, 1024, 1088, 1024, DC, pqb, 2);

  // ---- u sampling (fp32 u + bf16 rep cols 256..511) ----
  k_sample_u<<<dim3(544), dim3(256), 0, stream>>>(pq, u, repb, ku0, ku1);

  // ---- d2, A, An ----
  k_d2<<<dim3(NUM_MC), dim3(64), 0, stream>>>(u, d2);
  k_A <<<dim3(128), dim3(256), 0, stream>>>(d2, pg_ls, An, ka0, ka1);
  k_rownorm<<<dim3(NUM_MC), dim3(64), 0, stream>>>(An);

  // ---- pzcat = An @ qz[:64] (fp32) ----
  GEMM(An, NUM_RC, pq + 512, 1024, pzcat, 512, NUM_MC, 512, NUM_RC, nullptr, 0);

  // ---- z sampling + log_pqz ----
  k_sample_zM<<<dim3(512), dim3(256), 0, stream>>>(pq, zM, repb, kzm0, kzm1);
  k_logpqz<<<dim3(1024), dim3(256), 0, stream>>>(zM, pzcat, pq, scal);
  k_sample_zR<<<dim3(32), dim3(256), 0, stream>>>(pq, repb, kzr0, kzr1);

  // ---- fused output head: hid = relu(rep @ W1 + b1), then logits+loss ----
  BGEMM(repb, 512, repb, 512, 512, W1t, 512, hid, 256, NUM_RC+NUM_MC, 256, 512, out_b1, 2|4);
  k_out_head<<<dim3((NUM_RC+NUM_MC)/4), dim3(256), 0, stream>>>(hid, out_W2, out_b2, yM, yR, scal);

  // ---- reg term & final combine ----
  k_reg<<<dim3(128), dim3(256), 0, stream>>>(d2, yM, scal);
  k_final<<<dim3(1), dim3(1), 0, stream>>>(scal, out);
}

// Round 11
// 707.061 us; speedup vs baseline: 1.8406x; 1.0011x over previous
//
#include <hip/hip_runtime.h>
#include <stdint.h>

#define N_NODESC 50000
#define N_EDGESC 200000
#define D_INC 128
#define DC 256
#define N_LAYERSC 4
#define N_RELC 4
#define NUM_MC 1024
#define NUM_RC 64
#define NBLK_SCAN ((N_NODESC + 255) / 256)   // 196

typedef __attribute__((ext_vector_type(4))) float floatx4;
typedef __attribute__((ext_vector_type(8))) short short8;

// ---------------- threefry2x32 (JAX-compatible) ----------------
__host__ __device__ __forceinline__ uint32_t rotl32(uint32_t x, int r){ return (x<<r)|(x>>(32-r)); }

__host__ __device__ inline void tf2x32(uint32_t k0, uint32_t k1, uint32_t x0, uint32_t x1,
                                       uint32_t* o0, uint32_t* o1){
  uint32_t k2 = k0 ^ k1 ^ 0x1BD11BDAu;
#define TFR(r) { x0 += x1; x1 = rotl32(x1, (r)); x1 ^= x0; }
  x0 += k0; x1 += k1;
  TFR(13) TFR(15) TFR(26) TFR(6)
  x0 += k1; x1 += k2 + 1u;
  TFR(17) TFR(29) TFR(16) TFR(24)
  x0 += k2; x1 += k0 + 2u;
  TFR(13) TFR(15) TFR(26) TFR(6)
  x0 += k0; x1 += k1 + 3u;
  TFR(17) TFR(29) TFR(16) TFR(24)
  x0 += k1; x1 += k2 + 4u;
  TFR(13) TFR(15) TFR(26) TFR(6)
  x0 += k2; x1 += k0 + 5u;
#undef TFR
  *o0 = x0; *o1 = x1;
}

__device__ __forceinline__ float erfinv_f32(float x){
  float w = -log1pf(-x*x);
  float p;
  if (w < 5.0f){
    w -= 2.5f;
    p = 2.81022636e-08f;
    p = fmaf(p, w, 3.43273939e-07f);
    p = fmaf(p, w, -3.5233877e-06f);
    p = fmaf(p, w, -4.39150654e-06f);
    p = fmaf(p, w, 0.00021858087f);
    p = fmaf(p, w, -0.00125372503f);
    p = fmaf(p, w, -0.00417768164f);
    p = fmaf(p, w, 0.246640727f);
    p = fmaf(p, w, 1.50140941f);
  } else {
    w = sqrtf(w) - 3.0f;
    p = -0.000200214257f;
    p = fmaf(p, w, 0.000100950558f);
    p = fmaf(p, w, 0.00134934322f);
    p = fmaf(p, w, -0.00367342844f);
    p = fmaf(p, w, 0.00573950773f);
    p = fmaf(p, w, -0.0076224613f);
    p = fmaf(p, w, 0.00943887047f);
    p = fmaf(p, w, 1.00167406f);
    p = fmaf(p, w, 2.83297682f);
  }
  return p*x;
}

__device__ __forceinline__ float bits_to_unit(uint32_t b){
  return __uint_as_float((b >> 9) | 0x3f800000u) - 1.0f;
}

__device__ __forceinline__ float bits_to_normal(uint32_t b){
  float f = bits_to_unit(b);
  const float lo = -0.99999994f;
  float u = f * (1.0f - lo) + lo;
  u = fmaxf(u, lo);
  return 1.41421356f * erfinv_f32(u);
}

__device__ __forceinline__ float waveReduce(float v){
  #pragma unroll
  for (int m = 1; m < 64; m <<= 1) v += __shfl_xor(v, m, 64);
  return v;
}

__device__ __forceinline__ ushort f2bf(float f){
  uint32_t u = __float_as_uint(f);
  uint32_t r = u + 0x7fffu + ((u>>16)&1u);
  return (ushort)(r>>16);
}
__device__ __forceinline__ float bf2f(ushort h){
  return __uint_as_float(((uint32_t)h)<<16);
}

typedef const __attribute__((address_space(1))) void* gas_t;
typedef __attribute__((address_space(3))) void* las_t;
__device__ __forceinline__ void gld16(const void* g, void* l){
  __builtin_amdgcn_global_load_lds((gas_t)g, (las_t)l, 16, 0, 0);
}

// ---------------- setup kernels ----------------
__global__ __launch_bounds__(256) void k_zero4(float4* p, int n4){
  int i = blockIdx.x*256 + threadIdx.x;
  if (i < n4) p[i] = make_float4(0.f,0.f,0.f,0.f);
}

__global__ __launch_bounds__(256) void k_count(const int* __restrict__ ei, const int* __restrict__ et,
                                               float* __restrict__ cnt, int* __restrict__ deg){
  int e = blockIdx.x*256 + threadIdx.x;
  if (e >= N_EDGESC) return;
  int r = et[e], dstv = ei[N_EDGESC + e];
  atomicAdd(&cnt[(size_t)r*N_NODESC + dstv], 1.0f);
  atomicAdd(&deg[dstv], 1);
}

__global__ __launch_bounds__(256) void k_scan1(const int* __restrict__ deg, int* __restrict__ bsum){
  int i = blockIdx.x*256 + threadIdx.x;
  int v = (i < N_NODESC) ? deg[i] : 0;
  #pragma unroll
  for (int m = 1; m < 64; m <<= 1) v += __shfl_xor(v, m, 64);
  __shared__ int ws_[4];
  if ((threadIdx.x & 63) == 0) ws_[threadIdx.x >> 6] = v;
  __syncthreads();
  if (threadIdx.x == 0) bsum[blockIdx.x] = ws_[0]+ws_[1]+ws_[2]+ws_[3];
}

__global__ __launch_bounds__(256) void k_scan2(int* __restrict__ bsum, int* __restrict__ boff){
  __shared__ int s[256];
  int t = threadIdx.x;
  s[t] = (t < NBLK_SCAN) ? bsum[t] : 0;
  __syncthreads();
  if (t == 0){
    int run = 0;
    for (int i = 0; i < NBLK_SCAN; i++){ int v = s[i]; s[i] = run; run += v; }
  }
  __syncthreads();
  if (t < NBLK_SCAN) boff[t] = s[t];
}

__global__ __launch_bounds__(256) void k_scan3(const int* __restrict__ deg, const int* __restrict__ boff,
                                               int* __restrict__ rowptr){
  int i = blockIdx.x*256 + threadIdx.x;
  int lane = threadIdx.x & 63, w = threadIdx.x >> 6;
  int d = (i < N_NODESC) ? deg[i] : 0;
  int v = d;
  #pragma unroll
  for (int off = 1; off < 64; off <<= 1){
    int t = __shfl_up(v, off, 64);
    if (lane >= off) v += t;
  }
  __shared__ int wt[4];
  if (lane == 63) wt[w] = v;
  __syncthreads();
  int wo = 0;
  for (int k = 0; k < w; k++) wo += wt[k];
  int ex = boff[blockIdx.x] + wo + v - d;
  if (i <= N_NODESC) rowptr[i] = ex;
}

__global__ __launch_bounds__(256) void k_fill2(const int* __restrict__ ei, const int* __restrict__ et,
                                               const float* __restrict__ cnt, const int* __restrict__ rowptr,
                                               int* __restrict__ cursor, int* __restrict__ ep,
                                               float* __restrict__ einvc){
  int e = blockIdx.x*256 + threadIdx.x;
  if (e >= N_EDGESC) return;
  int src = ei[e], dstv = ei[N_EDGESC + e], r = et[e];
  int pos = rowptr[dstv] + atomicAdd(&cursor[dstv], 1);
  ep[pos] = src | (r << 16);
  einvc[pos] = 1.0f / fmaxf(cnt[(size_t)r*N_NODESC + dstv], 1.0f);
}

__global__ __launch_bounds__(256) void k_bnd(const int* __restrict__ batch, int* __restrict__ grow){
  int i = blockIdx.x*256 + threadIdx.x;
  if (i >= N_NODESC) return;
  int b = batch[i];
  if (i == 0){ for (int g = 0; g <= b; g++) grow[g] = 0; }
  else {
    int pb = batch[i-1];
    for (int g = pb+1; g <= b; g++) grow[g] = i;
  }
  if (i == N_NODESC-1){ for (int g = b+1; g <= NUM_MC; g++) grow[g] = N_NODESC; }
}

// ---- one fused prep kernel: x->bf16, all weight transposes/concats ----
#define SEG0 (N_NODESC*D_INC/4)            // x float4 -> ushort4
#define SEG1 (DC*D_INC)                    // node_Wt[n*128+k]
#define SEG2 (N_LAYERSC*DC*1280)           // Wcat[l][n(256)][k(1280)]
#define SEG3 (DC*1024)                     // pqW fp32 [k(256)][n(1024)]
#define SEG4 (DC*512)                      // W1t[n(256)][k(512)]
#define SEG5 1024                          // pqb
__global__ __launch_bounds__(256) void k_prep(const float* __restrict__ x, ushort* __restrict__ xb,
                                              const float* __restrict__ node_W, ushort* __restrict__ node_Wt,
                                              const float* __restrict__ Wroot, const float* __restrict__ Wr,
                                              ushort* __restrict__ Wcat,
                                              const float* __restrict__ pu_W, const float* __restrict__ qz_W,
                                              float* __restrict__ pqW,
                                              const float* __restrict__ out_W1, ushort* __restrict__ W1t,
                                              const float* __restrict__ pu_b, const float* __restrict__ qz_b,
                                              float* __restrict__ pqb){
  int idx = blockIdx.x*256 + threadIdx.x;
  if (idx < SEG0){
    float4 v = ((const float4*)x)[idx];
    ushort4 o; o.x=f2bf(v.x); o.y=f2bf(v.y); o.z=f2bf(v.z); o.w=f2bf(v.w);
    ((ushort4*)xb)[idx] = o;
    return;
  }
  idx -= SEG0;
  if (idx < SEG1){
    int n = idx >> 7, k = idx & 127;
    node_Wt[idx] = f2bf(node_W[(size_t)k*DC + n]);
    return;
  }
  idx -= SEG1;
  if (idx < SEG2){
    int l = idx / (DC*1280), rem = idx - l*(DC*1280);
    int n = rem / 1280, k = rem - n*1280;
    float v;
    if (k < DC) v = Wroot[((size_t)l*DC + k)*DC + n];
    else {
      int kk = k - DC, r = kk >> 8, kr = kk & 255;
      v = Wr[(((size_t)l*N_RELC + r)*DC + kr)*DC + n];
    }
    Wcat[idx] = f2bf(v);
    return;
  }
  idx -= SEG2;
  if (idx < SEG3){
    int k = idx >> 10, n = idx & 1023;
    pqW[idx] = (n < 512) ? pu_W[(size_t)k*512 + n] : qz_W[(size_t)k*512 + (n-512)];
    return;
  }
  idx -= SEG3;
  if (idx < SEG4){
    int n = idx >> 9, k = idx & 511;
    W1t[idx] = f2bf(out_W1[(size_t)k*DC + n]);
    return;
  }
  idx -= SEG4;
  if (idx < SEG5){
    pqb[idx] = (idx < 512) ? pu_b[idx] : qz_b[idx-512];
  }
}

// ---- aggregation: 2 dsts per wave (32-lane halves, ushort8/lane), 8-edge ILP ----
__global__ __launch_bounds__(256) void k_agg(const ushort* __restrict__ curb, ushort* __restrict__ agg,
                                             const int* __restrict__ rowptr, const int* __restrict__ ep,
                                             const float* __restrict__ einvc){
  int halfid = threadIdx.x >> 5;           // 0..7
  int dstv = blockIdx.x*8 + halfid;
  if (dstv >= N_NODESC) return;
  int lane = threadIdx.x & 31;             // 32 lanes cover 256 cols as 8 each
  int beg = rowptr[dstv], end = rowptr[dstv+1];
  float s0[8] = {}, s1[8] = {}, s2[8] = {}, s3[8] = {};
  int p = beg;
  while (p < end){
    int nb = end - p; if (nb > 8) nb = 8;
    int pk[8]; float ic[8]; short8 h[8];
    #pragma unroll
    for (int j = 0; j < 8; j++) if (j < nb){ pk[j] = ep[p+j]; ic[j] = einvc[p+j]; }
    #pragma unroll
    for (int j = 0; j < 8; j++) if (j < nb)
      h[j] = *(const short8*)(curb + (size_t)(pk[j] & 0xffff)*DC + lane*8);
    #pragma unroll
    for (int j = 0; j < 8; j++) if (j < nb){
      float c = ic[j];
      int r = pk[j] >> 16;
      if (r == 0){
        #pragma unroll
        for (int e = 0; e < 8; e++) s0[e] = fmaf(bf2f((ushort)h[j][e]), c, s0[e]);
      } else if (r == 1){
        #pragma unroll
        for (int e = 0; e < 8; e++) s1[e] = fmaf(bf2f((ushort)h[j][e]), c, s1[e]);
      } else if (r == 2){
        #pragma unroll
        for (int e = 0; e < 8; e++) s2[e] = fmaf(bf2f((ushort)h[j][e]), c, s2[e]);
      } else {
        #pragma unroll
        for (int e = 0; e < 8; e++) s3[e] = fmaf(bf2f((ushort)h[j][e]), c, s3[e]);
      }
    }
    p += nb;
  }
  ushort* ab = agg + (size_t)dstv*1024 + lane*8;
  short8 o;
  #pragma unroll
  for (int e = 0; e < 8; e++) o[e] = (short)f2bf(s0[e]);
  *(short8*)(ab      ) = o;
  #pragma unroll
  for (int e = 0; e < 8; e++) o[e] = (short)f2bf(s1[e]);
  *(short8*)(ab + 256) = o;
  #pragma unroll
  for (int e = 0; e < 8; e++) o[e] = (short)f2bf(s2[e]);
  *(short8*)(ab + 512) = o;
  #pragma unroll
  for (int e = 0; e < 8; e++) o[e] = (short)f2bf(s3[e]);
  *(short8*)(ab + 768) = o;
}

// pooling: rows 0..63 = relu(H_R); rows 64.. = relu(segment mean), 4-row ILP
__global__ __launch_bounds__(256) void k_pool(const ushort* __restrict__ featsb, const int* __restrict__ grow,
                                              const float* __restrict__ H_R, float* __restrict__ Hrelu){
  int row = blockIdx.x*4 + (threadIdx.x >> 6);
  if (row >= NUM_RC + NUM_MC) return;
  int lane = threadIdx.x & 63;
  float4 v;
  if (row < NUM_RC){
    v = *(const float4*)(H_R + (size_t)row*DC + lane*4);
  } else {
    int g = row - NUM_RC;
    int beg = grow[g], end = grow[g+1];
    float ax=0.f, ay=0.f, az=0.f, aw=0.f;
    int i = beg;
    while (i < end){
      int nb = end - i; if (nb > 4) nb = 4;
      ushort4 f[4];
      #pragma unroll
      for (int j = 0; j < 4; j++) if (j < nb)
        f[j] = *(const ushort4*)(featsb + (size_t)(i+j)*DC + lane*4);
      #pragma unroll
      for (int j = 0; j < 4; j++) if (j < nb){
        ax += bf2f(f[j].x); ay += bf2f(f[j].y); az += bf2f(f[j].z); aw += bf2f(f[j].w);
      }
      i += nb;
    }
    float ic = 1.0f / fmaxf((float)(end-beg), 1.0f);
    v.x = ax*ic; v.y = ay*ic; v.z = az*ic; v.w = aw*ic;
  }
  v.x = fmaxf(v.x,0.f); v.y = fmaxf(v.y,0.f); v.z = fmaxf(v.z,0.f); v.w = fmaxf(v.w,0.f);
  *(float4*)(Hrelu + (size_t)row*DC + lane*4) = v;
}

// ------- bf16 MFMA GEMM: BM=64, BN=128, BK=64, 512 threads (8 waves, 32x32/wave) -------
// C = [A1|A2](M x K) @ Bt(N x K)^T. flags: 1=bf16 out, 2=+bias, 4=relu
// Ksplit multiple of 64. LDS rows 128B (8 x 16B granules); granule g of
// row rr at phys slot g ^ (rr&7). Grid: (N/128, ceil(M/64)), 512 thr.
__global__ __launch_bounds__(512) void k_gemm_bf16(
    const ushort* __restrict__ A1, int lda1,
    const ushort* __restrict__ A2, int lda2, int Ksplit,
    const ushort* __restrict__ Bt, int ldb,
    void* __restrict__ Cout0, int ldc,
    int M, int N, int K,
    const float* __restrict__ bias, int flags)
{
  __shared__ ushort As[64*64];    // 8 KB
  __shared__ ushort Bs[128*64];   // 16 KB
  const int tid = threadIdx.x;
  const int wave = tid >> 6, lane = tid & 63;   // 8 waves
  const int m0 = blockIdx.y * 64, n0 = blockIdx.x * 128;
  const int wm = (wave >> 2) * 32;    // 0 / 32
  const int wn = (wave & 3) * 32;     // 0 / 32 / 64 / 96
  const int qa = lane >> 4, lm = lane & 15;

  const int lrow = lane >> 3;     // 0..7
  const int slot = lane & 7;      // 0..7

  floatx4 acc[2][2] = {};

  for (int k0 = 0; k0 < K; k0 += 64){
    const ushort* a_base; int a_ld, acol;
    if (k0 < Ksplit){ a_base = A1; a_ld = lda1; acol = k0; }
    else            { a_base = A2; a_ld = lda2; acol = k0 - Ksplit; }
    // As: 64 rows, 1 inst per wave (rows wave*8 .. +8)
    {
      int rr = wave*8 + lrow;
      int gl = slot ^ (rr & 7);
      int ar = m0 + rr; if (ar > M-1) ar = M-1;
      gld16(a_base + (size_t)ar*a_ld + acol + gl*8, As + (size_t)(wave*8)*64 + lane*8);
    }
    // Bs: 128 rows, 2 insts per wave (rows wave*16 .. +16)
    #pragma unroll
    for (int t = 0; t < 2; t++){
      int rb = wave*16 + t*8;
      int rr = rb + lrow;
      int gl = slot ^ (rr & 7);
      gld16(Bt + (size_t)(n0 + rr)*ldb + k0 + gl*8, Bs + (size_t)rb*64 + lane*8);
    }
    __syncthreads();
    #pragma unroll
    for (int kk2 = 0; kk2 < 2; kk2++){
      short8 af[2], bfv[2];
      #pragma unroll
      for (int mt = 0; mt < 2; mt++){
        int rr = wm + mt*16 + lm;
        af[mt] = *(const short8*)(As + (size_t)rr*64 + (size_t)(((kk2*4 + qa) ^ (rr & 7)))*8);
      }
      #pragma unroll
      for (int nt = 0; nt < 2; nt++){
        int rr = wn + nt*16 + lm;
        bfv[nt] = *(const short8*)(Bs + (size_t)rr*64 + (size_t)(((kk2*4 + qa) ^ (rr & 7)))*8);
      }
      #pragma unroll
      for (int mt = 0; mt < 2; mt++)
        #pragma unroll
        for (int nt = 0; nt < 2; nt++)
          acc[mt][nt] = __builtin_amdgcn_mfma_f32_16x16x32_bf16(af[mt], bfv[nt], acc[mt][nt], 0, 0, 0);
    }
    __syncthreads();
  }

  #pragma unroll
  for (int mt = 0; mt < 2; mt++){
    #pragma unroll
    for (int i = 0; i < 4; i++){
      int row = m0 + wm + mt*16 + qa*4 + i;
      if (row >= M) continue;
      #pragma unroll
      for (int nt = 0; nt < 2; nt++){
        int col = n0 + wn + nt*16 + lm;
        float v = acc[mt][nt][i];
        if (flags & 2) v += bias[col];
        if (flags & 4) v = fmaxf(v, 0.0f);
        if (flags & 1)
          ((ushort*)Cout0)[(size_t)row*ldc + col] = f2bf(v);
        else
          ((float*)Cout0)[(size_t)row*ldc + col] = v;
      }
    }
  }
}

// ---------------- fp32 GEMM (small/accuracy-critical) ----------------
__global__ __launch_bounds__(256) void k_gemm(
    const float* __restrict__ A, int lda,
    const float* __restrict__ B, int ldb,
    float* __restrict__ C, int ldc,
    int M, int N, int K,
    const float* __restrict__ bias, int flags)
{
  __shared__ __align__(16) float Asm[64][36];
  __shared__ __align__(16) float Bsm[32][64];
  const int tid = threadIdx.x;
  const int tx = tid & 15, ty = tid >> 4;
  const int m0 = blockIdx.y * 64, n0 = blockIdx.x * 64;
  const int am = tid >> 2, ak = (tid & 3) * 8;
  const int bk = tid >> 3, bn = (tid & 7) * 8;
  float acc[4][4] = {};
  for (int k0 = 0; k0 < K; k0 += 32){
    float4 a0, a1;
    int arow = m0 + am;
    if (arow < M){
      const float* ap = A + (size_t)arow*lda + (k0 + ak);
      a0 = *(const float4*)ap;
      a1 = *(const float4*)(ap + 4);
    } else {
      a0 = make_float4(0,0,0,0); a1 = a0;
    }
    const float* bp = B + (size_t)(k0 + bk)*ldb + (n0 + bn);
    float4 b0v = *(const float4*)bp;
    float4 b1v = *(const float4*)(bp + 4);
    *(float4*)&Asm[am][ak]   = a0;
    *(float4*)&Asm[am][ak+4] = a1;
    *(float4*)&Bsm[bk][bn]   = b0v;
    *(float4*)&Bsm[bk][bn+4] = b1v;
    __syncthreads();
    #pragma unroll
    for (int kk = 0; kk < 32; ++kk){
      float av[4], bv[4];
      #pragma unroll
      for (int i=0;i<4;i++) av[i] = Asm[ty*4+i][kk];
      #pragma unroll
      for (int j=0;j<4;j++) bv[j] = Bsm[kk][tx*4+j];
      #pragma unroll
      for (int i=0;i<4;i++)
        #pragma unroll
        for (int j=0;j<4;j++)
          acc[i][j] = fmaf(av[i], bv[j], acc[i][j]);
    }
    __syncthreads();
  }
  #pragma unroll
  for (int i=0;i<4;i++){
    int row = m0 + ty*4 + i;
    if (row >= M) continue;
    #pragma unroll
    for (int j=0;j<4;j++){
      int col = n0 + tx*4 + j;
      float v = acc[i][j];
      if (flags & 2) v += bias[col];
      if (flags & 4) v = fmaxf(v, 0.0f);
      C[(size_t)row*ldc + col] = v;
    }
  }
}

// ---------------- sampling & head kernels ----------------
// pq layout per row (1024): [pu_mean(256) | pu_ls(256) | qz_mean(256) | qz_ls(256)]
__global__ __launch_bounds__(256) void k_sample_u(const float* __restrict__ pq, float* __restrict__ u,
                                                  ushort* __restrict__ repb,
                                                  uint32_t k0, uint32_t k1){
  const int half = (1088*DC)/2;
  int j = blockIdx.x*256 + threadIdx.x;
  if (j >= half) return;
  uint32_t o0, o1;
  tf2x32(k0, k1, (uint32_t)j, (uint32_t)(j + half), &o0, &o1);
  #pragma unroll
  for (int t = 0; t < 2; t++){
    int i = j + t*half;
    uint32_t bits = t ? o1 : o0;
    int row = i >> 8, col = i & 255;
    const float* pr = pq + (size_t)row*1024;
    float val = pr[col] + expf(pr[256 + col]) * bits_to_normal(bits);
    u[i] = val;
    repb[(size_t)row*512 + 256 + col] = f2bf(val);
  }
}

__global__ __launch_bounds__(256) void k_sample_zM(const float* __restrict__ pq, float* __restrict__ zM,
                                                   ushort* __restrict__ repb,
                                                   uint32_t k0, uint32_t k1){
  const int half = (NUM_MC*DC)/2;
  int j = blockIdx.x*256 + threadIdx.x;
  if (j >= half) return;
  uint32_t o0, o1;
  tf2x32(k0, k1, (uint32_t)j, (uint32_t)(j + half), &o0, &o1);
  #pragma unroll
  for (int t = 0; t < 2; t++){
    int i = j + t*half;
    uint32_t bits = t ? o1 : o0;
    int m = i >> 8, col = i & 255;
    const float* pr = pq + (size_t)(NUM_RC + m)*1024;
    float val = pr[512 + col] + expf(pr[768 + col]) * bits_to_normal(bits);
    zM[i] = val;
    repb[(size_t)(NUM_RC + m)*512 + col] = f2bf(val);
  }
}

__global__ __launch_bounds__(256) void k_sample_zR(const float* __restrict__ pq, ushort* __restrict__ repb,
                                                   uint32_t k0, uint32_t k1){
  const int half = (NUM_RC*DC)/2;
  int j = blockIdx.x*256 + threadIdx.x;
  if (j >= half) return;
  uint32_t o0, o1;
  tf2x32(k0, k1, (uint32_t)j, (uint32_t)(j + half), &o0, &o1);
  #pragma unroll
  for (int t = 0; t < 2; t++){
    int i = j + t*half;
    uint32_t bits = t ? o1 : o0;
    int r = i >> 8, col = i & 255;
    const float* pr = pq + (size_t)r*1024;
    float val = pr[512 + col] + expf(pr[768 + col]) * bits_to_normal(bits);
    repb[(size_t)r*512 + col] = f2bf(val);
  }
}

__global__ __launch_bounds__(64) void k_d2(const float* __restrict__ u, float* __restrict__ d2){
  int m = blockIdx.x, r = threadIdx.x;
  const float4* um = (const float4*)(u + (size_t)(NUM_RC + m)*DC);
  const float4* ur = (const float4*)(u + (size_t)r*DC);
  float s = 0.f;
  #pragma unroll 4
  for (int d = 0; d < DC/4; ++d){
    float4 a = um[d], b = ur[d];
    float dx = a.x-b.x, dy = a.y-b.y, dz = a.z-b.z, dw = a.w-b.w;
    s = fmaf(dx,dx, fmaf(dy,dy, fmaf(dz,dz, fmaf(dw,dw, s))));
  }
  d2[m*NUM_RC + r] = s;
}

__device__ __forceinline__ void A_elem(float* An, const float* d2, int i, uint32_t bits, float inv_s){
  float logp = -0.5f * d2[i] * inv_s;
  float la = logp - logf(fmaxf(-expm1f(logp), 1e-20f));
  float f = bits_to_unit(bits);
  const float mn = 1e-6f, mx = 0.999999f;
  float U = fmaxf(f*(mx-mn) + mn, mn);
  float g = (la + logf(U) - log1pf(-U)) / 0.3f;
  An[i] = 1.0f / (1.0f + expf(-g));
}

__global__ __launch_bounds__(256) void k_A(const float* __restrict__ d2, const float* __restrict__ pg,
                                           float* __restrict__ An, uint32_t k0, uint32_t k1){
  const int HALF = (NUM_MC*NUM_RC)/2;
  int j = blockIdx.x*256 + threadIdx.x;
  if (j >= HALF) return;
  uint32_t o0, o1;
  tf2x32(k0, k1, (uint32_t)j, (uint32_t)(j + HALF), &o0, &o1);
  float inv_s = expf(-pg[0]);
  A_elem(An, d2, j, o0, inv_s);
  A_elem(An, d2, j + HALF, o1, inv_s);
}

__global__ __launch_bounds__(64) void k_rownorm(float* __restrict__ An){
  int m = blockIdx.x, r = threadIdx.x;
  float v = An[m*NUM_RC + r];
  float s = waveReduce(v);
  An[m*NUM_RC + r] = v / (s + 1e-8f);
}

__global__ __launch_bounds__(256) void k_logpqz(const float* __restrict__ zM, const float* __restrict__ pzcat,
                                                const float* __restrict__ pq, float* __restrict__ scal){
  int idx = blockIdx.x*256 + threadIdx.x;
  int m = idx >> 8, d = idx & 255;
  float z  = zM[idx];
  float pm = pzcat[(size_t)m*512 + d];
  float pl = pzcat[(size_t)m*512 + 256 + d];
  const float* qrow = pq + (size_t)(NUM_RC + m)*1024;
  float qm = qrow[512 + d], ql = qrow[768 + d];
  float tp = (z - pm) * expf(-pl);
  float tq = (z - qm) * expf(-ql);
  float term = (-pl - 0.5f*tp*tp) - (-ql - 0.5f*tq*tq);
  float s = waveReduce(term);
  if ((threadIdx.x & 63) == 0) atomicAdd(&scal[0], s);
}

// fused: rows 0..63 -> rationale (scal[2], yR); rows 64..1087 -> prediction (scal[1], yM)
__global__ __launch_bounds__(256) void k_out_head(const float* __restrict__ hid, const float* __restrict__ W2,
                                                  const float* __restrict__ b2, const int* __restrict__ yM,
                                                  const int* __restrict__ yR, float* __restrict__ scal){
  int wave = threadIdx.x >> 6, lane = threadIdx.x & 63;
  int row = blockIdx.x*4 + wave;
  if (row >= NUM_RC + NUM_MC) return;
  const float* h = hid + (size_t)row*256;
  float p0 = 0.f, p1 = 0.f;
  #pragma unroll
  for (int c = 0; c < 4; c++){
    int d = lane*4 + c;
    float hv = h[d];
    p0 = fmaf(hv, W2[d*2+0], p0);
    p1 = fmaf(hv, W2[d*2+1], p1);
  }
  p0 = waveReduce(p0);
  p1 = waveReduce(p1);
  if (lane == 0){
    float l0 = p0 + b2[0], l1 = p1 + b2[1];
    float mx = fmaxf(l0, l1);
    float lse = mx + logf(expf(l0-mx) + expf(l1-mx));
    int y = (row < NUM_RC) ? yR[row] : yM[row - NUM_RC];
    float lp = ((y == 0) ? l0 : l1) - lse;
    atomicAdd((row < NUM_RC) ? &scal[2] : &scal[1], lp);
  }
}

__global__ __launch_bounds__(256) void k_reg(const float* __restrict__ d2, const int* __restrict__ yM,
                                             float* __restrict__ scal){
  int t = blockIdx.x*256 + threadIdx.x;
  float v = 0.f;
  if (t < 32*1024){
    int i = t >> 10, m = t & 1023;
    int col = i + (1 - yM[m]) * 32;
    v = sqrtf(fmaxf(d2[m*NUM_RC + col], 1e-12f));
  }
  float s = waveReduce(v);
  if ((threadIdx.x & 63) == 0) atomicAdd(&scal[3], s);
}

__global__ void k_final(const float* __restrict__ scal, float* __restrict__ out){
  float pred = -(scal[1] + 0.1f*scal[0]) / 1024.0f;
  float rat  = -scal[2] / 64.0f;
  float regm = scal[3] / 32768.0f;
  out[0] = pred + rat - 0.1f*regm;
}

// ---------------- launch ----------------
extern "C" void kernel_launch(void* const* d_in, const int* in_sizes, int n_in,
                              void* d_out, int out_size, void* d_ws, size_t ws_size,
                              hipStream_t stream) {
  const float* x         = (const float*)d_in[0];
  const int*   edge_index= (const int*)  d_in[1];
  const int*   edge_type = (const int*)  d_in[2];
  const int*   batch     = (const int*)  d_in[3];
  const int*   yM        = (const int*)  d_in[4];
  const int*   yR        = (const int*)  d_in[5];
  const float* H_R       = (const float*)d_in[6];
  const float* node_W    = (const float*)d_in[7];
  const float* node_b    = (const float*)d_in[8];
  const float* gcn_Wr    = (const float*)d_in[9];
  const float* gcn_Wroot = (const float*)d_in[10];
  const float* gcn_b     = (const float*)d_in[11];
  const float* pg_ls     = (const float*)d_in[12];
  const float* pu_W      = (const float*)d_in[13];
  const float* pu_b      = (const float*)d_in[14];
  const float* qz_W      = (const float*)d_in[15];
  const float* qz_b      = (const float*)d_in[16];
  const float* out_W1    = (const float*)d_in[17];
  const float* out_b1    = (const float*)d_in[18];
  const float* out_W2    = (const float*)d_in[19];
  const float* out_b2    = (const float*)d_in[20];
  float* out = (float*)d_out;

  char* base = (char*)d_ws;
  size_t off = 0;
  auto ALLOC = [&](size_t nbytes)->void*{
    void* p = base + off; off += (nbytes + 255) & ~(size_t)255; return p;
  };
  ushort* curb_a  = (ushort*)ALLOC((size_t)N_NODESC*DC*2);
  ushort* curb_b  = (ushort*)ALLOC((size_t)N_NODESC*DC*2);
  ushort* agg     = (ushort*)ALLOC((size_t)N_NODESC*1024*2);
  ushort* xb      = (ushort*)ALLOC((size_t)N_NODESC*D_INC*2);
  ushort* node_Wt = (ushort*)ALLOC((size_t)SEG1*2);
  ushort* Wcat    = (ushort*)ALLOC((size_t)SEG2*2);
  float*  pqW     = (float*) ALLOC((size_t)SEG3*4);
  ushort* W1t     = (ushort*)ALLOC((size_t)SEG4*2);
  float*  pqb     = (float*) ALLOC((size_t)SEG5*4);
  // contiguous zero group: cnt | deg | cursor | scal
  float*  zgrp    = (float*) ALLOC((size_t)(N_RELC*N_NODESC + N_NODESC + N_NODESC + 16)*4);
  float*  cnt     = zgrp;
  int*    deg     = (int*)(cnt + (size_t)N_RELC*N_NODESC);
  int*    cursor  = deg + N_NODESC;
  float*  scal    = (float*)(cursor + N_NODESC);
  int*    rowptr  = (int*)   ALLOC((size_t)(N_NODESC+1)*4);
  int*    bsum    = (int*)   ALLOC((size_t)NBLK_SCAN*4);
  int*    boff    = (int*)   ALLOC((size_t)NBLK_SCAN*4);
  int*    ep      = (int*)   ALLOC((size_t)N_EDGESC*4);
  float*  einvc   = (float*) ALLOC((size_t)N_EDGESC*4);
  int*    grow    = (int*)   ALLOC((size_t)(NUM_MC+1)*4);
  float*  Hrelu   = (float*) ALLOC((size_t)1088*DC*4);
  float*  pq      = (float*) ALLOC((size_t)1088*1024*4);
  float*  u       = (float*) ALLOC((size_t)1088*DC*4);
  ushort* repb    = (ushort*)ALLOC((size_t)1088*512*2);
  float*  zM      = (float*) ALLOC((size_t)NUM_MC*DC*4);
  float*  d2      = (float*) ALLOC((size_t)NUM_MC*NUM_RC*4);
  float*  An      = (float*) ALLOC((size_t)NUM_MC*NUM_RC*4);
  float*  pzcat   = (float*) ALLOC((size_t)NUM_MC*512*4);
  float*  hid     = (float*) ALLOC((size_t)1088*256*4);
  (void)ws_size; (void)in_sizes; (void)n_in; (void)out_size;

  uint32_t ya0,ya1,yb0,yb1,yc0,yc1,yd0,yd1;
  tf2x32(0u,42u, 0u,4u, &ya0,&ya1);
  tf2x32(0u,42u, 1u,5u, &yb0,&yb1);
  tf2x32(0u,42u, 2u,6u, &yc0,&yc1);
  tf2x32(0u,42u, 3u,7u, &yd0,&yd1);
  const uint32_t ku0=ya0,  ku1=yb0;
  const uint32_t ka0=yc0,  ka1=yd0;
  const uint32_t kzm0=ya1, kzm1=yb1;
  const uint32_t kzr0=yc1, kzr1=yd1;

  auto GEMM = [&](const float* A, int lda, const float* B, int ldb, float* C, int ldc,
                  int M, int N, int K, const float* bias, int flags){
    k_gemm<<<dim3(N/64, (M+63)/64), dim3(256), 0, stream>>>(A, lda, B, ldb, C, ldc, M, N, K, bias, flags);
  };
  auto BGEMM = [&](const ushort* A1, int lda1, const ushort* A2, int lda2, int Ksplit,
                   const ushort* Bt, int ldb, void* C, int ldc,
                   int M, int N, int K, const float* bias, int flags){
    k_gemm_bf16<<<dim3(N/128, (M+63)/64), dim3(512), 0, stream>>>(
        A1, lda1, A2, lda2, Ksplit, Bt, ldb, C, ldc, M, N, K, bias, flags);
  };

  // ---- setup ----
  {
    int n4 = (N_RELC*N_NODESC + 2*N_NODESC + 16)/4;
    k_zero4<<<dim3((n4+255)/256), dim3(256), 0, stream>>>((float4*)zgrp, n4);
  }
  k_count<<<dim3((N_EDGESC+255)/256), dim3(256), 0, stream>>>(edge_index, edge_type, cnt, deg);
  k_scan1<<<dim3(NBLK_SCAN), dim3(256), 0, stream>>>(deg, bsum);
  k_scan2<<<dim3(1), dim3(256), 0, stream>>>(bsum, boff);
  k_scan3<<<dim3(NBLK_SCAN), dim3(256), 0, stream>>>(deg, boff, rowptr);
  k_fill2<<<dim3((N_EDGESC+255)/256), dim3(256), 0, stream>>>(edge_index, edge_type, cnt, rowptr, cursor, ep, einvc);
  k_bnd  <<<dim3((N_NODESC+255)/256), dim3(256), 0, stream>>>(batch, grow);
  {
    int total = SEG0+SEG1+SEG2+SEG3+SEG4+SEG5;
    k_prep<<<dim3((total+255)/256), dim3(256), 0, stream>>>(
        x, xb, node_W, node_Wt, gcn_Wroot, gcn_Wr, Wcat, pu_W, qz_W, pqW, out_W1, W1t, pu_b, qz_b, pqb);
  }

  // ---- input projection: curb_a = bf16(x @ node_W + node_b) ----
  BGEMM(xb, D_INC, xb, D_INC, D_INC, node_Wt, D_INC, curb_a, DC, N_NODESC, DC, D_INC, node_b, 1|2);

  // ---- RGCN layers: aggregate (CSR) then one K=1280 GEMM ----
  ushort* cur = curb_a; ushort* nxt = curb_b;
  for (int l = 0; l < N_LAYERSC; l++){
    k_agg<<<dim3((N_NODESC+7)/8), dim3(256), 0, stream>>>(cur, agg, rowptr, ep, einvc);
    int fl = 1 | 2 | ((l < N_LAYERSC-1) ? 4 : 0);
    BGEMM(cur, DC, agg, 1024, DC, Wcat + (size_t)l*DC*1280, 1280, nxt, DC,
          N_NODESC, DC, 1280, gcn_b + l*DC, fl);
    ushort* t = nxt; nxt = cur; cur = t;
  }
  // cur == final feats (bf16, no relu)

  // ---- pool + concat + relu (fp32) ----
  k_pool<<<dim3((NUM_RC+NUM_MC+3)/4), dim3(256), 0, stream>>>(cur, grow, H_R, Hrelu);

  // ---- fused pu|qz projection (fp32, accuracy-critical) ----
  GEMM(Hrelu, DC, pqW, 1024, pq, 1024, 1088, 1024, DC, pqb, 2);

  // ---- u sampling (fp32 u + bf16 rep cols 256..511) ----
  k_sample_u<<<dim3(544), dim3(256), 0, stream>>>(pq, u, repb, ku0, ku1);

  // ---- d2, A, An ----
  k_d2<<<dim3(NUM_MC), dim3(64), 0, stream>>>(u, d2);
  k_A <<<dim3(128), dim3(256), 0, stream>>>(d2, pg_ls, An, ka0, ka1);
  k_rownorm<<<dim3(NUM_MC), dim3(64), 0, stream>>>(An);

  // ---- pzcat = An @ qz[:64] (fp32) ----
  GEMM(An, NUM_RC, pq + 512, 1024, pzcat, 512, NUM_MC, 512, NUM_RC, nullptr, 0);

  // ---- z sampling + log_pqz ----
  k_sample_zM<<<dim3(512), dim3(256), 0, stream>>>(pq, zM, repb, kzm0, kzm1);
  k_logpqz<<<dim3(1024), dim3(256), 0, stream>>>(zM, pzcat, pq, scal);
  k_sample_zR<<<dim3(32), dim3(256), 0, stream>>>(pq, repb, kzr0, kzr1);

  // ---- fused output head: hid = relu(rep @ W1 + b1), then logits+loss ----
  BGEMM(repb, 512, repb, 512, 512, W1t, 512, hid, 256, NUM_RC+NUM_MC, 256, 512, out_b1, 2|4);
  k_out_head<<<dim3((NUM_RC+NUM_MC)/4), dim3(256), 0, stream>>>(hid, out_W2, out_b2, yM, yR, scal);

  // ---- reg term & final combine ----
  k_reg<<<dim3(128), dim3(256), 0, stream>>>(d2, yM, scal);
  k_final<<<dim3(1), dim3(1), 0, stream>>>(scal, out);
}